// Round 1
// baseline (1561.966 us; speedup 1.0000x reference)
//
#include <hip/hip_runtime.h>
#include <cstddef>

#define N_NODES 50000
#define E_EDGES 1000000
// IN = 128, HID = 128, OUT = 64

// ---------------------------------------------------------------- histograms
__global__ void hist6(const int* __restrict__ i0, const int* __restrict__ i1,
                      const int* __restrict__ i2, const int* __restrict__ i3,
                      const int* __restrict__ i4, const int* __restrict__ i5,
                      int* __restrict__ cnt) {
    int rel = blockIdx.y;
    const int* idx = rel == 0 ? i0 : rel == 1 ? i1 : rel == 2 ? i2
                   : rel == 3 ? i3 : rel == 4 ? i4 : i5;
    int* c = cnt + rel * N_NODES;
    for (int i = blockIdx.x * blockDim.x + threadIdx.x; i < E_EDGES;
         i += gridDim.x * blockDim.x)
        atomicAdd(&c[idx[i]], 1);
}

// ------------------------------------------------------------- deg^{-1/2}
__global__ void make_scales(const int* __restrict__ cnt, float* __restrict__ s, int n) {
    int i = blockIdx.x * blockDim.x + threadIdx.x;
    if (i < n) {
        int c = cnt[i];
        if (c < 1) c = 1;
        s[i] = 1.0f / sqrtf((float)c);
    }
}

// --------------------------------------------- exclusive scan -> row_ptr/cursor
#define SCAN_T 1024
__global__ void scan_kernel(const int* __restrict__ cnt, int* __restrict__ row_ptr,
                            int* __restrict__ cursor) {
    int rel = blockIdx.x;                       // 0..2
    const int* c = cnt + (2 * rel + 1) * N_NODES;  // dst-count arrays are 1,3,5
    int* rp  = row_ptr + rel * (N_NODES + 1);
    int* cur = cursor + rel * N_NODES;
    __shared__ int part[SCAN_T];
    int t = threadIdx.x;
    const int CH = (N_NODES + SCAN_T - 1) / SCAN_T;  // 49
    int lo = t * CH;
    int hi = lo + CH; if (hi > N_NODES) hi = N_NODES; if (lo > N_NODES) lo = N_NODES;
    int s = 0;
    for (int i = lo; i < hi; i++) s += c[i];
    part[t] = s;
    __syncthreads();
    for (int off = 1; off < SCAN_T; off <<= 1) {
        int v = part[t];
        int add = (t >= off) ? part[t - off] : 0;
        __syncthreads();
        part[t] = v + add;
        __syncthreads();
    }
    int run = (t == 0) ? 0 : part[t - 1];   // exclusive prefix of this chunk
    for (int i = lo; i < hi; i++) {
        rp[i] = run; cur[i] = run;
        run += c[i];
    }
    if (t == SCAN_T - 1) rp[N_NODES] = run; // == E_EDGES
}

// ----------------------------------------------------------------- CSR fill
__global__ void csr_fill(const int* __restrict__ s0, const int* __restrict__ d0,
                         const int* __restrict__ s1, const int* __restrict__ d1,
                         const int* __restrict__ s2, const int* __restrict__ d2,
                         int* __restrict__ cursor, int* __restrict__ col) {
    int rel = blockIdx.y;
    const int* src = rel == 0 ? s0 : rel == 1 ? s1 : s2;
    const int* dst = rel == 0 ? d0 : rel == 1 ? d1 : d2;
    int* cur = cursor + rel * N_NODES;
    int* cl  = col + (size_t)rel * E_EDGES;
    for (int i = blockIdx.x * blockDim.x + threadIdx.x; i < E_EDGES;
         i += gridDim.x * blockDim.x) {
        int d = dst[i];
        int slot = atomicAdd(&cur[d], 1);
        cl[slot] = src[i];
    }
}

// ------------------------------------------------- T = (X .* s[:,None]) @ W
// X [nrows,128], W [128,NCOL], T [nrows,NCOL].  f32 only (no fp32 MFMA on CDNA4).
template <int NCOL>
__global__ __launch_bounds__(256) void gemm_xw(const float* __restrict__ X,
                                               const float* __restrict__ sc,
                                               const float* __restrict__ W,
                                               float* __restrict__ T, int nrows) {
    constexpr int CG = NCOL / 4;      // float4 col-groups: 32 or 16
    constexpr int ROWS = 256 / CG;    // 8 or 16 rows per block
    __shared__ float Ws[64 * NCOL];   // 64-row k-slice of W (32KB / 16KB)
    __shared__ float xs[ROWS * 128];
    int row0 = blockIdx.x * ROWS;
    // stage scaled X rows
    for (int i = threadIdx.x; i < ROWS * 32; i += 256) {
        int r = i >> 5, cc = i & 31;
        int gr = row0 + r;
        float4 v = make_float4(0.f, 0.f, 0.f, 0.f);
        float s = 0.f;
        if (gr < nrows) {
            v = ((const float4*)(X + (size_t)gr * 128))[cc];
            s = sc[gr];
        }
        v.x *= s; v.y *= s; v.z *= s; v.w *= s;
        ((float4*)xs)[i] = v;
    }
    int cg = threadIdx.x % CG, r = threadIdx.x / CG;
    const float* xrow = xs + r * 128;
    float4 acc = make_float4(0.f, 0.f, 0.f, 0.f);
    for (int kb = 0; kb < 128; kb += 64) {
        __syncthreads();  // xs ready / Ws no longer in use
        for (int i = threadIdx.x; i < 64 * CG; i += 256)
            ((float4*)Ws)[i] = ((const float4*)W)[kb * CG + i];
        __syncthreads();
#pragma unroll
        for (int k = 0; k < 64; k++) {
            float xv = xrow[kb + k];
            float4 wv = ((const float4*)Ws)[k * CG + cg];
            acc.x = fmaf(xv, wv.x, acc.x);
            acc.y = fmaf(xv, wv.y, acc.y);
            acc.z = fmaf(xv, wv.z, acc.z);
            acc.w = fmaf(xv, wv.w, acc.w);
        }
    }
    int gr = row0 + r;
    if (gr < nrows) ((float4*)(T + (size_t)gr * NCOL))[cg] = acc;
}

// ------------------------------------------------------------- CSR SpMM
// out[row,:] = (sum_{e in row} T[col[e],:]) * s_in[row] + bias  (+prev) (relu)
template <int DIM, bool ACCUM, bool RELU>
__global__ __launch_bounds__(256) void spmm(const int* __restrict__ rp,
                                            const int* __restrict__ col,
                                            const float* __restrict__ T,
                                            const float* __restrict__ s_in,
                                            const float* __restrict__ bias,
                                            float* __restrict__ outp, int nrows) {
    int wave = (blockIdx.x * blockDim.x + threadIdx.x) >> 6;
    int lane = threadIdx.x & 63;
    int nw = (gridDim.x * blockDim.x) >> 6;
    for (int row = wave; row < nrows; row += nw) {
        int beg = rp[row], end = rp[row + 1];
        float ax = 0.f, ay = 0.f;
        int e = beg;
        for (; e + 4 <= end; e += 4) {
            int c0 = col[e], c1 = col[e + 1], c2 = col[e + 2], c3 = col[e + 3];
            if constexpr (DIM == 128) {
                float2 v0 = *(const float2*)(T + (size_t)c0 * 128 + 2 * lane);
                float2 v1 = *(const float2*)(T + (size_t)c1 * 128 + 2 * lane);
                float2 v2 = *(const float2*)(T + (size_t)c2 * 128 + 2 * lane);
                float2 v3 = *(const float2*)(T + (size_t)c3 * 128 + 2 * lane);
                ax += (v0.x + v1.x) + (v2.x + v3.x);
                ay += (v0.y + v1.y) + (v2.y + v3.y);
            } else {
                float v0 = T[(size_t)c0 * 64 + lane];
                float v1 = T[(size_t)c1 * 64 + lane];
                float v2 = T[(size_t)c2 * 64 + lane];
                float v3 = T[(size_t)c3 * 64 + lane];
                ax += (v0 + v1) + (v2 + v3);
            }
        }
        for (; e < end; e++) {
            int c = col[e];
            if constexpr (DIM == 128) {
                float2 v = *(const float2*)(T + (size_t)c * 128 + 2 * lane);
                ax += v.x; ay += v.y;
            } else {
                ax += T[(size_t)c * 64 + lane];
            }
        }
        float s = s_in[row];
        if constexpr (DIM == 128) {
            float* po = outp + (size_t)row * 128 + 2 * lane;
            float ox = fmaf(ax, s, bias[2 * lane]);
            float oy = fmaf(ay, s, bias[2 * lane + 1]);
            if constexpr (ACCUM) { ox += po[0]; oy += po[1]; }
            if constexpr (RELU) { ox = fmaxf(ox, 0.f); oy = fmaxf(oy, 0.f); }
            po[0] = ox; po[1] = oy;
        } else {
            float* po = outp + (size_t)row * 64 + lane;
            float ox = fmaf(ax, s, bias[lane]);
            if constexpr (ACCUM) ox += po[0];
            if constexpr (RELU) ox = fmaxf(ox, 0.f);
            po[0] = ox;
        }
    }
}

// ---------------------------------------------------------------- scoring
__global__ __launch_bounds__(256) void score_kernel(const float* __restrict__ oA,
                                                    const float* __restrict__ oB,
                                                    const int* __restrict__ src,
                                                    const int* __restrict__ dst,
                                                    float* __restrict__ out, int n) {
    int wave = (blockIdx.x * blockDim.x + threadIdx.x) >> 6;
    int lane = threadIdx.x & 63;
    int nw = (gridDim.x * blockDim.x) >> 6;
    for (int e = wave; e < n; e += nw) {
        int s = src[e], d = dst[e];
        float p = oA[(size_t)s * 64 + lane] * oB[(size_t)d * 64 + lane];
        for (int m = 32; m; m >>= 1) p += __shfl_xor(p, m);
        if (lane == 0) out[e] = p;
    }
}

// ---------------------------------------------------------------------------
extern "C" void kernel_launch(void* const* d_in, const int* in_sizes, int n_in,
                              void* d_out, int out_size, void* d_ws, size_t ws_size,
                              hipStream_t stream) {
    const float* feat_A     = (const float*)d_in[0];
    const float* feat_B     = (const float*)d_in[1];
    const int* rates_src    = (const int*)d_in[2];
    const int* rates_dst    = (const int*)d_in[3];
    const int* ratedby_src  = (const int*)d_in[4];
    const int* ratedby_dst  = (const int*)d_in[5];
    const int* follows_src  = (const int*)d_in[6];
    const int* follows_dst  = (const int*)d_in[7];
    const int* neg_src      = (const int*)d_in[8];
    const int* neg_dst      = (const int*)d_in[9];
    const float* W1_rates   = (const float*)d_in[10];
    const float* b1_rates   = (const float*)d_in[11];
    const float* W1_ratedby = (const float*)d_in[12];
    const float* b1_ratedby = (const float*)d_in[13];
    const float* W1_follows = (const float*)d_in[14];
    const float* b1_follows = (const float*)d_in[15];
    const float* W2_rates   = (const float*)d_in[16];
    const float* b2_rates   = (const float*)d_in[17];
    const float* W2_ratedby = (const float*)d_in[18];
    const float* b2_ratedby = (const float*)d_in[19];
    const float* W2_follows = (const float*)d_in[20];
    const float* b2_follows = (const float*)d_in[21];

    const int N = N_NODES, E = E_EDGES;

    char* ws = (char*)d_ws;
    size_t off = 0;
    auto alloc = [&](size_t bytes) -> void* {
        void* p = ws + off;
        off += (bytes + 255) & ~(size_t)255;
        return p;
    };
    int* counts   = (int*)alloc((size_t)6 * N * 4);
    float* scales = (float*)alloc((size_t)6 * N * 4);
    int* row_ptr  = (int*)alloc((size_t)3 * (N + 1) * 4);
    int* cursor   = (int*)alloc((size_t)3 * N * 4);
    int* col      = (int*)alloc((size_t)3 * E * 4);
    float* T      = (float*)alloc((size_t)N * 128 * 4);
    float* hA     = (float*)alloc((size_t)N * 128 * 4);
    float* hB     = (float*)alloc((size_t)N * 128 * 4);
    float* oA     = (float*)alloc((size_t)N * 64 * 4);
    float* oB     = (float*)alloc((size_t)N * 64 * 4);
    (void)ws_size;

    hipMemsetAsync(counts, 0, (size_t)6 * N * 4, stream);
    hist6<<<dim3(1024, 6), 256, 0, stream>>>(rates_src, rates_dst, ratedby_src,
                                             ratedby_dst, follows_src, follows_dst,
                                             counts);
    make_scales<<<(6 * N + 255) / 256, 256, 0, stream>>>(counts, scales, 6 * N);
    scan_kernel<<<3, SCAN_T, 0, stream>>>(counts, row_ptr, cursor);
    csr_fill<<<dim3(1024, 3), 256, 0, stream>>>(rates_src, rates_dst, ratedby_src,
                                                ratedby_dst, follows_src, follows_dst,
                                                cursor, col);

    const int* rp0 = row_ptr;                 const int* cl0 = col;
    const int* rp1 = row_ptr + (N + 1);       const int* cl1 = col + E;
    const int* rp2 = row_ptr + 2 * (N + 1);   const int* cl2 = col + 2 * (size_t)E;
    const float* s_rates_out   = scales;          // deg_out over rates_src (A)
    const float* s_rates_in    = scales + N;      // deg_in  over rates_dst (B)
    const float* s_ratedby_out = scales + 2 * N;  // deg_out over ratedby_src (B)
    const float* s_ratedby_in  = scales + 3 * N;  // deg_in  over ratedby_dst (A)
    const float* s_follows_out = scales + 4 * N;  // deg_out over follows_src (A)
    const float* s_follows_in  = scales + 5 * N;  // deg_in  over follows_dst (A)

    // ---------------- layer 1 (HID=128) ----------------
    gemm_xw<128><<<(N + 7) / 8, 256, 0, stream>>>(feat_A, s_rates_out, W1_rates, T, N);
    spmm<128, false, true><<<(N + 3) / 4, 256, 0, stream>>>(rp0, cl0, T, s_rates_in,
                                                            b1_rates, hB, N);
    gemm_xw<128><<<(N + 7) / 8, 256, 0, stream>>>(feat_B, s_ratedby_out, W1_ratedby, T, N);
    spmm<128, false, false><<<(N + 3) / 4, 256, 0, stream>>>(rp1, cl1, T, s_ratedby_in,
                                                             b1_ratedby, hA, N);
    gemm_xw<128><<<(N + 7) / 8, 256, 0, stream>>>(feat_A, s_follows_out, W1_follows, T, N);
    spmm<128, true, true><<<(N + 3) / 4, 256, 0, stream>>>(rp2, cl2, T, s_follows_in,
                                                           b1_follows, hA, N);

    // ---------------- layer 2 (OUT=64) ----------------
    gemm_xw<64><<<(N + 15) / 16, 256, 0, stream>>>(hA, s_rates_out, W2_rates, T, N);
    spmm<64, false, false><<<(N + 3) / 4, 256, 0, stream>>>(rp0, cl0, T, s_rates_in,
                                                            b2_rates, oB, N);
    gemm_xw<64><<<(N + 15) / 16, 256, 0, stream>>>(hB, s_ratedby_out, W2_ratedby, T, N);
    spmm<64, false, false><<<(N + 3) / 4, 256, 0, stream>>>(rp1, cl1, T, s_ratedby_in,
                                                            b2_ratedby, oA, N);
    gemm_xw<64><<<(N + 15) / 16, 256, 0, stream>>>(hA, s_follows_out, W2_follows, T, N);
    spmm<64, true, false><<<(N + 3) / 4, 256, 0, stream>>>(rp2, cl2, T, s_follows_in,
                                                           b2_follows, oA, N);

    // ---------------- scoring ----------------
    float* outp = (float*)d_out;
    score_kernel<<<8192, 256, 0, stream>>>(oA, oB, rates_src, rates_dst, outp, E);
    score_kernel<<<8192, 256, 0, stream>>>(oA, oB, neg_src, neg_dst, outp + E, E);
}

// Round 2
// 1100.788 us; speedup vs baseline: 1.4190x; 1.4190x over previous
//
#include <hip/hip_runtime.h>
#include <cstddef>

#define N_NODES 50000
#define E_EDGES 1000000
#define NBUCK 196          // ceil(50000/256) dst-buckets (dst>>8)
#define ACHUNK 3907        // ceil(E/256) edges per binA block
// IN = 128, HID = 128, OUT = 64

// ---------------------------------------------------------------- histograms
__global__ void hist6(const int* __restrict__ i0, const int* __restrict__ i1,
                      const int* __restrict__ i2, const int* __restrict__ i3,
                      const int* __restrict__ i4, const int* __restrict__ i5,
                      int* __restrict__ cnt) {
    int rel = blockIdx.y;
    const int* idx = rel == 0 ? i0 : rel == 1 ? i1 : rel == 2 ? i2
                   : rel == 3 ? i3 : rel == 4 ? i4 : i5;
    int* c = cnt + rel * N_NODES;
    for (int i = blockIdx.x * blockDim.x + threadIdx.x; i < E_EDGES;
         i += gridDim.x * blockDim.x)
        atomicAdd(&c[idx[i]], 1);
}

// ------------------------------------------------------------- deg^{-1/2}
__global__ void make_scales(const int* __restrict__ cnt, float* __restrict__ s, int n) {
    int i = blockIdx.x * blockDim.x + threadIdx.x;
    if (i < n) {
        int c = cnt[i];
        if (c < 1) c = 1;
        s[i] = 1.0f / sqrtf((float)c);
    }
}

// --------------------------------------------- exclusive scan -> row_ptr/cursor
#define SCAN_T 1024
__global__ void scan_kernel(const int* __restrict__ cnt, int* __restrict__ row_ptr,
                            int* __restrict__ cursor) {
    int rel = blockIdx.x;                       // 0..2
    const int* c = cnt + (2 * rel + 1) * N_NODES;  // dst-count arrays are 1,3,5
    int* rp  = row_ptr + rel * (N_NODES + 1);
    int* cur = cursor + rel * N_NODES;
    __shared__ int part[SCAN_T];
    int t = threadIdx.x;
    const int CH = (N_NODES + SCAN_T - 1) / SCAN_T;  // 49
    int lo = t * CH;
    int hi = lo + CH; if (hi > N_NODES) hi = N_NODES; if (lo > N_NODES) lo = N_NODES;
    int s = 0;
    for (int i = lo; i < hi; i++) s += c[i];
    part[t] = s;
    __syncthreads();
    for (int off = 1; off < SCAN_T; off <<= 1) {
        int v = part[t];
        int add = (t >= off) ? part[t - off] : 0;
        __syncthreads();
        part[t] = v + add;
        __syncthreads();
    }
    int run = (t == 0) ? 0 : part[t - 1];   // exclusive prefix of this chunk
    for (int i = lo; i < hi; i++) {
        rp[i] = run; cur[i] = run;
        run += c[i];
    }
    if (t == SCAN_T - 1) rp[N_NODES] = run; // == E_EDGES
}

// ------------------------------------- per-bucket counts from degree histogram
__global__ void bucket_scan(const int* __restrict__ counts, int* __restrict__ gbase,
                            int* __restrict__ gcur) {
    int rel = blockIdx.x;                            // 0..2
    const int* c = counts + (2 * rel + 1) * N_NODES; // dst-degree array
    __shared__ int sb[NBUCK];
    for (int b = threadIdx.x; b < NBUCK; b += blockDim.x) {
        int lo = b << 8, hi = lo + 256; if (hi > N_NODES) hi = N_NODES;
        int s = 0;
        for (int i = lo; i < hi; i++) s += c[i];
        sb[b] = s;
    }
    __syncthreads();
    if (threadIdx.x == 0) {
        int* gb = gbase + rel * (NBUCK + 1);
        int* gc = gcur + rel * NBUCK;
        int run = 0;
        for (int b = 0; b < NBUCK; b++) { gb[b] = run; gc[b] = run; run += sb[b]; }
        gb[NBUCK] = run;
    }
}

// --------------------------------- phase A: bin edges into dst-bucket regions
__global__ __launch_bounds__(256) void binA(const int* __restrict__ s0, const int* __restrict__ d0,
                                            const int* __restrict__ s1, const int* __restrict__ d1,
                                            const int* __restrict__ s2, const int* __restrict__ d2,
                                            int* __restrict__ gcur, int2* __restrict__ pairs) {
    int rel = blockIdx.y;
    const int* src = rel == 0 ? s0 : rel == 1 ? s1 : s2;
    const int* dst = rel == 0 ? d0 : rel == 1 ? d1 : d2;
    int e0 = blockIdx.x * ACHUNK;
    int e1 = e0 + ACHUNK; if (e1 > E_EDGES) e1 = E_EDGES;
    __shared__ int lcnt[NBUCK];
    __shared__ int lbase[NBUCK];
    for (int b = threadIdx.x; b < NBUCK; b += 256) lcnt[b] = 0;
    __syncthreads();
    for (int i = e0 + threadIdx.x; i < e1; i += 256)
        atomicAdd(&lcnt[dst[i] >> 8], 1);
    __syncthreads();
    for (int b = threadIdx.x; b < NBUCK; b += 256) {
        lbase[b] = atomicAdd(&gcur[rel * NBUCK + b], lcnt[b]);
        lcnt[b] = 0;   // reuse as local cursor
    }
    __syncthreads();
    int2* pp = pairs + (size_t)rel * E_EDGES;
    for (int i = e0 + threadIdx.x; i < e1; i += 256) {
        int d = dst[i];
        int b = d >> 8;
        int p = lbase[b] + atomicAdd(&lcnt[b], 1);
        pp[p] = make_int2(src[i], d);
    }
}

// ------------------- phase B: per-bucket scatter into contiguous CSR span
__global__ __launch_bounds__(256) void fillB(const int2* __restrict__ pairs,
                                             const int* __restrict__ gbase,
                                             int* __restrict__ cursor, int* __restrict__ col) {
    int rel = blockIdx.y, b = blockIdx.x;
    int p0 = gbase[rel * (NBUCK + 1) + b];
    int p1 = gbase[rel * (NBUCK + 1) + b + 1];
    const int2* pp = pairs + (size_t)rel * E_EDGES;
    int* cur = cursor + rel * N_NODES;
    int* cl  = col + (size_t)rel * E_EDGES;
    for (int i = p0 + threadIdx.x; i < p1; i += 256) {
        int2 pr = pp[i];
        int slot = atomicAdd(&cur[pr.y], 1);
        cl[slot] = pr.x;
    }
}

// ------------------------------------------------- T = (X .* s[:,None]) @ W
// X [nrows,128], W [128,NCOL], T [nrows,NCOL].  f32 only (no fp32 MFMA on CDNA4).
// 64-row tile, register blocking: each thread RPT rows x 4 cols.
#define XS_LD 132   // padded row stride (floats): keeps float4 alignment, breaks 4-way bank conflict
template <int NCOL>
__global__ __launch_bounds__(256) void gemm_xw(const float* __restrict__ X,
                                               const float* __restrict__ sc,
                                               const float* __restrict__ W,
                                               float* __restrict__ T, int nrows) {
    constexpr int CG  = NCOL / 4;    // float4 col-groups: 32 or 16
    constexpr int RT  = 256 / CG;    // row-threads: 8 or 16
    constexpr int RPT = 64 / RT;     // rows per thread: 8 or 4
    __shared__ float Ws[32 * NCOL];  // 32-row k-slice of W (16KB / 8KB)
    __shared__ float xs[64 * XS_LD]; // 64 scaled X rows (33KB)
    int row0 = blockIdx.x * 64;
    int cg = threadIdx.x % CG;
    int rt = threadIdx.x / CG;
    int rbase = rt * RPT;
    // stage scaled X rows
    for (int i = threadIdx.x; i < 64 * 32; i += 256) {
        int r = i >> 5, c = i & 31;
        int gr = row0 + r;
        float4 v = make_float4(0.f, 0.f, 0.f, 0.f);
        float s = 0.f;
        if (gr < nrows) {
            v = ((const float4*)(X + (size_t)gr * 128))[c];
            s = sc[gr];
        }
        v.x *= s; v.y *= s; v.z *= s; v.w *= s;
        *(float4*)(xs + r * XS_LD + c * 4) = v;
    }
    float4 acc[RPT];
#pragma unroll
    for (int i = 0; i < RPT; i++) acc[i] = make_float4(0.f, 0.f, 0.f, 0.f);
    for (int kb = 0; kb < 128; kb += 32) {
        __syncthreads();   // xs ready / previous Ws slice no longer in use
        for (int i = threadIdx.x; i < 32 * CG; i += 256)
            ((float4*)Ws)[i] = ((const float4*)W)[kb * CG + i];
        __syncthreads();
#pragma unroll
        for (int kk = 0; kk < 32; kk += 4) {
            float4 w0 = ((const float4*)Ws)[(kk + 0) * CG + cg];
            float4 w1 = ((const float4*)Ws)[(kk + 1) * CG + cg];
            float4 w2 = ((const float4*)Ws)[(kk + 2) * CG + cg];
            float4 w3 = ((const float4*)Ws)[(kk + 3) * CG + cg];
#pragma unroll
            for (int i = 0; i < RPT; i++) {
                float4 xq = *(const float4*)(xs + (rbase + i) * XS_LD + kb + kk);
                acc[i].x = fmaf(xq.x, w0.x, acc[i].x);
                acc[i].y = fmaf(xq.x, w0.y, acc[i].y);
                acc[i].z = fmaf(xq.x, w0.z, acc[i].z);
                acc[i].w = fmaf(xq.x, w0.w, acc[i].w);
                acc[i].x = fmaf(xq.y, w1.x, acc[i].x);
                acc[i].y = fmaf(xq.y, w1.y, acc[i].y);
                acc[i].z = fmaf(xq.y, w1.z, acc[i].z);
                acc[i].w = fmaf(xq.y, w1.w, acc[i].w);
                acc[i].x = fmaf(xq.z, w2.x, acc[i].x);
                acc[i].y = fmaf(xq.z, w2.y, acc[i].y);
                acc[i].z = fmaf(xq.z, w2.z, acc[i].z);
                acc[i].w = fmaf(xq.z, w2.w, acc[i].w);
                acc[i].x = fmaf(xq.w, w3.x, acc[i].x);
                acc[i].y = fmaf(xq.w, w3.y, acc[i].y);
                acc[i].z = fmaf(xq.w, w3.z, acc[i].z);
                acc[i].w = fmaf(xq.w, w3.w, acc[i].w);
            }
        }
    }
#pragma unroll
    for (int i = 0; i < RPT; i++) {
        int gr = row0 + rbase + i;
        if (gr < nrows) ((float4*)(T + (size_t)gr * NCOL))[cg] = acc[i];
    }
}

// ------------------------------------------------------------- CSR SpMM
// out[row,:] = (sum_{e in row} T[col[e],:]) * s_in[row] + bias  (+prev) (relu)
template <int DIM, bool ACCUM, bool RELU>
__global__ __launch_bounds__(256) void spmm(const int* __restrict__ rp,
                                            const int* __restrict__ col,
                                            const float* __restrict__ T,
                                            const float* __restrict__ s_in,
                                            const float* __restrict__ bias,
                                            float* __restrict__ outp, int nrows) {
    int wave = (blockIdx.x * blockDim.x + threadIdx.x) >> 6;
    int lane = threadIdx.x & 63;
    int nw = (gridDim.x * blockDim.x) >> 6;
    for (int row = wave; row < nrows; row += nw) {
        int beg = rp[row], end = rp[row + 1];
        float ax = 0.f, ay = 0.f;
        int e = beg;
        for (; e + 4 <= end; e += 4) {
            int c0 = col[e], c1 = col[e + 1], c2 = col[e + 2], c3 = col[e + 3];
            if constexpr (DIM == 128) {
                float2 v0 = *(const float2*)(T + (size_t)c0 * 128 + 2 * lane);
                float2 v1 = *(const float2*)(T + (size_t)c1 * 128 + 2 * lane);
                float2 v2 = *(const float2*)(T + (size_t)c2 * 128 + 2 * lane);
                float2 v3 = *(const float2*)(T + (size_t)c3 * 128 + 2 * lane);
                ax += (v0.x + v1.x) + (v2.x + v3.x);
                ay += (v0.y + v1.y) + (v2.y + v3.y);
            } else {
                float v0 = T[(size_t)c0 * 64 + lane];
                float v1 = T[(size_t)c1 * 64 + lane];
                float v2 = T[(size_t)c2 * 64 + lane];
                float v3 = T[(size_t)c3 * 64 + lane];
                ax += (v0 + v1) + (v2 + v3);
            }
        }
        for (; e < end; e++) {
            int c = col[e];
            if constexpr (DIM == 128) {
                float2 v = *(const float2*)(T + (size_t)c * 128 + 2 * lane);
                ax += v.x; ay += v.y;
            } else {
                ax += T[(size_t)c * 64 + lane];
            }
        }
        float s = s_in[row];
        if constexpr (DIM == 128) {
            float* po = outp + (size_t)row * 128 + 2 * lane;
            float ox = fmaf(ax, s, bias[2 * lane]);
            float oy = fmaf(ay, s, bias[2 * lane + 1]);
            if constexpr (ACCUM) { ox += po[0]; oy += po[1]; }
            if constexpr (RELU) { ox = fmaxf(ox, 0.f); oy = fmaxf(oy, 0.f); }
            po[0] = ox; po[1] = oy;
        } else {
            float* po = outp + (size_t)row * 64 + lane;
            float ox = fmaf(ax, s, bias[lane]);
            if constexpr (ACCUM) ox += po[0];
            if constexpr (RELU) ox = fmaxf(ox, 0.f);
            po[0] = ox;
        }
    }
}

// ---------------------------------------------------------------- scoring
// 16-lane groups, float4 loads: 4 edges per wave.
__global__ __launch_bounds__(256) void score_kernel(const float* __restrict__ oA,
                                                    const float* __restrict__ oB,
                                                    const int* __restrict__ src,
                                                    const int* __restrict__ dst,
                                                    float* __restrict__ out, int n) {
    int g = (blockIdx.x * blockDim.x + threadIdx.x) >> 4;
    int l = threadIdx.x & 15;
    int ng = (gridDim.x * blockDim.x) >> 4;
    for (int e = g; e < n; e += ng) {
        int s = src[e], d = dst[e];
        float4 a = *(const float4*)(oA + (size_t)s * 64 + 4 * l);
        float4 b = *(const float4*)(oB + (size_t)d * 64 + 4 * l);
        float p = a.x * b.x + a.y * b.y + a.z * b.z + a.w * b.w;
        p += __shfl_xor(p, 8);
        p += __shfl_xor(p, 4);
        p += __shfl_xor(p, 2);
        p += __shfl_xor(p, 1);
        if (l == 0) out[e] = p;
    }
}

// ---------------------------------------------------------------------------
extern "C" void kernel_launch(void* const* d_in, const int* in_sizes, int n_in,
                              void* d_out, int out_size, void* d_ws, size_t ws_size,
                              hipStream_t stream) {
    const float* feat_A     = (const float*)d_in[0];
    const float* feat_B     = (const float*)d_in[1];
    const int* rates_src    = (const int*)d_in[2];
    const int* rates_dst    = (const int*)d_in[3];
    const int* ratedby_src  = (const int*)d_in[4];
    const int* ratedby_dst  = (const int*)d_in[5];
    const int* follows_src  = (const int*)d_in[6];
    const int* follows_dst  = (const int*)d_in[7];
    const int* neg_src      = (const int*)d_in[8];
    const int* neg_dst      = (const int*)d_in[9];
    const float* W1_rates   = (const float*)d_in[10];
    const float* b1_rates   = (const float*)d_in[11];
    const float* W1_ratedby = (const float*)d_in[12];
    const float* b1_ratedby = (const float*)d_in[13];
    const float* W1_follows = (const float*)d_in[14];
    const float* b1_follows = (const float*)d_in[15];
    const float* W2_rates   = (const float*)d_in[16];
    const float* b2_rates   = (const float*)d_in[17];
    const float* W2_ratedby = (const float*)d_in[18];
    const float* b2_ratedby = (const float*)d_in[19];
    const float* W2_follows = (const float*)d_in[20];
    const float* b2_follows = (const float*)d_in[21];

    const int N = N_NODES, E = E_EDGES;

    char* ws = (char*)d_ws;
    size_t off = 0;
    auto alloc = [&](size_t bytes) -> void* {
        void* p = ws + off;
        off += (bytes + 255) & ~(size_t)255;
        return p;
    };
    int* counts   = (int*)alloc((size_t)6 * N * 4);
    float* scales = (float*)alloc((size_t)6 * N * 4);
    int* row_ptr  = (int*)alloc((size_t)3 * (N + 1) * 4);
    int* cursor   = (int*)alloc((size_t)3 * N * 4);
    int* gbase    = (int*)alloc((size_t)3 * (NBUCK + 1) * 4);
    int* gcur     = (int*)alloc((size_t)3 * NBUCK * 4);
    int* col      = (int*)alloc((size_t)3 * E * 4);
    float* T      = (float*)alloc((size_t)N * 128 * 4);
    float* hA     = (float*)alloc((size_t)N * 128 * 4);
    float* hB     = (float*)alloc((size_t)N * 128 * 4);
    float* oA     = (float*)alloc((size_t)N * 64 * 4);
    float* oB     = (float*)alloc((size_t)N * 64 * 4);
    (void)ws_size;
    // pairs buffer aliases T: binA writes it, fillB consumes it, all before
    // the first gemm writes T (stream-ordered).
    int2* pairs = (int2*)T;   // 3*E*8 = 24MB <= 25.6MB

    hipMemsetAsync(counts, 0, (size_t)6 * N * 4, stream);
    hist6<<<dim3(1024, 6), 256, 0, stream>>>(rates_src, rates_dst, ratedby_src,
                                             ratedby_dst, follows_src, follows_dst,
                                             counts);
    make_scales<<<(6 * N + 255) / 256, 256, 0, stream>>>(counts, scales, 6 * N);
    scan_kernel<<<3, SCAN_T, 0, stream>>>(counts, row_ptr, cursor);
    bucket_scan<<<3, 256, 0, stream>>>(counts, gbase, gcur);
    binA<<<dim3(256, 3), 256, 0, stream>>>(rates_src, rates_dst, ratedby_src,
                                           ratedby_dst, follows_src, follows_dst,
                                           gcur, pairs);
    fillB<<<dim3(NBUCK, 3), 256, 0, stream>>>(pairs, gbase, cursor, col);

    const int* rp0 = row_ptr;                 const int* cl0 = col;
    const int* rp1 = row_ptr + (N + 1);       const int* cl1 = col + E;
    const int* rp2 = row_ptr + 2 * (N + 1);   const int* cl2 = col + 2 * (size_t)E;
    const float* s_rates_out   = scales;          // deg_out over rates_src (A)
    const float* s_rates_in    = scales + N;      // deg_in  over rates_dst (B)
    const float* s_ratedby_out = scales + 2 * N;  // deg_out over ratedby_src (B)
    const float* s_ratedby_in  = scales + 3 * N;  // deg_in  over ratedby_dst (A)
    const float* s_follows_out = scales + 4 * N;  // deg_out over follows_src (A)
    const float* s_follows_in  = scales + 5 * N;  // deg_in  over follows_dst (A)

    const int GB = (N + 63) / 64;   // gemm blocks

    // ---------------- layer 1 (HID=128) ----------------
    gemm_xw<128><<<GB, 256, 0, stream>>>(feat_A, s_rates_out, W1_rates, T, N);
    spmm<128, false, true><<<(N + 3) / 4, 256, 0, stream>>>(rp0, cl0, T, s_rates_in,
                                                            b1_rates, hB, N);
    gemm_xw<128><<<GB, 256, 0, stream>>>(feat_B, s_ratedby_out, W1_ratedby, T, N);
    spmm<128, false, false><<<(N + 3) / 4, 256, 0, stream>>>(rp1, cl1, T, s_ratedby_in,
                                                             b1_ratedby, hA, N);
    gemm_xw<128><<<GB, 256, 0, stream>>>(feat_A, s_follows_out, W1_follows, T, N);
    spmm<128, true, true><<<(N + 3) / 4, 256, 0, stream>>>(rp2, cl2, T, s_follows_in,
                                                           b1_follows, hA, N);

    // ---------------- layer 2 (OUT=64) ----------------
    gemm_xw<64><<<GB, 256, 0, stream>>>(hA, s_rates_out, W2_rates, T, N);
    spmm<64, false, false><<<(N + 3) / 4, 256, 0, stream>>>(rp0, cl0, T, s_rates_in,
                                                            b2_rates, oB, N);
    gemm_xw<64><<<GB, 256, 0, stream>>>(hB, s_ratedby_out, W2_ratedby, T, N);
    spmm<64, false, false><<<(N + 3) / 4, 256, 0, stream>>>(rp1, cl1, T, s_ratedby_in,
                                                            b2_ratedby, oA, N);
    gemm_xw<64><<<GB, 256, 0, stream>>>(hA, s_follows_out, W2_follows, T, N);
    spmm<64, true, false><<<(N + 3) / 4, 256, 0, stream>>>(rp2, cl2, T, s_follows_in,
                                                           b2_follows, oA, N);

    // ---------------- scoring ----------------
    float* outp = (float*)d_out;
    score_kernel<<<8192, 256, 0, stream>>>(oA, oB, rates_src, rates_dst, outp, E);
    score_kernel<<<8192, 256, 0, stream>>>(oA, oB, neg_src, neg_dst, outp + E, E);
}

// Round 3
// 1099.563 us; speedup vs baseline: 1.4205x; 1.0011x over previous
//
#include <hip/hip_runtime.h>
#include <cstddef>

#define N_NODES 50000
#define E_EDGES 1000000
#define NBUCK 196          // ceil(50000/256) dst-buckets (dst>>8)
#define ACHUNK 3907        // ceil(E/256) edges per binA block
// IN = 128, HID = 128, OUT = 64

// ------------------------------------------------ XCD-sliced histograms
// 8 private partial-count arrays (one per XCD, selected by blockIdx&7) keep
// the atomic lines resident in a single XCD's L2 -> no cross-XCD HBM ping-pong.
__global__ void hist8(const int* __restrict__ i0, const int* __restrict__ i1,
                      const int* __restrict__ i2, const int* __restrict__ i3,
                      const int* __restrict__ i4, const int* __restrict__ i5,
                      int* __restrict__ cnt8) {
    int rel = blockIdx.y;
    const int* idx = rel == 0 ? i0 : rel == 1 ? i1 : rel == 2 ? i2
                   : rel == 3 ? i3 : rel == 4 ? i4 : i5;
    int* c = cnt8 + (size_t)(blockIdx.x & 7) * 6 * N_NODES + rel * N_NODES;
    for (int i = blockIdx.x * blockDim.x + threadIdx.x; i < E_EDGES;
         i += gridDim.x * blockDim.x)
        atomicAdd(&c[idx[i]], 1);
}

// ---------------------------- reduce 8 partials -> counts + deg^{-1/2} scales
__global__ void reduce_counts(const int* __restrict__ cnt8, int* __restrict__ counts,
                              float* __restrict__ scales) {
    int a = blockIdx.x * blockDim.x + threadIdx.x;
    if (a < 6 * N_NODES) {
        int s = 0;
#pragma unroll
        for (int x = 0; x < 8; x++) s += cnt8[(size_t)x * 6 * N_NODES + a];
        counts[a] = s;
        if (s < 1) s = 1;
        scales[a] = 1.0f / sqrtf((float)s);
    }
}

// --------------------------------------------- exclusive scan -> row_ptr/cursor
#define SCAN_T 1024
__global__ void scan_kernel(const int* __restrict__ cnt, int* __restrict__ row_ptr,
                            int* __restrict__ cursor) {
    int rel = blockIdx.x;                       // 0..2
    const int* c = cnt + (2 * rel + 1) * N_NODES;  // dst-count arrays are 1,3,5
    int* rp  = row_ptr + rel * (N_NODES + 1);
    int* cur = cursor + rel * N_NODES;
    __shared__ int part[SCAN_T];
    int t = threadIdx.x;
    const int CH = (N_NODES + SCAN_T - 1) / SCAN_T;  // 49
    int lo = t * CH;
    int hi = lo + CH; if (hi > N_NODES) hi = N_NODES; if (lo > N_NODES) lo = N_NODES;
    int s = 0;
    for (int i = lo; i < hi; i++) s += c[i];
    part[t] = s;
    __syncthreads();
    for (int off = 1; off < SCAN_T; off <<= 1) {
        int v = part[t];
        int add = (t >= off) ? part[t - off] : 0;
        __syncthreads();
        part[t] = v + add;
        __syncthreads();
    }
    int run = (t == 0) ? 0 : part[t - 1];   // exclusive prefix of this chunk
    for (int i = lo; i < hi; i++) {
        rp[i] = run; cur[i] = run;
        run += c[i];
    }
    if (t == SCAN_T - 1) rp[N_NODES] = run; // == E_EDGES
}

// ------------------------------------- per-bucket counts from degree histogram
__global__ void bucket_scan(const int* __restrict__ counts, int* __restrict__ gbase,
                            int* __restrict__ gcur) {
    int rel = blockIdx.x;                            // 0..2
    const int* c = counts + (2 * rel + 1) * N_NODES; // dst-degree array
    __shared__ int sb[NBUCK];
    for (int b = threadIdx.x; b < NBUCK; b += blockDim.x) {
        int lo = b << 8, hi = lo + 256; if (hi > N_NODES) hi = N_NODES;
        int s = 0;
        for (int i = lo; i < hi; i++) s += c[i];
        sb[b] = s;
    }
    __syncthreads();
    if (threadIdx.x == 0) {
        int* gb = gbase + rel * (NBUCK + 1);
        int* gc = gcur + rel * NBUCK;
        int run = 0;
        for (int b = 0; b < NBUCK; b++) { gb[b] = run; gc[b] = run; run += sb[b]; }
        gb[NBUCK] = run;
    }
}

// --------------------------------- phase A: bin edges into dst-bucket regions
__global__ __launch_bounds__(256) void binA(const int* __restrict__ s0, const int* __restrict__ d0,
                                            const int* __restrict__ s1, const int* __restrict__ d1,
                                            const int* __restrict__ s2, const int* __restrict__ d2,
                                            int* __restrict__ gcur, int2* __restrict__ pairs) {
    int rel = blockIdx.y;
    const int* src = rel == 0 ? s0 : rel == 1 ? s1 : s2;
    const int* dst = rel == 0 ? d0 : rel == 1 ? d1 : d2;
    int e0 = blockIdx.x * ACHUNK;
    int e1 = e0 + ACHUNK; if (e1 > E_EDGES) e1 = E_EDGES;
    __shared__ int lcnt[NBUCK];
    __shared__ int lbase[NBUCK];
    for (int b = threadIdx.x; b < NBUCK; b += 256) lcnt[b] = 0;
    __syncthreads();
    for (int i = e0 + threadIdx.x; i < e1; i += 256)
        atomicAdd(&lcnt[dst[i] >> 8], 1);
    __syncthreads();
    for (int b = threadIdx.x; b < NBUCK; b += 256) {
        lbase[b] = atomicAdd(&gcur[rel * NBUCK + b], lcnt[b]);
        lcnt[b] = 0;   // reuse as local cursor
    }
    __syncthreads();
    int2* pp = pairs + (size_t)rel * E_EDGES;
    for (int i = e0 + threadIdx.x; i < e1; i += 256) {
        int d = dst[i];
        int b = d >> 8;
        int p = lbase[b] + atomicAdd(&lcnt[b], 1);
        pp[p] = make_int2(src[i], d);
    }
}

// ------------------- phase B: per-bucket scatter into contiguous CSR span
__global__ __launch_bounds__(256) void fillB(const int2* __restrict__ pairs,
                                             const int* __restrict__ gbase,
                                             int* __restrict__ cursor, int* __restrict__ col) {
    int rel = blockIdx.y, b = blockIdx.x;
    int p0 = gbase[rel * (NBUCK + 1) + b];
    int p1 = gbase[rel * (NBUCK + 1) + b + 1];
    const int2* pp = pairs + (size_t)rel * E_EDGES;
    int* cur = cursor + rel * N_NODES;
    int* cl  = col + (size_t)rel * E_EDGES;
    for (int i = p0 + threadIdx.x; i < p1; i += 256) {
        int2 pr = pp[i];
        int slot = atomicAdd(&cur[pr.y], 1);
        cl[slot] = pr.x;
    }
}

// ------------------------------------------------- T = (X .* s[:,None]) @ W
// X [nrows,128], W [128,NCOL], T [nrows,NCOL].  f32 only (no fp32 MFMA on CDNA4).
// 64-row tile, register blocking: each thread RPT rows x 4 cols.
#define XS_LD 132   // padded row stride (floats): keeps float4 alignment, breaks 4-way bank conflict
template <int NCOL>
__global__ __launch_bounds__(256) void gemm_xw(const float* __restrict__ X,
                                               const float* __restrict__ sc,
                                               const float* __restrict__ W,
                                               float* __restrict__ T, int nrows) {
    constexpr int CG  = NCOL / 4;    // float4 col-groups: 32 or 16
    constexpr int RT  = 256 / CG;    // row-threads: 8 or 16
    constexpr int RPT = 64 / RT;     // rows per thread: 8 or 4
    __shared__ float Ws[32 * NCOL];  // 32-row k-slice of W (16KB / 8KB)
    __shared__ float xs[64 * XS_LD]; // 64 scaled X rows (33KB)
    int row0 = blockIdx.x * 64;
    int cg = threadIdx.x % CG;
    int rt = threadIdx.x / CG;
    int rbase = rt * RPT;
    // stage scaled X rows
    for (int i = threadIdx.x; i < 64 * 32; i += 256) {
        int r = i >> 5, c = i & 31;
        int gr = row0 + r;
        float4 v = make_float4(0.f, 0.f, 0.f, 0.f);
        float s = 0.f;
        if (gr < nrows) {
            v = ((const float4*)(X + (size_t)gr * 128))[c];
            s = sc[gr];
        }
        v.x *= s; v.y *= s; v.z *= s; v.w *= s;
        *(float4*)(xs + r * XS_LD + c * 4) = v;
    }
    float4 acc[RPT];
#pragma unroll
    for (int i = 0; i < RPT; i++) acc[i] = make_float4(0.f, 0.f, 0.f, 0.f);
    for (int kb = 0; kb < 128; kb += 32) {
        __syncthreads();   // xs ready / previous Ws slice no longer in use
        for (int i = threadIdx.x; i < 32 * CG; i += 256)
            ((float4*)Ws)[i] = ((const float4*)W)[kb * CG + i];
        __syncthreads();
#pragma unroll
        for (int kk = 0; kk < 32; kk += 4) {
            float4 w0 = ((const float4*)Ws)[(kk + 0) * CG + cg];
            float4 w1 = ((const float4*)Ws)[(kk + 1) * CG + cg];
            float4 w2 = ((const float4*)Ws)[(kk + 2) * CG + cg];
            float4 w3 = ((const float4*)Ws)[(kk + 3) * CG + cg];
#pragma unroll
            for (int i = 0; i < RPT; i++) {
                float4 xq = *(const float4*)(xs + (rbase + i) * XS_LD + kb + kk);
                acc[i].x = fmaf(xq.x, w0.x, acc[i].x);
                acc[i].y = fmaf(xq.x, w0.y, acc[i].y);
                acc[i].z = fmaf(xq.x, w0.z, acc[i].z);
                acc[i].w = fmaf(xq.x, w0.w, acc[i].w);
                acc[i].x = fmaf(xq.y, w1.x, acc[i].x);
                acc[i].y = fmaf(xq.y, w1.y, acc[i].y);
                acc[i].z = fmaf(xq.y, w1.z, acc[i].z);
                acc[i].w = fmaf(xq.y, w1.w, acc[i].w);
                acc[i].x = fmaf(xq.z, w2.x, acc[i].x);
                acc[i].y = fmaf(xq.z, w2.y, acc[i].y);
                acc[i].z = fmaf(xq.z, w2.z, acc[i].z);
                acc[i].w = fmaf(xq.z, w2.w, acc[i].w);
                acc[i].x = fmaf(xq.w, w3.x, acc[i].x);
                acc[i].y = fmaf(xq.w, w3.y, acc[i].y);
                acc[i].z = fmaf(xq.w, w3.z, acc[i].z);
                acc[i].w = fmaf(xq.w, w3.w, acc[i].w);
            }
        }
    }
#pragma unroll
    for (int i = 0; i < RPT; i++) {
        int gr = row0 + rbase + i;
        if (gr < nrows) ((float4*)(T + (size_t)gr * NCOL))[cg] = acc[i];
    }
}

// ------------------------------------------------------------- CSR SpMM
// out[row,:] = (sum_{e in row} T[col[e],:]) * s_in[row] + bias  (+prev) (relu)
template <int DIM, bool ACCUM, bool RELU>
__global__ __launch_bounds__(256) void spmm(const int* __restrict__ rp,
                                            const int* __restrict__ col,
                                            const float* __restrict__ T,
                                            const float* __restrict__ s_in,
                                            const float* __restrict__ bias,
                                            float* __restrict__ outp, int nrows) {
    int wave = (blockIdx.x * blockDim.x + threadIdx.x) >> 6;
    int lane = threadIdx.x & 63;
    int nw = (gridDim.x * blockDim.x) >> 6;
    for (int row = wave; row < nrows; row += nw) {
        int beg = rp[row], end = rp[row + 1];
        float ax = 0.f, ay = 0.f;
        int e = beg;
        for (; e + 4 <= end; e += 4) {
            int c0 = col[e], c1 = col[e + 1], c2 = col[e + 2], c3 = col[e + 3];
            if constexpr (DIM == 128) {
                float2 v0 = *(const float2*)(T + (size_t)c0 * 128 + 2 * lane);
                float2 v1 = *(const float2*)(T + (size_t)c1 * 128 + 2 * lane);
                float2 v2 = *(const float2*)(T + (size_t)c2 * 128 + 2 * lane);
                float2 v3 = *(const float2*)(T + (size_t)c3 * 128 + 2 * lane);
                ax += (v0.x + v1.x) + (v2.x + v3.x);
                ay += (v0.y + v1.y) + (v2.y + v3.y);
            } else {
                float v0 = T[(size_t)c0 * 64 + lane];
                float v1 = T[(size_t)c1 * 64 + lane];
                float v2 = T[(size_t)c2 * 64 + lane];
                float v3 = T[(size_t)c3 * 64 + lane];
                ax += (v0 + v1) + (v2 + v3);
            }
        }
        for (; e < end; e++) {
            int c = col[e];
            if constexpr (DIM == 128) {
                float2 v = *(const float2*)(T + (size_t)c * 128 + 2 * lane);
                ax += v.x; ay += v.y;
            } else {
                ax += T[(size_t)c * 64 + lane];
            }
        }
        float s = s_in[row];
        if constexpr (DIM == 128) {
            float* po = outp + (size_t)row * 128 + 2 * lane;
            float ox = fmaf(ax, s, bias[2 * lane]);
            float oy = fmaf(ay, s, bias[2 * lane + 1]);
            if constexpr (ACCUM) { ox += po[0]; oy += po[1]; }
            if constexpr (RELU) { ox = fmaxf(ox, 0.f); oy = fmaxf(oy, 0.f); }
            po[0] = ox; po[1] = oy;
        } else {
            float* po = outp + (size_t)row * 64 + lane;
            float ox = fmaf(ax, s, bias[lane]);
            if constexpr (ACCUM) ox += po[0];
            if constexpr (RELU) ox = fmaxf(ox, 0.f);
            po[0] = ox;
        }
    }
}

// ---------------------------------------------------------------- scoring
// 16-lane groups, float4 loads: 4 edges per wave.
__global__ __launch_bounds__(256) void score_kernel(const float* __restrict__ oA,
                                                    const float* __restrict__ oB,
                                                    const int* __restrict__ src,
                                                    const int* __restrict__ dst,
                                                    float* __restrict__ out, int n) {
    int g = (blockIdx.x * blockDim.x + threadIdx.x) >> 4;
    int l = threadIdx.x & 15;
    int ng = (gridDim.x * blockDim.x) >> 4;
    for (int e = g; e < n; e += ng) {
        int s = src[e], d = dst[e];
        float4 a = *(const float4*)(oA + (size_t)s * 64 + 4 * l);
        float4 b = *(const float4*)(oB + (size_t)d * 64 + 4 * l);
        float p = a.x * b.x + a.y * b.y + a.z * b.z + a.w * b.w;
        p += __shfl_xor(p, 8);
        p += __shfl_xor(p, 4);
        p += __shfl_xor(p, 2);
        p += __shfl_xor(p, 1);
        if (l == 0) out[e] = p;
    }
}

// ---------------------------------------------------------------------------
extern "C" void kernel_launch(void* const* d_in, const int* in_sizes, int n_in,
                              void* d_out, int out_size, void* d_ws, size_t ws_size,
                              hipStream_t stream) {
    const float* feat_A     = (const float*)d_in[0];
    const float* feat_B     = (const float*)d_in[1];
    const int* rates_src    = (const int*)d_in[2];
    const int* rates_dst    = (const int*)d_in[3];
    const int* ratedby_src  = (const int*)d_in[4];
    const int* ratedby_dst  = (const int*)d_in[5];
    const int* follows_src  = (const int*)d_in[6];
    const int* follows_dst  = (const int*)d_in[7];
    const int* neg_src      = (const int*)d_in[8];
    const int* neg_dst      = (const int*)d_in[9];
    const float* W1_rates   = (const float*)d_in[10];
    const float* b1_rates   = (const float*)d_in[11];
    const float* W1_ratedby = (const float*)d_in[12];
    const float* b1_ratedby = (const float*)d_in[13];
    const float* W1_follows = (const float*)d_in[14];
    const float* b1_follows = (const float*)d_in[15];
    const float* W2_rates   = (const float*)d_in[16];
    const float* b2_rates   = (const float*)d_in[17];
    const float* W2_ratedby = (const float*)d_in[18];
    const float* b2_ratedby = (const float*)d_in[19];
    const float* W2_follows = (const float*)d_in[20];
    const float* b2_follows = (const float*)d_in[21];

    const int N = N_NODES, E = E_EDGES;

    char* ws = (char*)d_ws;
    size_t off = 0;
    auto alloc = [&](size_t bytes) -> void* {
        void* p = ws + off;
        off += (bytes + 255) & ~(size_t)255;
        return p;
    };
    int* cnt8     = (int*)alloc((size_t)8 * 6 * N * 4);   // XCD-sliced partials
    int* counts   = (int*)alloc((size_t)6 * N * 4);
    float* scales = (float*)alloc((size_t)6 * N * 4);
    int* row_ptr  = (int*)alloc((size_t)3 * (N + 1) * 4);
    int* cursor   = (int*)alloc((size_t)3 * N * 4);
    int* gbase    = (int*)alloc((size_t)3 * (NBUCK + 1) * 4);
    int* gcur     = (int*)alloc((size_t)3 * NBUCK * 4);
    int* col      = (int*)alloc((size_t)3 * E * 4);
    float* T      = (float*)alloc((size_t)N * 128 * 4);
    float* hA     = (float*)alloc((size_t)N * 128 * 4);
    float* hB     = (float*)alloc((size_t)N * 128 * 4);
    float* oA     = (float*)alloc((size_t)N * 64 * 4);
    float* oB     = (float*)alloc((size_t)N * 64 * 4);
    (void)ws_size;
    // pairs buffer aliases T: binA writes it, fillB consumes it, all before
    // the first gemm writes T (stream-ordered).
    int2* pairs = (int2*)T;   // 3*E*8 = 24MB <= 25.6MB

    hipMemsetAsync(cnt8, 0, (size_t)8 * 6 * N * 4, stream);
    hist8<<<dim3(1024, 6), 256, 0, stream>>>(rates_src, rates_dst, ratedby_src,
                                             ratedby_dst, follows_src, follows_dst,
                                             cnt8);
    reduce_counts<<<(6 * N + 255) / 256, 256, 0, stream>>>(cnt8, counts, scales);
    scan_kernel<<<3, SCAN_T, 0, stream>>>(counts, row_ptr, cursor);
    bucket_scan<<<3, 256, 0, stream>>>(counts, gbase, gcur);
    binA<<<dim3(256, 3), 256, 0, stream>>>(rates_src, rates_dst, ratedby_src,
                                           ratedby_dst, follows_src, follows_dst,
                                           gcur, pairs);
    fillB<<<dim3(NBUCK, 3), 256, 0, stream>>>(pairs, gbase, cursor, col);

    const int* rp0 = row_ptr;                 const int* cl0 = col;
    const int* rp1 = row_ptr + (N + 1);       const int* cl1 = col + E;
    const int* rp2 = row_ptr + 2 * (N + 1);   const int* cl2 = col + 2 * (size_t)E;
    const float* s_rates_out   = scales;          // deg_out over rates_src (A)
    const float* s_rates_in    = scales + N;      // deg_in  over rates_dst (B)
    const float* s_ratedby_out = scales + 2 * N;  // deg_out over ratedby_src (B)
    const float* s_ratedby_in  = scales + 3 * N;  // deg_in  over ratedby_dst (A)
    const float* s_follows_out = scales + 4 * N;  // deg_out over follows_src (A)
    const float* s_follows_in  = scales + 5 * N;  // deg_in  over follows_dst (A)

    const int GB = (N + 63) / 64;   // gemm blocks

    // ---------------- layer 1 (HID=128) ----------------
    gemm_xw<128><<<GB, 256, 0, stream>>>(feat_A, s_rates_out, W1_rates, T, N);
    spmm<128, false, true><<<(N + 3) / 4, 256, 0, stream>>>(rp0, cl0, T, s_rates_in,
                                                            b1_rates, hB, N);
    gemm_xw<128><<<GB, 256, 0, stream>>>(feat_B, s_ratedby_out, W1_ratedby, T, N);
    spmm<128, false, false><<<(N + 3) / 4, 256, 0, stream>>>(rp1, cl1, T, s_ratedby_in,
                                                             b1_ratedby, hA, N);
    gemm_xw<128><<<GB, 256, 0, stream>>>(feat_A, s_follows_out, W1_follows, T, N);
    spmm<128, true, true><<<(N + 3) / 4, 256, 0, stream>>>(rp2, cl2, T, s_follows_in,
                                                           b1_follows, hA, N);

    // ---------------- layer 2 (OUT=64) ----------------
    gemm_xw<64><<<GB, 256, 0, stream>>>(hA, s_rates_out, W2_rates, T, N);
    spmm<64, false, false><<<(N + 3) / 4, 256, 0, stream>>>(rp0, cl0, T, s_rates_in,
                                                            b2_rates, oB, N);
    gemm_xw<64><<<GB, 256, 0, stream>>>(hB, s_ratedby_out, W2_ratedby, T, N);
    spmm<64, false, false><<<(N + 3) / 4, 256, 0, stream>>>(rp1, cl1, T, s_ratedby_in,
                                                            b2_ratedby, oA, N);
    gemm_xw<64><<<GB, 256, 0, stream>>>(hA, s_follows_out, W2_follows, T, N);
    spmm<64, true, false><<<(N + 3) / 4, 256, 0, stream>>>(rp2, cl2, T, s_follows_in,
                                                           b2_follows, oA, N);

    // ---------------- scoring ----------------
    float* outp = (float*)d_out;
    score_kernel<<<8192, 256, 0, stream>>>(oA, oB, rates_src, rates_dst, outp, E);
    score_kernel<<<8192, 256, 0, stream>>>(oA, oB, neg_src, neg_dst, outp + E, E);
}

// Round 4
// 751.617 us; speedup vs baseline: 2.0781x; 1.4629x over previous
//
#include <hip/hip_runtime.h>
#include <cstddef>

#define N_NODES 50000
#define E_EDGES 1000000
#define NBUCK 196          // ceil(50000/256) node-buckets (node>>8)
#define ACHUNK 3907        // ceil(E/256) edges per binning block
// IN = 128, HID = 128, OUT = 64

// ---------------------------------------------- per-bucket histogram (coarse)
// LDS 196-bin histogram per block; ONE global atomic per (block,bucket).
// arr 0..5 = rates_src, rates_dst, ratedby_src, ratedby_dst, follows_src, follows_dst
__global__ __launch_bounds__(256) void bucket_hist(const int* __restrict__ i0, const int* __restrict__ i1,
                                                   const int* __restrict__ i2, const int* __restrict__ i3,
                                                   const int* __restrict__ i4, const int* __restrict__ i5,
                                                   int* __restrict__ bhist) {
    int arr = blockIdx.y;
    const int* idx = arr == 0 ? i0 : arr == 1 ? i1 : arr == 2 ? i2
                   : arr == 3 ? i3 : arr == 4 ? i4 : i5;
    __shared__ int l[NBUCK];
    for (int b = threadIdx.x; b < NBUCK; b += 256) l[b] = 0;
    __syncthreads();
    int e0 = blockIdx.x * ACHUNK;
    int e1 = e0 + ACHUNK; if (e1 > E_EDGES) e1 = E_EDGES;
    for (int i = e0 + threadIdx.x; i < e1; i += 256)
        atomicAdd(&l[((unsigned)idx[i]) >> 8], 1);
    __syncthreads();
    for (int b = threadIdx.x; b < NBUCK; b += 256)
        if (l[b]) atomicAdd(&bhist[arr * NBUCK + b], l[b]);
}

// ------------------------------------- scan bucket counts -> gbase, gcur
__global__ void bucket_scan2(const int* __restrict__ bhist, int* __restrict__ gbase,
                             int* __restrict__ gcur) {
    int arr = blockIdx.x;   // 0..5
    if (threadIdx.x == 0) {
        int run = 0;
        for (int b = 0; b < NBUCK; b++) {
            gbase[arr * (NBUCK + 1) + b] = run;
            gcur[arr * NBUCK + b] = run;
            run += bhist[arr * NBUCK + b];
        }
        gbase[arr * (NBUCK + 1) + NBUCK] = run;
    }
}

// ---------------------- bin (dst&255)<<16 | src by dst-bucket (arrs 1,3,5)
__global__ __launch_bounds__(256) void binP(const int* __restrict__ s0, const int* __restrict__ d0,
                                            const int* __restrict__ s1, const int* __restrict__ d1,
                                            const int* __restrict__ s2, const int* __restrict__ d2,
                                            int* __restrict__ gcur, unsigned* __restrict__ pairs) {
    int rel = blockIdx.y;
    int arr = 2 * rel + 1;
    const int* src = rel == 0 ? s0 : rel == 1 ? s1 : s2;
    const int* dst = rel == 0 ? d0 : rel == 1 ? d1 : d2;
    int e0 = blockIdx.x * ACHUNK;
    int e1 = e0 + ACHUNK; if (e1 > E_EDGES) e1 = E_EDGES;
    __shared__ int lcnt[NBUCK];
    __shared__ int lbase[NBUCK];
    for (int b = threadIdx.x; b < NBUCK; b += 256) lcnt[b] = 0;
    __syncthreads();
    for (int i = e0 + threadIdx.x; i < e1; i += 256)
        atomicAdd(&lcnt[((unsigned)dst[i]) >> 8], 1);
    __syncthreads();
    for (int b = threadIdx.x; b < NBUCK; b += 256) {
        lbase[b] = lcnt[b] ? atomicAdd(&gcur[arr * NBUCK + b], lcnt[b]) : 0;
        lcnt[b] = 0;   // reuse as local cursor
    }
    __syncthreads();
    unsigned* pp = pairs + (size_t)rel * E_EDGES;
    for (int i = e0 + threadIdx.x; i < e1; i += 256) {
        int d = dst[i];
        int b = ((unsigned)d) >> 8;
        int p = lbase[b] + atomicAdd(&lcnt[b], 1);
        pp[p] = ((unsigned)(d & 255) << 16) | (unsigned)src[i];
    }
}

// ---------------------- bin src&255 bytes by src-bucket (arrs 0,2,4)
__global__ __launch_bounds__(256) void binS(const int* __restrict__ s0, const int* __restrict__ s1,
                                            const int* __restrict__ s2,
                                            int* __restrict__ gcur, unsigned char* __restrict__ sbytes) {
    int rel = blockIdx.y;
    int arr = 2 * rel;
    const int* src = rel == 0 ? s0 : rel == 1 ? s1 : s2;
    int e0 = blockIdx.x * ACHUNK;
    int e1 = e0 + ACHUNK; if (e1 > E_EDGES) e1 = E_EDGES;
    __shared__ int lcnt[NBUCK];
    __shared__ int lbase[NBUCK];
    for (int b = threadIdx.x; b < NBUCK; b += 256) lcnt[b] = 0;
    __syncthreads();
    for (int i = e0 + threadIdx.x; i < e1; i += 256)
        atomicAdd(&lcnt[((unsigned)src[i]) >> 8], 1);
    __syncthreads();
    for (int b = threadIdx.x; b < NBUCK; b += 256) {
        lbase[b] = lcnt[b] ? atomicAdd(&gcur[arr * NBUCK + b], lcnt[b]) : 0;
        lcnt[b] = 0;
    }
    __syncthreads();
    unsigned char* sb = sbytes + (size_t)rel * E_EDGES;
    for (int i = e0 + threadIdx.x; i < e1; i += 256) {
        int s = src[i];
        int b = ((unsigned)s) >> 8;
        int p = lbase[b] + atomicAdd(&lcnt[b], 1);
        sb[p] = (unsigned char)(s & 255);
    }
}

// ------------------- per-bucket src-degree count -> scales (arrs 0,2,4)
__global__ __launch_bounds__(256) void countS(const unsigned char* __restrict__ sbytes,
                                              const int* __restrict__ gbase,
                                              float* __restrict__ scales) {
    int rel = blockIdx.y, b = blockIdx.x;
    int arr = 2 * rel;
    int p0 = gbase[arr * (NBUCK + 1) + b];
    int p1 = gbase[arr * (NBUCK + 1) + b + 1];
    const unsigned char* sb = sbytes + (size_t)rel * E_EDGES;
    __shared__ int cnt[256];
    cnt[threadIdx.x] = 0;
    __syncthreads();
    for (int i = p0 + threadIdx.x; i < p1; i += 256)
        atomicAdd(&cnt[sb[i]], 1);
    __syncthreads();
    int node = b * 256 + threadIdx.x;
    if (node < N_NODES) {
        int c = cnt[threadIdx.x];
        if (c < 1) c = 1;
        scales[(size_t)arr * N_NODES + node] = 1.0f / sqrtf((float)c);
    }
}

// ---- per-bucket: dst counts -> row_ptr + dst scales + CSR col scatter (LDS cursors)
__global__ __launch_bounds__(256) void fillB2(const unsigned* __restrict__ pairs,
                                              const int* __restrict__ gbase,
                                              int* __restrict__ row_ptr,
                                              float* __restrict__ scales,
                                              int* __restrict__ col) {
    int rel = blockIdx.y, b = blockIdx.x;
    int arr = 2 * rel + 1;
    int gb = gbase[arr * (NBUCK + 1) + b];
    int ge = gbase[arr * (NBUCK + 1) + b + 1];
    const unsigned* pp = pairs + (size_t)rel * E_EDGES;
    __shared__ int cnt[256];
    __shared__ int rowbase[256];
    __shared__ int wsum[4];
    int t = threadIdx.x;
    cnt[t] = 0;
    __syncthreads();
    for (int i = gb + t; i < ge; i += 256)
        atomicAdd(&cnt[pp[i] >> 16], 1);
    __syncthreads();
    // exclusive prefix scan of cnt[256] (4 waves, shfl)
    int lane = t & 63, wid = t >> 6;
    int c0 = cnt[t];
    int v = c0;
#pragma unroll
    for (int o = 1; o < 64; o <<= 1) {
        int u = __shfl_up(v, o);
        if (lane >= o) v += u;
    }
    if (lane == 63) wsum[wid] = v;
    __syncthreads();
    int base = gb;
    for (int w = 0; w < wid; w++) base += wsum[w];
    int excl = base + v - c0;
    rowbase[t] = excl;
    int node = b * 256 + t;
    if (node <= N_NODES)   // node==N only at bucket 195,t=80 -> excl==E (sentinel)
        row_ptr[(size_t)rel * (N_NODES + 1) + node] = excl;
    if (node < N_NODES) {
        int c = c0; if (c < 1) c = 1;
        scales[(size_t)arr * N_NODES + node] = 1.0f / sqrtf((float)c);
    }
    cnt[t] = 0;   // reuse as per-row cursor
    __syncthreads();
    int* cl = col + (size_t)rel * E_EDGES;
    for (int i = gb + t; i < ge; i += 256) {
        unsigned p = pp[i];
        int dl = p >> 16;
        int slot = rowbase[dl] + atomicAdd(&cnt[dl], 1);
        cl[slot] = (int)(p & 0xFFFFu);
    }
}

// ------------------------------------------------- T = (X .* s[:,None]) @ W
// X [nrows,128], W [128,NCOL], T [nrows,NCOL].  f32 only (no fp32 MFMA on CDNA4).
// 64-row tile, register blocking: each thread RPT rows x 4 cols.
#define XS_LD 132   // padded row stride (floats): keeps float4 alignment, breaks 4-way bank conflict
template <int NCOL>
__global__ __launch_bounds__(256) void gemm_xw(const float* __restrict__ X,
                                               const float* __restrict__ sc,
                                               const float* __restrict__ W,
                                               float* __restrict__ T, int nrows) {
    constexpr int CG  = NCOL / 4;    // float4 col-groups: 32 or 16
    constexpr int RT  = 256 / CG;    // row-threads: 8 or 16
    constexpr int RPT = 64 / RT;     // rows per thread: 8 or 4
    __shared__ float Ws[32 * NCOL];  // 32-row k-slice of W (16KB / 8KB)
    __shared__ float xs[64 * XS_LD]; // 64 scaled X rows (33KB)
    int row0 = blockIdx.x * 64;
    int cg = threadIdx.x % CG;
    int rt = threadIdx.x / CG;
    int rbase = rt * RPT;
    // stage scaled X rows
    for (int i = threadIdx.x; i < 64 * 32; i += 256) {
        int r = i >> 5, c = i & 31;
        int gr = row0 + r;
        float4 v = make_float4(0.f, 0.f, 0.f, 0.f);
        float s = 0.f;
        if (gr < nrows) {
            v = ((const float4*)(X + (size_t)gr * 128))[c];
            s = sc[gr];
        }
        v.x *= s; v.y *= s; v.z *= s; v.w *= s;
        *(float4*)(xs + r * XS_LD + c * 4) = v;
    }
    float4 acc[RPT];
#pragma unroll
    for (int i = 0; i < RPT; i++) acc[i] = make_float4(0.f, 0.f, 0.f, 0.f);
    for (int kb = 0; kb < 128; kb += 32) {
        __syncthreads();   // xs ready / previous Ws slice no longer in use
        for (int i = threadIdx.x; i < 32 * CG; i += 256)
            ((float4*)Ws)[i] = ((const float4*)W)[kb * CG + i];
        __syncthreads();
#pragma unroll
        for (int kk = 0; kk < 32; kk += 4) {
            float4 w0 = ((const float4*)Ws)[(kk + 0) * CG + cg];
            float4 w1 = ((const float4*)Ws)[(kk + 1) * CG + cg];
            float4 w2 = ((const float4*)Ws)[(kk + 2) * CG + cg];
            float4 w3 = ((const float4*)Ws)[(kk + 3) * CG + cg];
#pragma unroll
            for (int i = 0; i < RPT; i++) {
                float4 xq = *(const float4*)(xs + (rbase + i) * XS_LD + kb + kk);
                acc[i].x = fmaf(xq.x, w0.x, acc[i].x);
                acc[i].y = fmaf(xq.x, w0.y, acc[i].y);
                acc[i].z = fmaf(xq.x, w0.z, acc[i].z);
                acc[i].w = fmaf(xq.x, w0.w, acc[i].w);
                acc[i].x = fmaf(xq.y, w1.x, acc[i].x);
                acc[i].y = fmaf(xq.y, w1.y, acc[i].y);
                acc[i].z = fmaf(xq.y, w1.z, acc[i].z);
                acc[i].w = fmaf(xq.y, w1.w, acc[i].w);
                acc[i].x = fmaf(xq.z, w2.x, acc[i].x);
                acc[i].y = fmaf(xq.z, w2.y, acc[i].y);
                acc[i].z = fmaf(xq.z, w2.z, acc[i].z);
                acc[i].w = fmaf(xq.z, w2.w, acc[i].w);
                acc[i].x = fmaf(xq.w, w3.x, acc[i].x);
                acc[i].y = fmaf(xq.w, w3.y, acc[i].y);
                acc[i].z = fmaf(xq.w, w3.z, acc[i].z);
                acc[i].w = fmaf(xq.w, w3.w, acc[i].w);
            }
        }
    }
#pragma unroll
    for (int i = 0; i < RPT; i++) {
        int gr = row0 + rbase + i;
        if (gr < nrows) ((float4*)(T + (size_t)gr * NCOL))[cg] = acc[i];
    }
}

// ------------------------------------------------------------- CSR SpMM
// out[row,:] = (sum_{e in row} T[col[e],:]) * s_in[row] + bias  (+prev) (relu)
template <int DIM, bool ACCUM, bool RELU>
__global__ __launch_bounds__(256) void spmm(const int* __restrict__ rp,
                                            const int* __restrict__ col,
                                            const float* __restrict__ T,
                                            const float* __restrict__ s_in,
                                            const float* __restrict__ bias,
                                            float* __restrict__ outp, int nrows) {
    int wave = (blockIdx.x * blockDim.x + threadIdx.x) >> 6;
    int lane = threadIdx.x & 63;
    int nw = (gridDim.x * blockDim.x) >> 6;
    for (int row = wave; row < nrows; row += nw) {
        int beg = rp[row], end = rp[row + 1];
        float ax = 0.f, ay = 0.f;
        int e = beg;
        for (; e + 4 <= end; e += 4) {
            int c0 = col[e], c1 = col[e + 1], c2 = col[e + 2], c3 = col[e + 3];
            if constexpr (DIM == 128) {
                float2 v0 = *(const float2*)(T + (size_t)c0 * 128 + 2 * lane);
                float2 v1 = *(const float2*)(T + (size_t)c1 * 128 + 2 * lane);
                float2 v2 = *(const float2*)(T + (size_t)c2 * 128 + 2 * lane);
                float2 v3 = *(const float2*)(T + (size_t)c3 * 128 + 2 * lane);
                ax += (v0.x + v1.x) + (v2.x + v3.x);
                ay += (v0.y + v1.y) + (v2.y + v3.y);
            } else {
                float v0 = T[(size_t)c0 * 64 + lane];
                float v1 = T[(size_t)c1 * 64 + lane];
                float v2 = T[(size_t)c2 * 64 + lane];
                float v3 = T[(size_t)c3 * 64 + lane];
                ax += (v0 + v1) + (v2 + v3);
            }
        }
        for (; e < end; e++) {
            int c = col[e];
            if constexpr (DIM == 128) {
                float2 v = *(const float2*)(T + (size_t)c * 128 + 2 * lane);
                ax += v.x; ay += v.y;
            } else {
                ax += T[(size_t)c * 64 + lane];
            }
        }
        float s = s_in[row];
        if constexpr (DIM == 128) {
            float* po = outp + (size_t)row * 128 + 2 * lane;
            float ox = fmaf(ax, s, bias[2 * lane]);
            float oy = fmaf(ay, s, bias[2 * lane + 1]);
            if constexpr (ACCUM) { ox += po[0]; oy += po[1]; }
            if constexpr (RELU) { ox = fmaxf(ox, 0.f); oy = fmaxf(oy, 0.f); }
            po[0] = ox; po[1] = oy;
        } else {
            float* po = outp + (size_t)row * 64 + lane;
            float ox = fmaf(ax, s, bias[lane]);
            if constexpr (ACCUM) ox += po[0];
            if constexpr (RELU) ox = fmaxf(ox, 0.f);
            po[0] = ox;
        }
    }
}

// ---------------------------------------------------------------- scoring
// 16-lane groups, float4 loads: 4 edges per wave.
__global__ __launch_bounds__(256) void score_kernel(const float* __restrict__ oA,
                                                    const float* __restrict__ oB,
                                                    const int* __restrict__ src,
                                                    const int* __restrict__ dst,
                                                    float* __restrict__ out, int n) {
    int g = (blockIdx.x * blockDim.x + threadIdx.x) >> 4;
    int l = threadIdx.x & 15;
    int ng = (gridDim.x * blockDim.x) >> 4;
    for (int e = g; e < n; e += ng) {
        int s = src[e], d = dst[e];
        float4 a = *(const float4*)(oA + (size_t)s * 64 + 4 * l);
        float4 b = *(const float4*)(oB + (size_t)d * 64 + 4 * l);
        float p = a.x * b.x + a.y * b.y + a.z * b.z + a.w * b.w;
        p += __shfl_xor(p, 8);
        p += __shfl_xor(p, 4);
        p += __shfl_xor(p, 2);
        p += __shfl_xor(p, 1);
        if (l == 0) out[e] = p;
    }
}

// ---------------------------------------------------------------------------
extern "C" void kernel_launch(void* const* d_in, const int* in_sizes, int n_in,
                              void* d_out, int out_size, void* d_ws, size_t ws_size,
                              hipStream_t stream) {
    const float* feat_A     = (const float*)d_in[0];
    const float* feat_B     = (const float*)d_in[1];
    const int* rates_src    = (const int*)d_in[2];
    const int* rates_dst    = (const int*)d_in[3];
    const int* ratedby_src  = (const int*)d_in[4];
    const int* ratedby_dst  = (const int*)d_in[5];
    const int* follows_src  = (const int*)d_in[6];
    const int* follows_dst  = (const int*)d_in[7];
    const int* neg_src      = (const int*)d_in[8];
    const int* neg_dst      = (const int*)d_in[9];
    const float* W1_rates   = (const float*)d_in[10];
    const float* b1_rates   = (const float*)d_in[11];
    const float* W1_ratedby = (const float*)d_in[12];
    const float* b1_ratedby = (const float*)d_in[13];
    const float* W1_follows = (const float*)d_in[14];
    const float* b1_follows = (const float*)d_in[15];
    const float* W2_rates   = (const float*)d_in[16];
    const float* b2_rates   = (const float*)d_in[17];
    const float* W2_ratedby = (const float*)d_in[18];
    const float* b2_ratedby = (const float*)d_in[19];
    const float* W2_follows = (const float*)d_in[20];
    const float* b2_follows = (const float*)d_in[21];

    const int N = N_NODES, E = E_EDGES;

    char* ws = (char*)d_ws;
    size_t off = 0;
    auto alloc = [&](size_t bytes) -> void* {
        void* p = ws + off;
        off += (bytes + 255) & ~(size_t)255;
        return p;
    };
    float* scales = (float*)alloc((size_t)6 * N * 4);
    int* row_ptr  = (int*)alloc((size_t)3 * (N + 1) * 4);
    int* bhist    = (int*)alloc((size_t)6 * NBUCK * 4);
    int* gbase    = (int*)alloc((size_t)6 * (NBUCK + 1) * 4);
    int* gcur     = (int*)alloc((size_t)6 * NBUCK * 4);
    int* col      = (int*)alloc((size_t)3 * E * 4);
    float* T      = (float*)alloc((size_t)N * 128 * 4);
    float* hA     = (float*)alloc((size_t)N * 128 * 4);
    float* hB     = (float*)alloc((size_t)N * 128 * 4);
    float* oA     = (float*)alloc((size_t)N * 64 * 4);
    float* oB     = (float*)alloc((size_t)N * 64 * 4);
    (void)ws_size;
    // pairs (12MB) + sbytes (3MB) alias T (25.6MB): all build kernels complete
    // before the first gemm writes T (stream-ordered).
    unsigned* pairs = (unsigned*)T;
    unsigned char* sbytes = (unsigned char*)(pairs + (size_t)3 * E);

    hipMemsetAsync(bhist, 0, (size_t)6 * NBUCK * 4, stream);
    bucket_hist<<<dim3(256, 6), 256, 0, stream>>>(rates_src, rates_dst, ratedby_src,
                                                  ratedby_dst, follows_src, follows_dst,
                                                  bhist);
    bucket_scan2<<<6, 64, 0, stream>>>(bhist, gbase, gcur);
    binP<<<dim3(256, 3), 256, 0, stream>>>(rates_src, rates_dst, ratedby_src,
                                           ratedby_dst, follows_src, follows_dst,
                                           gcur, pairs);
    binS<<<dim3(256, 3), 256, 0, stream>>>(rates_src, ratedby_src, follows_src,
                                           gcur, sbytes);
    countS<<<dim3(NBUCK, 3), 256, 0, stream>>>(sbytes, gbase, scales);
    fillB2<<<dim3(NBUCK, 3), 256, 0, stream>>>(pairs, gbase, row_ptr, scales, col);

    const int* rp0 = row_ptr;                 const int* cl0 = col;
    const int* rp1 = row_ptr + (N + 1);       const int* cl1 = col + E;
    const int* rp2 = row_ptr + 2 * (N + 1);   const int* cl2 = col + 2 * (size_t)E;
    const float* s_rates_out   = scales;          // deg_out over rates_src (A)
    const float* s_rates_in    = scales + N;      // deg_in  over rates_dst (B)
    const float* s_ratedby_out = scales + 2 * N;  // deg_out over ratedby_src (B)
    const float* s_ratedby_in  = scales + 3 * N;  // deg_in  over ratedby_dst (A)
    const float* s_follows_out = scales + 4 * N;  // deg_out over follows_src (A)
    const float* s_follows_in  = scales + 5 * N;  // deg_in  over follows_dst (A)

    const int GB = (N + 63) / 64;   // gemm blocks

    // ---------------- layer 1 (HID=128) ----------------
    gemm_xw<128><<<GB, 256, 0, stream>>>(feat_A, s_rates_out, W1_rates, T, N);
    spmm<128, false, true><<<(N + 3) / 4, 256, 0, stream>>>(rp0, cl0, T, s_rates_in,
                                                            b1_rates, hB, N);
    gemm_xw<128><<<GB, 256, 0, stream>>>(feat_B, s_ratedby_out, W1_ratedby, T, N);
    spmm<128, false, false><<<(N + 3) / 4, 256, 0, stream>>>(rp1, cl1, T, s_ratedby_in,
                                                             b1_ratedby, hA, N);
    gemm_xw<128><<<GB, 256, 0, stream>>>(feat_A, s_follows_out, W1_follows, T, N);
    spmm<128, true, true><<<(N + 3) / 4, 256, 0, stream>>>(rp2, cl2, T, s_follows_in,
                                                           b1_follows, hA, N);

    // ---------------- layer 2 (OUT=64) ----------------
    gemm_xw<64><<<GB, 256, 0, stream>>>(hA, s_rates_out, W2_rates, T, N);
    spmm<64, false, false><<<(N + 3) / 4, 256, 0, stream>>>(rp0, cl0, T, s_rates_in,
                                                            b2_rates, oB, N);
    gemm_xw<64><<<GB, 256, 0, stream>>>(hB, s_ratedby_out, W2_ratedby, T, N);
    spmm<64, false, false><<<(N + 3) / 4, 256, 0, stream>>>(rp1, cl1, T, s_ratedby_in,
                                                            b2_ratedby, oA, N);
    gemm_xw<64><<<GB, 256, 0, stream>>>(hA, s_follows_out, W2_follows, T, N);
    spmm<64, true, false><<<(N + 3) / 4, 256, 0, stream>>>(rp2, cl2, T, s_follows_in,
                                                           b2_follows, oA, N);

    // ---------------- scoring ----------------
    float* outp = (float*)d_out;
    score_kernel<<<8192, 256, 0, stream>>>(oA, oB, rates_src, rates_dst, outp, E);
    score_kernel<<<8192, 256, 0, stream>>>(oA, oB, neg_src, neg_dst, outp + E, E);
}

// Round 5
// 559.408 us; speedup vs baseline: 2.7922x; 1.3436x over previous
//
#include <hip/hip_runtime.h>
#include <hip/hip_fp16.h>
#include <cstddef>

#define N_NODES 50000
#define E_EDGES 1000000
#define NBUCK 196          // ceil(50000/256) node-buckets (node>>8)
#define ACHUNK 3907        // ceil(E/256) edges per binning block
// IN = 128, HID = 128, OUT = 64

// ---------------------------------------------- per-bucket histogram (coarse)
__global__ __launch_bounds__(256) void bucket_hist(const int* __restrict__ i0, const int* __restrict__ i1,
                                                   const int* __restrict__ i2, const int* __restrict__ i3,
                                                   const int* __restrict__ i4, const int* __restrict__ i5,
                                                   int* __restrict__ bhist) {
    int arr = blockIdx.y;
    const int* idx = arr == 0 ? i0 : arr == 1 ? i1 : arr == 2 ? i2
                   : arr == 3 ? i3 : arr == 4 ? i4 : i5;
    __shared__ int l[NBUCK];
    for (int b = threadIdx.x; b < NBUCK; b += 256) l[b] = 0;
    __syncthreads();
    int e0 = blockIdx.x * ACHUNK;
    int e1 = e0 + ACHUNK; if (e1 > E_EDGES) e1 = E_EDGES;
    for (int i = e0 + threadIdx.x; i < e1; i += 256)
        atomicAdd(&l[((unsigned)idx[i]) >> 8], 1);
    __syncthreads();
    for (int b = threadIdx.x; b < NBUCK; b += 256)
        if (l[b]) atomicAdd(&bhist[arr * NBUCK + b], l[b]);
}

// ------------------------------------- scan bucket counts -> gbase, gcur
__global__ void bucket_scan2(const int* __restrict__ bhist, int* __restrict__ gbase,
                             int* __restrict__ gcur) {
    int arr = blockIdx.x;   // 0..5
    if (threadIdx.x == 0) {
        int run = 0;
        for (int b = 0; b < NBUCK; b++) {
            gbase[arr * (NBUCK + 1) + b] = run;
            gcur[arr * NBUCK + b] = run;
            run += bhist[arr * NBUCK + b];
        }
        gbase[arr * (NBUCK + 1) + NBUCK] = run;
    }
}

// ---------------------- bin (dst&255)<<16 | src by dst-bucket (arrs 1,3,5)
__global__ __launch_bounds__(256) void binP(const int* __restrict__ s0, const int* __restrict__ d0,
                                            const int* __restrict__ s1, const int* __restrict__ d1,
                                            const int* __restrict__ s2, const int* __restrict__ d2,
                                            int* __restrict__ gcur, unsigned* __restrict__ pairs) {
    int rel = blockIdx.y;
    int arr = 2 * rel + 1;
    const int* src = rel == 0 ? s0 : rel == 1 ? s1 : s2;
    const int* dst = rel == 0 ? d0 : rel == 1 ? d1 : d2;
    int e0 = blockIdx.x * ACHUNK;
    int e1 = e0 + ACHUNK; if (e1 > E_EDGES) e1 = E_EDGES;
    __shared__ int lcnt[NBUCK];
    __shared__ int lbase[NBUCK];
    for (int b = threadIdx.x; b < NBUCK; b += 256) lcnt[b] = 0;
    __syncthreads();
    for (int i = e0 + threadIdx.x; i < e1; i += 256)
        atomicAdd(&lcnt[((unsigned)dst[i]) >> 8], 1);
    __syncthreads();
    for (int b = threadIdx.x; b < NBUCK; b += 256) {
        lbase[b] = lcnt[b] ? atomicAdd(&gcur[arr * NBUCK + b], lcnt[b]) : 0;
        lcnt[b] = 0;   // reuse as local cursor
    }
    __syncthreads();
    unsigned* pp = pairs + (size_t)rel * E_EDGES;
    for (int i = e0 + threadIdx.x; i < e1; i += 256) {
        int d = dst[i];
        int b = ((unsigned)d) >> 8;
        int p = lbase[b] + atomicAdd(&lcnt[b], 1);
        pp[p] = ((unsigned)(d & 255) << 16) | (unsigned)src[i];
    }
}

// ---------------------- bin src&255 bytes by src-bucket (arrs 0,2,4)
__global__ __launch_bounds__(256) void binS(const int* __restrict__ s0, const int* __restrict__ s1,
                                            const int* __restrict__ s2,
                                            int* __restrict__ gcur, unsigned char* __restrict__ sbytes) {
    int rel = blockIdx.y;
    int arr = 2 * rel;
    const int* src = rel == 0 ? s0 : rel == 1 ? s1 : s2;
    int e0 = blockIdx.x * ACHUNK;
    int e1 = e0 + ACHUNK; if (e1 > E_EDGES) e1 = E_EDGES;
    __shared__ int lcnt[NBUCK];
    __shared__ int lbase[NBUCK];
    for (int b = threadIdx.x; b < NBUCK; b += 256) lcnt[b] = 0;
    __syncthreads();
    for (int i = e0 + threadIdx.x; i < e1; i += 256)
        atomicAdd(&lcnt[((unsigned)src[i]) >> 8], 1);
    __syncthreads();
    for (int b = threadIdx.x; b < NBUCK; b += 256) {
        lbase[b] = lcnt[b] ? atomicAdd(&gcur[arr * NBUCK + b], lcnt[b]) : 0;
        lcnt[b] = 0;
    }
    __syncthreads();
    unsigned char* sb = sbytes + (size_t)rel * E_EDGES;
    for (int i = e0 + threadIdx.x; i < e1; i += 256) {
        int s = src[i];
        int b = ((unsigned)s) >> 8;
        int p = lbase[b] + atomicAdd(&lcnt[b], 1);
        sb[p] = (unsigned char)(s & 255);
    }
}

// ------------------- per-bucket src-degree count -> scales (arrs 0,2,4)
__global__ __launch_bounds__(256) void countS(const unsigned char* __restrict__ sbytes,
                                              const int* __restrict__ gbase,
                                              float* __restrict__ scales) {
    int rel = blockIdx.y, b = blockIdx.x;
    int arr = 2 * rel;
    int p0 = gbase[arr * (NBUCK + 1) + b];
    int p1 = gbase[arr * (NBUCK + 1) + b + 1];
    const unsigned char* sb = sbytes + (size_t)rel * E_EDGES;
    __shared__ int cnt[256];
    cnt[threadIdx.x] = 0;
    __syncthreads();
    for (int i = p0 + threadIdx.x; i < p1; i += 256)
        atomicAdd(&cnt[sb[i]], 1);
    __syncthreads();
    int node = b * 256 + threadIdx.x;
    if (node < N_NODES) {
        int c = cnt[threadIdx.x];
        if (c < 1) c = 1;
        scales[(size_t)arr * N_NODES + node] = 1.0f / sqrtf((float)c);
    }
}

// ---- per-bucket: dst counts -> row_ptr + dst scales + CSR col scatter (LDS cursors)
__global__ __launch_bounds__(256) void fillB2(const unsigned* __restrict__ pairs,
                                              const int* __restrict__ gbase,
                                              int* __restrict__ row_ptr,
                                              float* __restrict__ scales,
                                              int* __restrict__ col) {
    int rel = blockIdx.y, b = blockIdx.x;
    int arr = 2 * rel + 1;
    int gb = gbase[arr * (NBUCK + 1) + b];
    int ge = gbase[arr * (NBUCK + 1) + b + 1];
    const unsigned* pp = pairs + (size_t)rel * E_EDGES;
    __shared__ int cnt[256];
    __shared__ int rowbase[256];
    __shared__ int wsum[4];
    int t = threadIdx.x;
    cnt[t] = 0;
    __syncthreads();
    for (int i = gb + t; i < ge; i += 256)
        atomicAdd(&cnt[pp[i] >> 16], 1);
    __syncthreads();
    int lane = t & 63, wid = t >> 6;
    int c0 = cnt[t];
    int v = c0;
#pragma unroll
    for (int o = 1; o < 64; o <<= 1) {
        int u = __shfl_up(v, o);
        if (lane >= o) v += u;
    }
    if (lane == 63) wsum[wid] = v;
    __syncthreads();
    int base = gb;
    for (int w = 0; w < wid; w++) base += wsum[w];
    int excl = base + v - c0;
    rowbase[t] = excl;
    int node = b * 256 + t;
    if (node <= N_NODES)
        row_ptr[(size_t)rel * (N_NODES + 1) + node] = excl;
    if (node < N_NODES) {
        int c = c0; if (c < 1) c = 1;
        scales[(size_t)arr * N_NODES + node] = 1.0f / sqrtf((float)c);
    }
    cnt[t] = 0;   // reuse as per-row cursor
    __syncthreads();
    int* cl = col + (size_t)rel * E_EDGES;
    for (int i = gb + t; i < ge; i += 256) {
        unsigned p = pp[i];
        int dl = p >> 16;
        int slot = rowbase[dl] + atomicAdd(&cnt[dl], 1);
        cl[slot] = (int)(p & 0xFFFFu);
    }
}

// ------------------------------------------------- T = (X .* s[:,None]) @ W  (fp16 out)
#define XS_LD 132
template <int NCOL>
__global__ __launch_bounds__(256) void gemm_xw(const float* __restrict__ X,
                                               const float* __restrict__ sc,
                                               const float* __restrict__ W,
                                               __half* __restrict__ T, int nrows) {
    constexpr int CG  = NCOL / 4;    // float4 col-groups: 32 or 16
    constexpr int RT  = 256 / CG;    // row-threads: 8 or 16
    constexpr int RPT = 64 / RT;     // rows per thread: 8 or 4
    __shared__ float Ws[32 * NCOL];
    __shared__ float xs[64 * XS_LD];
    int row0 = blockIdx.x * 64;
    int cg = threadIdx.x % CG;
    int rt = threadIdx.x / CG;
    int rbase = rt * RPT;
    for (int i = threadIdx.x; i < 64 * 32; i += 256) {
        int r = i >> 5, c = i & 31;
        int gr = row0 + r;
        float4 v = make_float4(0.f, 0.f, 0.f, 0.f);
        float s = 0.f;
        if (gr < nrows) {
            v = ((const float4*)(X + (size_t)gr * 128))[c];
            s = sc[gr];
        }
        v.x *= s; v.y *= s; v.z *= s; v.w *= s;
        *(float4*)(xs + r * XS_LD + c * 4) = v;
    }
    float4 acc[RPT];
#pragma unroll
    for (int i = 0; i < RPT; i++) acc[i] = make_float4(0.f, 0.f, 0.f, 0.f);
    for (int kb = 0; kb < 128; kb += 32) {
        __syncthreads();
        for (int i = threadIdx.x; i < 32 * CG; i += 256)
            ((float4*)Ws)[i] = ((const float4*)W)[kb * CG + i];
        __syncthreads();
#pragma unroll
        for (int kk = 0; kk < 32; kk += 4) {
            float4 w0 = ((const float4*)Ws)[(kk + 0) * CG + cg];
            float4 w1 = ((const float4*)Ws)[(kk + 1) * CG + cg];
            float4 w2 = ((const float4*)Ws)[(kk + 2) * CG + cg];
            float4 w3 = ((const float4*)Ws)[(kk + 3) * CG + cg];
#pragma unroll
            for (int i = 0; i < RPT; i++) {
                float4 xq = *(const float4*)(xs + (rbase + i) * XS_LD + kb + kk);
                acc[i].x = fmaf(xq.x, w0.x, acc[i].x);
                acc[i].y = fmaf(xq.x, w0.y, acc[i].y);
                acc[i].z = fmaf(xq.x, w0.z, acc[i].z);
                acc[i].w = fmaf(xq.x, w0.w, acc[i].w);
                acc[i].x = fmaf(xq.y, w1.x, acc[i].x);
                acc[i].y = fmaf(xq.y, w1.y, acc[i].y);
                acc[i].z = fmaf(xq.y, w1.z, acc[i].z);
                acc[i].w = fmaf(xq.y, w1.w, acc[i].w);
                acc[i].x = fmaf(xq.z, w2.x, acc[i].x);
                acc[i].y = fmaf(xq.z, w2.y, acc[i].y);
                acc[i].z = fmaf(xq.z, w2.z, acc[i].z);
                acc[i].w = fmaf(xq.z, w2.w, acc[i].w);
                acc[i].x = fmaf(xq.w, w3.x, acc[i].x);
                acc[i].y = fmaf(xq.w, w3.y, acc[i].y);
                acc[i].z = fmaf(xq.w, w3.z, acc[i].z);
                acc[i].w = fmaf(xq.w, w3.w, acc[i].w);
            }
        }
    }
#pragma unroll
    for (int i = 0; i < RPT; i++) {
        int gr = row0 + rbase + i;
        if (gr < nrows) {
            union { __half2 h[2]; uint2 u; } cv;
            cv.h[0] = __floats2half2_rn(acc[i].x, acc[i].y);
            cv.h[1] = __floats2half2_rn(acc[i].z, acc[i].w);
            *(uint2*)(T + (size_t)gr * NCOL + cg * 4) = cv.u;
        }
    }
}

// -------------------------------------- SpMM DIM=128 (fp16 gather, f32 out)
template <bool ACCUM, bool RELU>
__global__ __launch_bounds__(256) void spmm128(const int* __restrict__ rp,
                                               const int* __restrict__ col,
                                               const __half* __restrict__ T,
                                               const float* __restrict__ s_in,
                                               const float* __restrict__ bias,
                                               float* __restrict__ outp, int nrows) {
    int wave = (blockIdx.x * blockDim.x + threadIdx.x) >> 6;
    int lane = threadIdx.x & 63;
    int nw = (gridDim.x * blockDim.x) >> 6;
    for (int row = wave; row < nrows; row += nw) {
        int beg = rp[row], end = rp[row + 1];
        float ax = 0.f, ay = 0.f;
        int e = beg;
        for (; e + 4 <= end; e += 4) {
            int c0 = col[e], c1 = col[e + 1], c2 = col[e + 2], c3 = col[e + 3];
            float2 v0 = __half22float2(*(const __half2*)(T + (size_t)c0 * 128 + 2 * lane));
            float2 v1 = __half22float2(*(const __half2*)(T + (size_t)c1 * 128 + 2 * lane));
            float2 v2 = __half22float2(*(const __half2*)(T + (size_t)c2 * 128 + 2 * lane));
            float2 v3 = __half22float2(*(const __half2*)(T + (size_t)c3 * 128 + 2 * lane));
            ax += (v0.x + v1.x) + (v2.x + v3.x);
            ay += (v0.y + v1.y) + (v2.y + v3.y);
        }
        for (; e < end; e++) {
            int c = col[e];
            float2 v = __half22float2(*(const __half2*)(T + (size_t)c * 128 + 2 * lane));
            ax += v.x; ay += v.y;
        }
        float s = s_in[row];
        float* po = outp + (size_t)row * 128 + 2 * lane;
        float ox = fmaf(ax, s, bias[2 * lane]);
        float oy = fmaf(ay, s, bias[2 * lane + 1]);
        if constexpr (ACCUM) { ox += po[0]; oy += po[1]; }
        if constexpr (RELU) { ox = fmaxf(ox, 0.f); oy = fmaxf(oy, 0.f); }
        po[0] = ox; po[1] = oy;
    }
}

// ------------------- SpMM DIM=64 (fp16 gather, fp16 out, 32-lane half-rows)
template <bool ACCUM>
__global__ __launch_bounds__(256) void spmm64(const int* __restrict__ rp,
                                              const int* __restrict__ col,
                                              const __half* __restrict__ T,
                                              const float* __restrict__ s_in,
                                              const float* __restrict__ bias,
                                              __half* __restrict__ outp, int nrows) {
    int g = (blockIdx.x * blockDim.x + threadIdx.x) >> 5;   // half-wave id
    int l2 = threadIdx.x & 31;
    int ng = (gridDim.x * blockDim.x) >> 5;
    for (int row = g; row < nrows; row += ng) {
        int beg = rp[row], end = rp[row + 1];
        float ax = 0.f, ay = 0.f;
        int e = beg;
        for (; e + 4 <= end; e += 4) {
            int c0 = col[e], c1 = col[e + 1], c2 = col[e + 2], c3 = col[e + 3];
            float2 v0 = __half22float2(*(const __half2*)(T + (size_t)c0 * 64 + 2 * l2));
            float2 v1 = __half22float2(*(const __half2*)(T + (size_t)c1 * 64 + 2 * l2));
            float2 v2 = __half22float2(*(const __half2*)(T + (size_t)c2 * 64 + 2 * l2));
            float2 v3 = __half22float2(*(const __half2*)(T + (size_t)c3 * 64 + 2 * l2));
            ax += (v0.x + v1.x) + (v2.x + v3.x);
            ay += (v0.y + v1.y) + (v2.y + v3.y);
        }
        for (; e < end; e++) {
            int c = col[e];
            float2 v = __half22float2(*(const __half2*)(T + (size_t)c * 64 + 2 * l2));
            ax += v.x; ay += v.y;
        }
        float s = s_in[row];
        __half2* po = (__half2*)(outp + (size_t)row * 64 + 2 * l2);
        float ox = fmaf(ax, s, bias[2 * l2]);
        float oy = fmaf(ay, s, bias[2 * l2 + 1]);
        if constexpr (ACCUM) {
            float2 prev = __half22float2(*po);
            ox += prev.x; oy += prev.y;
        }
        *po = __floats2half2_rn(ox, oy);
    }
}

// ---------------------------------------------------------------- scoring
// 16-lane groups, 4 halves (8B) per lane.
__global__ __launch_bounds__(256) void score_kernel(const __half* __restrict__ oA,
                                                    const __half* __restrict__ oB,
                                                    const int* __restrict__ src,
                                                    const int* __restrict__ dst,
                                                    float* __restrict__ out, int n) {
    int g = (blockIdx.x * blockDim.x + threadIdx.x) >> 4;
    int l = threadIdx.x & 15;
    int ng = (gridDim.x * blockDim.x) >> 4;
    for (int e = g; e < n; e += ng) {
        int s = src[e], d = dst[e];
        union { uint2 u; __half2 h[2]; } a, b;
        a.u = *(const uint2*)(oA + (size_t)s * 64 + 4 * l);
        b.u = *(const uint2*)(oB + (size_t)d * 64 + 4 * l);
        float2 a0 = __half22float2(a.h[0]), a1 = __half22float2(a.h[1]);
        float2 b0 = __half22float2(b.h[0]), b1 = __half22float2(b.h[1]);
        float p = a0.x * b0.x + a0.y * b0.y + a1.x * b1.x + a1.y * b1.y;
        p += __shfl_xor(p, 8);
        p += __shfl_xor(p, 4);
        p += __shfl_xor(p, 2);
        p += __shfl_xor(p, 1);
        if (l == 0) out[e] = p;
    }
}

// ---------------------------------------------------------------------------
extern "C" void kernel_launch(void* const* d_in, const int* in_sizes, int n_in,
                              void* d_out, int out_size, void* d_ws, size_t ws_size,
                              hipStream_t stream) {
    const float* feat_A     = (const float*)d_in[0];
    const float* feat_B     = (const float*)d_in[1];
    const int* rates_src    = (const int*)d_in[2];
    const int* rates_dst    = (const int*)d_in[3];
    const int* ratedby_src  = (const int*)d_in[4];
    const int* ratedby_dst  = (const int*)d_in[5];
    const int* follows_src  = (const int*)d_in[6];
    const int* follows_dst  = (const int*)d_in[7];
    const int* neg_src      = (const int*)d_in[8];
    const int* neg_dst      = (const int*)d_in[9];
    const float* W1_rates   = (const float*)d_in[10];
    const float* b1_rates   = (const float*)d_in[11];
    const float* W1_ratedby = (const float*)d_in[12];
    const float* b1_ratedby = (const float*)d_in[13];
    const float* W1_follows = (const float*)d_in[14];
    const float* b1_follows = (const float*)d_in[15];
    const float* W2_rates   = (const float*)d_in[16];
    const float* b2_rates   = (const float*)d_in[17];
    const float* W2_ratedby = (const float*)d_in[18];
    const float* b2_ratedby = (const float*)d_in[19];
    const float* W2_follows = (const float*)d_in[20];
    const float* b2_follows = (const float*)d_in[21];

    const int N = N_NODES, E = E_EDGES;

    char* ws = (char*)d_ws;
    size_t off = 0;
    auto alloc = [&](size_t bytes) -> void* {
        void* p = ws + off;
        off += (bytes + 255) & ~(size_t)255;
        return p;
    };
    float* scales = (float*)alloc((size_t)6 * N * 4);
    int* row_ptr  = (int*)alloc((size_t)3 * (N + 1) * 4);
    int* bhist    = (int*)alloc((size_t)6 * NBUCK * 4);
    int* gbase    = (int*)alloc((size_t)6 * (NBUCK + 1) * 4);
    int* gcur     = (int*)alloc((size_t)6 * NBUCK * 4);
    int* col      = (int*)alloc((size_t)3 * E * 4);
    __half* T     = (__half*)alloc((size_t)N * 128 * 4);   // region kept f32-sized: pairs+sbytes alias it
    float* hA     = (float*)alloc((size_t)N * 128 * 4);
    float* hB     = (float*)alloc((size_t)N * 128 * 4);
    __half* oA    = (__half*)alloc((size_t)N * 64 * 2);
    __half* oB    = (__half*)alloc((size_t)N * 64 * 2);
    (void)ws_size;
    // pairs (12MB) + sbytes (3MB) alias the T region (25.6MB): all build kernels
    // complete before the first gemm writes T (stream-ordered).
    unsigned* pairs = (unsigned*)T;
    unsigned char* sbytes = (unsigned char*)(pairs + (size_t)3 * E);

    hipMemsetAsync(bhist, 0, (size_t)6 * NBUCK * 4, stream);
    bucket_hist<<<dim3(256, 6), 256, 0, stream>>>(rates_src, rates_dst, ratedby_src,
                                                  ratedby_dst, follows_src, follows_dst,
                                                  bhist);
    bucket_scan2<<<6, 64, 0, stream>>>(bhist, gbase, gcur);
    binP<<<dim3(256, 3), 256, 0, stream>>>(rates_src, rates_dst, ratedby_src,
                                           ratedby_dst, follows_src, follows_dst,
                                           gcur, pairs);
    binS<<<dim3(256, 3), 256, 0, stream>>>(rates_src, ratedby_src, follows_src,
                                           gcur, sbytes);
    countS<<<dim3(NBUCK, 3), 256, 0, stream>>>(sbytes, gbase, scales);
    fillB2<<<dim3(NBUCK, 3), 256, 0, stream>>>(pairs, gbase, row_ptr, scales, col);

    const int* rp0 = row_ptr;                 const int* cl0 = col;
    const int* rp1 = row_ptr + (N + 1);       const int* cl1 = col + E;
    const int* rp2 = row_ptr + 2 * (N + 1);   const int* cl2 = col + 2 * (size_t)E;
    const float* s_rates_out   = scales;
    const float* s_rates_in    = scales + N;
    const float* s_ratedby_out = scales + 2 * N;
    const float* s_ratedby_in  = scales + 3 * N;
    const float* s_follows_out = scales + 4 * N;
    const float* s_follows_in  = scales + 5 * N;

    const int GB = (N + 63) / 64;   // gemm blocks

    // ---------------- layer 1 (HID=128) ----------------
    gemm_xw<128><<<GB, 256, 0, stream>>>(feat_A, s_rates_out, W1_rates, T, N);
    spmm128<false, true><<<(N + 3) / 4, 256, 0, stream>>>(rp0, cl0, T, s_rates_in,
                                                          b1_rates, hB, N);
    gemm_xw<128><<<GB, 256, 0, stream>>>(feat_B, s_ratedby_out, W1_ratedby, T, N);
    spmm128<false, false><<<(N + 3) / 4, 256, 0, stream>>>(rp1, cl1, T, s_ratedby_in,
                                                           b1_ratedby, hA, N);
    gemm_xw<128><<<GB, 256, 0, stream>>>(feat_A, s_follows_out, W1_follows, T, N);
    spmm128<true, true><<<(N + 3) / 4, 256, 0, stream>>>(rp2, cl2, T, s_follows_in,
                                                         b1_follows, hA, N);

    // ---------------- layer 2 (OUT=64) ----------------
    gemm_xw<64><<<GB, 256, 0, stream>>>(hA, s_rates_out, W2_rates, T, N);
    spmm64<false><<<(N + 7) / 8, 256, 0, stream>>>(rp0, cl0, T, s_rates_in,
                                                   b2_rates, oB, N);
    gemm_xw<64><<<GB, 256, 0, stream>>>(hB, s_ratedby_out, W2_ratedby, T, N);
    spmm64<false><<<(N + 7) / 8, 256, 0, stream>>>(rp1, cl1, T, s_ratedby_in,
                                                   b2_ratedby, oA, N);
    gemm_xw<64><<<GB, 256, 0, stream>>>(hA, s_follows_out, W2_follows, T, N);
    spmm64<true><<<(N + 7) / 8, 256, 0, stream>>>(rp2, cl2, T, s_follows_in,
                                                  b2_follows, oA, N);

    // ---------------- scoring ----------------
    float* outp = (float*)d_out;
    score_kernel<<<8192, 256, 0, stream>>>(oA, oB, rates_src, rates_dst, outp, E);
    score_kernel<<<8192, 256, 0, stream>>>(oA, oB, neg_src, neg_dst, outp + E, E);
}

// Round 6
// 528.197 us; speedup vs baseline: 2.9572x; 1.0591x over previous
//
#include <hip/hip_runtime.h>
#include <hip/hip_fp16.h>
#include <cstddef>
#include <type_traits>

#define N_NODES 50000
#define E_EDGES 1000000
#define NBUCK 196          // ceil(50000/256) node-buckets (node>>8)
#define ACHUNK 3907        // ceil(E/256) edges per binning block
// IN = 128, HID = 128, OUT = 64

// ---------------------------------------------- per-bucket histogram (coarse)
__global__ __launch_bounds__(256) void bucket_hist(const int* __restrict__ i0, const int* __restrict__ i1,
                                                   const int* __restrict__ i2, const int* __restrict__ i3,
                                                   const int* __restrict__ i4, const int* __restrict__ i5,
                                                   int* __restrict__ bhist) {
    int arr = blockIdx.y;
    const int* idx = arr == 0 ? i0 : arr == 1 ? i1 : arr == 2 ? i2
                   : arr == 3 ? i3 : arr == 4 ? i4 : i5;
    __shared__ int l[NBUCK];
    for (int b = threadIdx.x; b < NBUCK; b += 256) l[b] = 0;
    __syncthreads();
    int e0 = blockIdx.x * ACHUNK;
    int e1 = e0 + ACHUNK; if (e1 > E_EDGES) e1 = E_EDGES;
    for (int i = e0 + threadIdx.x; i < e1; i += 256)
        atomicAdd(&l[((unsigned)idx[i]) >> 8], 1);
    __syncthreads();
    for (int b = threadIdx.x; b < NBUCK; b += 256)
        if (l[b]) atomicAdd(&bhist[arr * NBUCK + b], l[b]);
}

// ------------------------------------- scan bucket counts -> gbase, gcur
__global__ void bucket_scan2(const int* __restrict__ bhist, int* __restrict__ gbase,
                             int* __restrict__ gcur) {
    int arr = blockIdx.x;   // 0..5
    if (threadIdx.x == 0) {
        int run = 0;
        for (int b = 0; b < NBUCK; b++) {
            gbase[arr * (NBUCK + 1) + b] = run;
            gcur[arr * NBUCK + b] = run;
            run += bhist[arr * NBUCK + b];
        }
        gbase[arr * (NBUCK + 1) + NBUCK] = run;
    }
}

// ---------------------- bin (dst&255)<<16 | src by dst-bucket (arrs 1,3,5)
__global__ __launch_bounds__(256) void binP(const int* __restrict__ s0, const int* __restrict__ d0,
                                            const int* __restrict__ s1, const int* __restrict__ d1,
                                            const int* __restrict__ s2, const int* __restrict__ d2,
                                            int* __restrict__ gcur, unsigned* __restrict__ pairs) {
    int rel = blockIdx.y;
    int arr = 2 * rel + 1;
    const int* src = rel == 0 ? s0 : rel == 1 ? s1 : s2;
    const int* dst = rel == 0 ? d0 : rel == 1 ? d1 : d2;
    int e0 = blockIdx.x * ACHUNK;
    int e1 = e0 + ACHUNK; if (e1 > E_EDGES) e1 = E_EDGES;
    __shared__ int lcnt[NBUCK];
    __shared__ int lbase[NBUCK];
    for (int b = threadIdx.x; b < NBUCK; b += 256) lcnt[b] = 0;
    __syncthreads();
    for (int i = e0 + threadIdx.x; i < e1; i += 256)
        atomicAdd(&lcnt[((unsigned)dst[i]) >> 8], 1);
    __syncthreads();
    for (int b = threadIdx.x; b < NBUCK; b += 256) {
        lbase[b] = lcnt[b] ? atomicAdd(&gcur[arr * NBUCK + b], lcnt[b]) : 0;
        lcnt[b] = 0;   // reuse as local cursor
    }
    __syncthreads();
    unsigned* pp = pairs + (size_t)rel * E_EDGES;
    for (int i = e0 + threadIdx.x; i < e1; i += 256) {
        int d = dst[i];
        int b = ((unsigned)d) >> 8;
        int p = lbase[b] + atomicAdd(&lcnt[b], 1);
        pp[p] = ((unsigned)(d & 255) << 16) | (unsigned)src[i];
    }
}

// ---------------------- bin src&255 bytes by src-bucket (arrs 0,2,4)
__global__ __launch_bounds__(256) void binS(const int* __restrict__ s0, const int* __restrict__ s1,
                                            const int* __restrict__ s2,
                                            int* __restrict__ gcur, unsigned char* __restrict__ sbytes) {
    int rel = blockIdx.y;
    int arr = 2 * rel;
    const int* src = rel == 0 ? s0 : rel == 1 ? s1 : s2;
    int e0 = blockIdx.x * ACHUNK;
    int e1 = e0 + ACHUNK; if (e1 > E_EDGES) e1 = E_EDGES;
    __shared__ int lcnt[NBUCK];
    __shared__ int lbase[NBUCK];
    for (int b = threadIdx.x; b < NBUCK; b += 256) lcnt[b] = 0;
    __syncthreads();
    for (int i = e0 + threadIdx.x; i < e1; i += 256)
        atomicAdd(&lcnt[((unsigned)src[i]) >> 8], 1);
    __syncthreads();
    for (int b = threadIdx.x; b < NBUCK; b += 256) {
        lbase[b] = lcnt[b] ? atomicAdd(&gcur[arr * NBUCK + b], lcnt[b]) : 0;
        lcnt[b] = 0;
    }
    __syncthreads();
    unsigned char* sb = sbytes + (size_t)rel * E_EDGES;
    for (int i = e0 + threadIdx.x; i < e1; i += 256) {
        int s = src[i];
        int b = ((unsigned)s) >> 8;
        int p = lbase[b] + atomicAdd(&lcnt[b], 1);
        sb[p] = (unsigned char)(s & 255);
    }
}

// ------------------- per-bucket src-degree count -> scales (arrs 0,2,4)
__global__ __launch_bounds__(256) void countS(const unsigned char* __restrict__ sbytes,
                                              const int* __restrict__ gbase,
                                              float* __restrict__ scales) {
    int rel = blockIdx.y, b = blockIdx.x;
    int arr = 2 * rel;
    int p0 = gbase[arr * (NBUCK + 1) + b];
    int p1 = gbase[arr * (NBUCK + 1) + b + 1];
    const unsigned char* sb = sbytes + (size_t)rel * E_EDGES;
    __shared__ int cnt[256];
    cnt[threadIdx.x] = 0;
    __syncthreads();
    for (int i = p0 + threadIdx.x; i < p1; i += 256)
        atomicAdd(&cnt[sb[i]], 1);
    __syncthreads();
    int node = b * 256 + threadIdx.x;
    if (node < N_NODES) {
        int c = cnt[threadIdx.x];
        if (c < 1) c = 1;
        scales[(size_t)arr * N_NODES + node] = 1.0f / sqrtf((float)c);
    }
}

// ---- per-bucket: dst counts -> row_ptr + dst scales + CSR col scatter (LDS cursors)
__global__ __launch_bounds__(256) void fillB2(const unsigned* __restrict__ pairs,
                                              const int* __restrict__ gbase,
                                              int* __restrict__ row_ptr,
                                              float* __restrict__ scales,
                                              int* __restrict__ col) {
    int rel = blockIdx.y, b = blockIdx.x;
    int arr = 2 * rel + 1;
    int gb = gbase[arr * (NBUCK + 1) + b];
    int ge = gbase[arr * (NBUCK + 1) + b + 1];
    const unsigned* pp = pairs + (size_t)rel * E_EDGES;
    __shared__ int cnt[256];
    __shared__ int rowbase[256];
    __shared__ int wsum[4];
    int t = threadIdx.x;
    cnt[t] = 0;
    __syncthreads();
    for (int i = gb + t; i < ge; i += 256)
        atomicAdd(&cnt[pp[i] >> 16], 1);
    __syncthreads();
    int lane = t & 63, wid = t >> 6;
    int c0 = cnt[t];
    int v = c0;
#pragma unroll
    for (int o = 1; o < 64; o <<= 1) {
        int u = __shfl_up(v, o);
        if (lane >= o) v += u;
    }
    if (lane == 63) wsum[wid] = v;
    __syncthreads();
    int base = gb;
    for (int w = 0; w < wid; w++) base += wsum[w];
    int excl = base + v - c0;
    rowbase[t] = excl;
    int node = b * 256 + t;
    if (node <= N_NODES)
        row_ptr[(size_t)rel * (N_NODES + 1) + node] = excl;
    if (node < N_NODES) {
        int c = c0; if (c < 1) c = 1;
        scales[(size_t)arr * N_NODES + node] = 1.0f / sqrtf((float)c);
    }
    cnt[t] = 0;   // reuse as per-row cursor
    __syncthreads();
    int* cl = col + (size_t)rel * E_EDGES;
    for (int i = gb + t; i < ge; i += 256) {
        unsigned p = pp[i];
        int dl = p >> 16;
        int slot = rowbase[dl] + atomicAdd(&cnt[dl], 1);
        cl[slot] = (int)(p & 0xFFFFu);
    }
}

// ------------------------------------------------- T = (X .* s[:,None]) @ W  (fp16 out)
// X row stride = 128 elements (f32 or fp16), W [128,NCOL] f32.
#define XS_LD 132
template <int NCOL, typename XT>
__global__ __launch_bounds__(256) void gemm_xw(const XT* __restrict__ X,
                                               const float* __restrict__ sc,
                                               const float* __restrict__ W,
                                               __half* __restrict__ T, int nrows) {
    constexpr int CG  = NCOL / 4;    // float4 col-groups: 32 or 16
    constexpr int RT  = 256 / CG;    // row-threads: 8 or 16
    constexpr int RPT = 64 / RT;     // rows per thread: 8 or 4
    __shared__ float Ws[32 * NCOL];
    __shared__ float xs[64 * XS_LD];
    int row0 = blockIdx.x * 64;
    int cg = threadIdx.x % CG;
    int rt = threadIdx.x / CG;
    int rbase = rt * RPT;
    for (int i = threadIdx.x; i < 64 * 32; i += 256) {
        int r = i >> 5, c = i & 31;
        int gr = row0 + r;
        float4 v = make_float4(0.f, 0.f, 0.f, 0.f);
        float s = 0.f;
        if (gr < nrows) {
            if constexpr (std::is_same<XT, float>::value) {
                v = ((const float4*)(X + (size_t)gr * 128))[c];
            } else {
                union { uint2 u; __half2 h[2]; } tu;
                tu.u = ((const uint2*)(X + (size_t)gr * 128))[c];
                float2 f0 = __half22float2(tu.h[0]), f1 = __half22float2(tu.h[1]);
                v = make_float4(f0.x, f0.y, f1.x, f1.y);
            }
            s = sc[gr];
        }
        v.x *= s; v.y *= s; v.z *= s; v.w *= s;
        *(float4*)(xs + r * XS_LD + c * 4) = v;
    }
    float4 acc[RPT];
#pragma unroll
    for (int i = 0; i < RPT; i++) acc[i] = make_float4(0.f, 0.f, 0.f, 0.f);
    for (int kb = 0; kb < 128; kb += 32) {
        __syncthreads();
        for (int i = threadIdx.x; i < 32 * CG; i += 256)
            ((float4*)Ws)[i] = ((const float4*)W)[kb * CG + i];
        __syncthreads();
#pragma unroll
        for (int kk = 0; kk < 32; kk += 4) {
            float4 w0 = ((const float4*)Ws)[(kk + 0) * CG + cg];
            float4 w1 = ((const float4*)Ws)[(kk + 1) * CG + cg];
            float4 w2 = ((const float4*)Ws)[(kk + 2) * CG + cg];
            float4 w3 = ((const float4*)Ws)[(kk + 3) * CG + cg];
#pragma unroll
            for (int i = 0; i < RPT; i++) {
                float4 xq = *(const float4*)(xs + (rbase + i) * XS_LD + kb + kk);
                acc[i].x = fmaf(xq.x, w0.x, acc[i].x);
                acc[i].y = fmaf(xq.x, w0.y, acc[i].y);
                acc[i].z = fmaf(xq.x, w0.z, acc[i].z);
                acc[i].w = fmaf(xq.x, w0.w, acc[i].w);
                acc[i].x = fmaf(xq.y, w1.x, acc[i].x);
                acc[i].y = fmaf(xq.y, w1.y, acc[i].y);
                acc[i].z = fmaf(xq.y, w1.z, acc[i].z);
                acc[i].w = fmaf(xq.y, w1.w, acc[i].w);
                acc[i].x = fmaf(xq.z, w2.x, acc[i].x);
                acc[i].y = fmaf(xq.z, w2.y, acc[i].y);
                acc[i].z = fmaf(xq.z, w2.z, acc[i].z);
                acc[i].w = fmaf(xq.z, w2.w, acc[i].w);
                acc[i].x = fmaf(xq.w, w3.x, acc[i].x);
                acc[i].y = fmaf(xq.w, w3.y, acc[i].y);
                acc[i].z = fmaf(xq.w, w3.z, acc[i].z);
                acc[i].w = fmaf(xq.w, w3.w, acc[i].w);
            }
        }
    }
#pragma unroll
    for (int i = 0; i < RPT; i++) {
        int gr = row0 + rbase + i;
        if (gr < nrows) {
            union { __half2 h[2]; uint2 u; } cv;
            cv.h[0] = __floats2half2_rn(acc[i].x, acc[i].y);
            cv.h[1] = __floats2half2_rn(acc[i].z, acc[i].w);
            *(uint2*)(T + (size_t)gr * NCOL + cg * 4) = cv.u;
        }
    }
}

// -------------------------------------- SpMM DIM=128 (fp16 gather, fp16 out)
// Two adjacent rows per wave, interleaved 4+4 gathers for 8 outstanding loads.
template <bool ACCUM, bool RELU>
__global__ __launch_bounds__(256) void spmm128(const int* __restrict__ rp,
                                               const int* __restrict__ col,
                                               const __half* __restrict__ T,
                                               const float* __restrict__ s_in,
                                               const float* __restrict__ bias,
                                               __half* __restrict__ outp, int nrows) {
    int wave = (blockIdx.x * blockDim.x + threadIdx.x) >> 6;
    int lane = threadIdx.x & 63;
    int rowA = wave * 2, rowB = rowA + 1;
    if (rowA >= nrows) return;
    const char* Tb = (const char*)T;
    unsigned loff = (unsigned)lane << 2;   // half2 per lane
#define LD128(c) __half22float2(*(const __half2*)(Tb + (((unsigned)(c) << 8) + loff)))
    int begA = rp[rowA], endA = rp[rowA + 1];
    int eB = endA, endB = (rowB < nrows) ? rp[rowB + 1] : endA;  // contiguous CSR
    float axA = 0.f, ayA = 0.f, axB = 0.f, ayB = 0.f;
    int eA = begA;
    while (eA + 4 <= endA && eB + 4 <= endB) {
        int a0 = col[eA], a1 = col[eA+1], a2 = col[eA+2], a3 = col[eA+3];
        int b0 = col[eB], b1 = col[eB+1], b2 = col[eB+2], b3 = col[eB+3];
        float2 va0 = LD128(a0), va1 = LD128(a1), va2 = LD128(a2), va3 = LD128(a3);
        float2 vb0 = LD128(b0), vb1 = LD128(b1), vb2 = LD128(b2), vb3 = LD128(b3);
        axA += (va0.x + va1.x) + (va2.x + va3.x);
        ayA += (va0.y + va1.y) + (va2.y + va3.y);
        axB += (vb0.x + vb1.x) + (vb2.x + vb3.x);
        ayB += (vb0.y + vb1.y) + (vb2.y + vb3.y);
        eA += 4; eB += 4;
    }
    while (eA + 4 <= endA) {
        int a0 = col[eA], a1 = col[eA+1], a2 = col[eA+2], a3 = col[eA+3];
        float2 va0 = LD128(a0), va1 = LD128(a1), va2 = LD128(a2), va3 = LD128(a3);
        axA += (va0.x + va1.x) + (va2.x + va3.x);
        ayA += (va0.y + va1.y) + (va2.y + va3.y);
        eA += 4;
    }
    while (eB + 4 <= endB) {
        int b0 = col[eB], b1 = col[eB+1], b2 = col[eB+2], b3 = col[eB+3];
        float2 vb0 = LD128(b0), vb1 = LD128(b1), vb2 = LD128(b2), vb3 = LD128(b3);
        axB += (vb0.x + vb1.x) + (vb2.x + vb3.x);
        ayB += (vb0.y + vb1.y) + (vb2.y + vb3.y);
        eB += 4;
    }
    while (eA < endA && eB < endB) {
        float2 va = LD128(col[eA]), vb = LD128(col[eB]);
        axA += va.x; ayA += va.y; axB += vb.x; ayB += vb.y;
        eA++; eB++;
    }
    for (; eA < endA; eA++) { float2 v = LD128(col[eA]); axA += v.x; ayA += v.y; }
    for (; eB < endB; eB++) { float2 v = LD128(col[eB]); axB += v.x; ayB += v.y; }
#undef LD128
    float bx = bias[2 * lane], by = bias[2 * lane + 1];
    {
        float s = s_in[rowA];
        __half2* po = (__half2*)(outp + (size_t)rowA * 128 + 2 * lane);
        float ox = fmaf(axA, s, bx), oy = fmaf(ayA, s, by);
        if constexpr (ACCUM) { float2 p = __half22float2(*po); ox += p.x; oy += p.y; }
        if constexpr (RELU) { ox = fmaxf(ox, 0.f); oy = fmaxf(oy, 0.f); }
        *po = __floats2half2_rn(ox, oy);
    }
    if (rowB < nrows) {
        float s = s_in[rowB];
        __half2* po = (__half2*)(outp + (size_t)rowB * 128 + 2 * lane);
        float ox = fmaf(axB, s, bx), oy = fmaf(ayB, s, by);
        if constexpr (ACCUM) { float2 p = __half22float2(*po); ox += p.x; oy += p.y; }
        if constexpr (RELU) { ox = fmaxf(ox, 0.f); oy = fmaxf(oy, 0.f); }
        *po = __floats2half2_rn(ox, oy);
    }
}

// ------------------- SpMM DIM=64 (fp16 gather, fp16 out, 32-lane half-rows)
// Two adjacent rows per 32-lane group, interleaved.
template <bool ACCUM>
__global__ __launch_bounds__(256) void spmm64(const int* __restrict__ rp,
                                              const int* __restrict__ col,
                                              const __half* __restrict__ T,
                                              const float* __restrict__ s_in,
                                              const float* __restrict__ bias,
                                              __half* __restrict__ outp, int nrows) {
    int g = (blockIdx.x * blockDim.x + threadIdx.x) >> 5;
    int l2 = threadIdx.x & 31;
    int rowA = g * 2, rowB = rowA + 1;
    if (rowA >= nrows) return;
    const char* Tb = (const char*)T;
    unsigned loff = (unsigned)l2 << 2;
#define LD64(c) __half22float2(*(const __half2*)(Tb + (((unsigned)(c) << 7) + loff)))
    int begA = rp[rowA], endA = rp[rowA + 1];
    int eB = endA, endB = (rowB < nrows) ? rp[rowB + 1] : endA;
    float axA = 0.f, ayA = 0.f, axB = 0.f, ayB = 0.f;
    int eA = begA;
    while (eA + 4 <= endA && eB + 4 <= endB) {
        int a0 = col[eA], a1 = col[eA+1], a2 = col[eA+2], a3 = col[eA+3];
        int b0 = col[eB], b1 = col[eB+1], b2 = col[eB+2], b3 = col[eB+3];
        float2 va0 = LD64(a0), va1 = LD64(a1), va2 = LD64(a2), va3 = LD64(a3);
        float2 vb0 = LD64(b0), vb1 = LD64(b1), vb2 = LD64(b2), vb3 = LD64(b3);
        axA += (va0.x + va1.x) + (va2.x + va3.x);
        ayA += (va0.y + va1.y) + (va2.y + va3.y);
        axB += (vb0.x + vb1.x) + (vb2.x + vb3.x);
        ayB += (vb0.y + vb1.y) + (vb2.y + vb3.y);
        eA += 4; eB += 4;
    }
    while (eA + 4 <= endA) {
        int a0 = col[eA], a1 = col[eA+1], a2 = col[eA+2], a3 = col[eA+3];
        float2 va0 = LD64(a0), va1 = LD64(a1), va2 = LD64(a2), va3 = LD64(a3);
        axA += (va0.x + va1.x) + (va2.x + va3.x);
        ayA += (va0.y + va1.y) + (va2.y + va3.y);
        eA += 4;
    }
    while (eB + 4 <= endB) {
        int b0 = col[eB], b1 = col[eB+1], b2 = col[eB+2], b3 = col[eB+3];
        float2 vb0 = LD64(b0), vb1 = LD64(b1), vb2 = LD64(b2), vb3 = LD64(b3);
        axB += (vb0.x + vb1.x) + (vb2.x + vb3.x);
        ayB += (vb0.y + vb1.y) + (vb2.y + vb3.y);
        eB += 4;
    }
    while (eA < endA && eB < endB) {
        float2 va = LD64(col[eA]), vb = LD64(col[eB]);
        axA += va.x; ayA += va.y; axB += vb.x; ayB += vb.y;
        eA++; eB++;
    }
    for (; eA < endA; eA++) { float2 v = LD64(col[eA]); axA += v.x; ayA += v.y; }
    for (; eB < endB; eB++) { float2 v = LD64(col[eB]); axB += v.x; ayB += v.y; }
#undef LD64
    float bx = bias[2 * l2], by = bias[2 * l2 + 1];
    {
        float s = s_in[rowA];
        __half2* po = (__half2*)(outp + (size_t)rowA * 64 + 2 * l2);
        float ox = fmaf(axA, s, bx), oy = fmaf(ayA, s, by);
        if constexpr (ACCUM) { float2 p = __half22float2(*po); ox += p.x; oy += p.y; }
        *po = __floats2half2_rn(ox, oy);
    }
    if (rowB < nrows) {
        float s = s_in[rowB];
        __half2* po = (__half2*)(outp + (size_t)rowB * 64 + 2 * l2);
        float ox = fmaf(axB, s, bx), oy = fmaf(ayB, s, by);
        if constexpr (ACCUM) { float2 p = __half22float2(*po); ox += p.x; oy += p.y; }
        *po = __floats2half2_rn(ox, oy);
    }
}

// ---------------------------------------------------------------- scoring
// 16-lane groups, 2 edges per group per iteration (4 outstanding loads).
__global__ __launch_bounds__(256) void score_kernel(const __half* __restrict__ oA,
                                                    const __half* __restrict__ oB,
                                                    const int* __restrict__ src,
                                                    const int* __restrict__ dst,
                                                    float* __restrict__ out, int n) {
    int g = (blockIdx.x * blockDim.x + threadIdx.x) >> 4;
    int l = threadIdx.x & 15;
    int ng = (gridDim.x * blockDim.x) >> 4;
    const char* A = (const char*)oA;
    const char* B = (const char*)oB;
    unsigned loff = (unsigned)l << 3;   // 4 halves per lane
    for (int e0 = g * 2; e0 < n; e0 += ng * 2) {   // n even -> e0+1 < n always
        int e1 = e0 + 1;
        int s0 = src[e0], d0 = dst[e0], s1 = src[e1], d1 = dst[e1];
        union { uint2 u; __half2 h[2]; } a0, b0, a1, b1;
        a0.u = *(const uint2*)(A + (((unsigned)s0 << 7) + loff));
        b0.u = *(const uint2*)(B + (((unsigned)d0 << 7) + loff));
        a1.u = *(const uint2*)(A + (((unsigned)s1 << 7) + loff));
        b1.u = *(const uint2*)(B + (((unsigned)d1 << 7) + loff));
        float2 fa, fb;
        fa = __half22float2(a0.h[0]); fb = __half22float2(b0.h[0]);
        float p0 = fa.x * fb.x + fa.y * fb.y;
        fa = __half22float2(a0.h[1]); fb = __half22float2(b0.h[1]);
        p0 += fa.x * fb.x + fa.y * fb.y;
        fa = __half22float2(a1.h[0]); fb = __half22float2(b1.h[0]);
        float p1 = fa.x * fb.x + fa.y * fb.y;
        fa = __half22float2(a1.h[1]); fb = __half22float2(b1.h[1]);
        p1 += fa.x * fb.x + fa.y * fb.y;
        p0 += __shfl_xor(p0, 8); p1 += __shfl_xor(p1, 8);
        p0 += __shfl_xor(p0, 4); p1 += __shfl_xor(p1, 4);
        p0 += __shfl_xor(p0, 2); p1 += __shfl_xor(p1, 2);
        p0 += __shfl_xor(p0, 1); p1 += __shfl_xor(p1, 1);
        if (l == 0) { out[e0] = p0; out[e1] = p1; }
    }
}

// ---------------------------------------------------------------------------
extern "C" void kernel_launch(void* const* d_in, const int* in_sizes, int n_in,
                              void* d_out, int out_size, void* d_ws, size_t ws_size,
                              hipStream_t stream) {
    const float* feat_A     = (const float*)d_in[0];
    const float* feat_B     = (const float*)d_in[1];
    const int* rates_src    = (const int*)d_in[2];
    const int* rates_dst    = (const int*)d_in[3];
    const int* ratedby_src  = (const int*)d_in[4];
    const int* ratedby_dst  = (const int*)d_in[5];
    const int* follows_src  = (const int*)d_in[6];
    const int* follows_dst  = (const int*)d_in[7];
    const int* neg_src      = (const int*)d_in[8];
    const int* neg_dst      = (const int*)d_in[9];
    const float* W1_rates   = (const float*)d_in[10];
    const float* b1_rates   = (const float*)d_in[11];
    const float* W1_ratedby = (const float*)d_in[12];
    const float* b1_ratedby = (const float*)d_in[13];
    const float* W1_follows = (const float*)d_in[14];
    const float* b1_follows = (const float*)d_in[15];
    const float* W2_rates   = (const float*)d_in[16];
    const float* b2_rates   = (const float*)d_in[17];
    const float* W2_ratedby = (const float*)d_in[18];
    const float* b2_ratedby = (const float*)d_in[19];
    const float* W2_follows = (const float*)d_in[20];
    const float* b2_follows = (const float*)d_in[21];

    const int N = N_NODES, E = E_EDGES;

    char* ws = (char*)d_ws;
    size_t off = 0;
    auto alloc = [&](size_t bytes) -> void* {
        void* p = ws + off;
        off += (bytes + 255) & ~(size_t)255;
        return p;
    };
    float* scales = (float*)alloc((size_t)6 * N * 4);
    int* row_ptr  = (int*)alloc((size_t)3 * (N + 1) * 4);
    int* bhist    = (int*)alloc((size_t)6 * NBUCK * 4);
    int* gbase    = (int*)alloc((size_t)6 * (NBUCK + 1) * 4);
    int* gcur     = (int*)alloc((size_t)6 * NBUCK * 4);
    int* col      = (int*)alloc((size_t)3 * E * 4);
    __half* T     = (__half*)alloc((size_t)N * 128 * 4);   // f32-sized region: pairs+sbytes alias it
    __half* hA    = (__half*)alloc((size_t)N * 128 * 2);
    __half* hB    = (__half*)alloc((size_t)N * 128 * 2);
    __half* oA    = (__half*)alloc((size_t)N * 64 * 2);
    __half* oB    = (__half*)alloc((size_t)N * 64 * 2);
    (void)ws_size;
    // pairs (12MB) + sbytes (3MB) alias the T region (25.6MB): all build kernels
    // complete before the first gemm writes T (stream-ordered).
    unsigned* pairs = (unsigned*)T;
    unsigned char* sbytes = (unsigned char*)(pairs + (size_t)3 * E);

    hipMemsetAsync(bhist, 0, (size_t)6 * NBUCK * 4, stream);
    bucket_hist<<<dim3(256, 6), 256, 0, stream>>>(rates_src, rates_dst, ratedby_src,
                                                  ratedby_dst, follows_src, follows_dst,
                                                  bhist);
    bucket_scan2<<<6, 64, 0, stream>>>(bhist, gbase, gcur);
    binP<<<dim3(256, 3), 256, 0, stream>>>(rates_src, rates_dst, ratedby_src,
                                           ratedby_dst, follows_src, follows_dst,
                                           gcur, pairs);
    binS<<<dim3(256, 3), 256, 0, stream>>>(rates_src, ratedby_src, follows_src,
                                           gcur, sbytes);
    countS<<<dim3(NBUCK, 3), 256, 0, stream>>>(sbytes, gbase, scales);
    fillB2<<<dim3(NBUCK, 3), 256, 0, stream>>>(pairs, gbase, row_ptr, scales, col);

    const int* rp0 = row_ptr;                 const int* cl0 = col;
    const int* rp1 = row_ptr + (N + 1);       const int* cl1 = col + E;
    const int* rp2 = row_ptr + 2 * (N + 1);   const int* cl2 = col + 2 * (size_t)E;
    const float* s_rates_out   = scales;
    const float* s_rates_in    = scales + N;
    const float* s_ratedby_out = scales + 2 * N;
    const float* s_ratedby_in  = scales + 3 * N;
    const float* s_follows_out = scales + 4 * N;
    const float* s_follows_in  = scales + 5 * N;

    const int GB = (N + 63) / 64;           // gemm blocks
    const int SB128 = (N / 2 + 3) / 4;      // spmm128 blocks (2 rows/wave, 4 waves/block)
    const int SB64  = (N / 2 + 7) / 8;      // spmm64 blocks (2 rows/group, 8 groups/block)

    // ---------------- layer 1 (HID=128) ----------------
    gemm_xw<128, float><<<GB, 256, 0, stream>>>(feat_A, s_rates_out, W1_rates, T, N);
    spmm128<false, true><<<SB128, 256, 0, stream>>>(rp0, cl0, T, s_rates_in,
                                                    b1_rates, hB, N);
    gemm_xw<128, float><<<GB, 256, 0, stream>>>(feat_B, s_ratedby_out, W1_ratedby, T, N);
    spmm128<false, false><<<SB128, 256, 0, stream>>>(rp1, cl1, T, s_ratedby_in,
                                                     b1_ratedby, hA, N);
    gemm_xw<128, float><<<GB, 256, 0, stream>>>(feat_A, s_follows_out, W1_follows, T, N);
    spmm128<true, true><<<SB128, 256, 0, stream>>>(rp2, cl2, T, s_follows_in,
                                                   b1_follows, hA, N);

    // ---------------- layer 2 (OUT=64) ----------------
    gemm_xw<64, __half><<<GB, 256, 0, stream>>>(hA, s_rates_out, W2_rates, T, N);
    spmm64<false><<<SB64, 256, 0, stream>>>(rp0, cl0, T, s_rates_in, b2_rates, oB, N);
    gemm_xw<64, __half><<<GB, 256, 0, stream>>>(hB, s_ratedby_out, W2_ratedby, T, N);
    spmm64<false><<<SB64, 256, 0, stream>>>(rp1, cl1, T, s_ratedby_in, b2_ratedby, oA, N);
    gemm_xw<64, __half><<<GB, 256, 0, stream>>>(hA, s_follows_out, W2_follows, T, N);
    spmm64<true><<<SB64, 256, 0, stream>>>(rp2, cl2, T, s_follows_in, b2_follows, oA, N);

    // ---------------- scoring ----------------
    float* outp = (float*)d_out;
    score_kernel<<<8192, 256, 0, stream>>>(oA, oB, rates_src, rates_dst, outp, E);
    score_kernel<<<8192, 256, 0, stream>>>(oA, oB, neg_src, neg_dst, outp + E, E);
}

// Round 7
// 444.808 us; speedup vs baseline: 3.5116x; 1.1875x over previous
//
#include <hip/hip_runtime.h>
#include <hip/hip_fp16.h>
#include <cstddef>
#include <type_traits>

#define N_NODES 50000
#define E_EDGES 1000000
#define NBUCK 196          // ceil(50000/256) node-buckets (node>>8)
#define ACHUNK 3907        // ceil(E/256) edges per binning block
#define MTILES 3125        // 50000 / 16
// IN = 128, HID = 128, OUT = 64

typedef _Float16 f16x8 __attribute__((ext_vector_type(8)));
typedef float f32x4 __attribute__((ext_vector_type(4)));

// ---------------------------------------------- per-bucket histogram (coarse)
__global__ __launch_bounds__(256) void bucket_hist(const int* __restrict__ i0, const int* __restrict__ i1,
                                                   const int* __restrict__ i2, const int* __restrict__ i3,
                                                   const int* __restrict__ i4, const int* __restrict__ i5,
                                                   int* __restrict__ bhist) {
    int arr = blockIdx.y;
    const int* idx = arr == 0 ? i0 : arr == 1 ? i1 : arr == 2 ? i2
                   : arr == 3 ? i3 : arr == 4 ? i4 : i5;
    __shared__ int l[NBUCK];
    for (int b = threadIdx.x; b < NBUCK; b += 256) l[b] = 0;
    __syncthreads();
    int e0 = blockIdx.x * ACHUNK;
    int e1 = e0 + ACHUNK; if (e1 > E_EDGES) e1 = E_EDGES;
    for (int i = e0 + threadIdx.x; i < e1; i += 256)
        atomicAdd(&l[((unsigned)idx[i]) >> 8], 1);
    __syncthreads();
    for (int b = threadIdx.x; b < NBUCK; b += 256)
        if (l[b]) atomicAdd(&bhist[arr * NBUCK + b], l[b]);
}

// ------------------------------------- scan bucket counts -> gbase, gcur
__global__ void bucket_scan2(const int* __restrict__ bhist, int* __restrict__ gbase,
                             int* __restrict__ gcur) {
    int arr = blockIdx.x;   // 0..5
    if (threadIdx.x == 0) {
        int run = 0;
        for (int b = 0; b < NBUCK; b++) {
            gbase[arr * (NBUCK + 1) + b] = run;
            gcur[arr * NBUCK + b] = run;
            run += bhist[arr * NBUCK + b];
        }
        gbase[arr * (NBUCK + 1) + NBUCK] = run;
    }
}

// ---------------------- bin (dst&255)<<16 | src by dst-bucket (arrs 1,3,5)
__global__ __launch_bounds__(256) void binP(const int* __restrict__ s0, const int* __restrict__ d0,
                                            const int* __restrict__ s1, const int* __restrict__ d1,
                                            const int* __restrict__ s2, const int* __restrict__ d2,
                                            int* __restrict__ gcur, unsigned* __restrict__ pairs) {
    int rel = blockIdx.y;
    int arr = 2 * rel + 1;
    const int* src = rel == 0 ? s0 : rel == 1 ? s1 : s2;
    const int* dst = rel == 0 ? d0 : rel == 1 ? d1 : d2;
    int e0 = blockIdx.x * ACHUNK;
    int e1 = e0 + ACHUNK; if (e1 > E_EDGES) e1 = E_EDGES;
    __shared__ int lcnt[NBUCK];
    __shared__ int lbase[NBUCK];
    for (int b = threadIdx.x; b < NBUCK; b += 256) lcnt[b] = 0;
    __syncthreads();
    for (int i = e0 + threadIdx.x; i < e1; i += 256)
        atomicAdd(&lcnt[((unsigned)dst[i]) >> 8], 1);
    __syncthreads();
    for (int b = threadIdx.x; b < NBUCK; b += 256) {
        lbase[b] = lcnt[b] ? atomicAdd(&gcur[arr * NBUCK + b], lcnt[b]) : 0;
        lcnt[b] = 0;   // reuse as local cursor
    }
    __syncthreads();
    unsigned* pp = pairs + (size_t)rel * E_EDGES;
    for (int i = e0 + threadIdx.x; i < e1; i += 256) {
        int d = dst[i];
        int b = ((unsigned)d) >> 8;
        int p = lbase[b] + atomicAdd(&lcnt[b], 1);
        pp[p] = ((unsigned)(d & 255) << 16) | (unsigned)src[i];
    }
}

// ---------------------- bin src&255 bytes by src-bucket (arrs 0,2,4)
__global__ __launch_bounds__(256) void binS(const int* __restrict__ s0, const int* __restrict__ s1,
                                            const int* __restrict__ s2,
                                            int* __restrict__ gcur, unsigned char* __restrict__ sbytes) {
    int rel = blockIdx.y;
    int arr = 2 * rel;
    const int* src = rel == 0 ? s0 : rel == 1 ? s1 : s2;
    int e0 = blockIdx.x * ACHUNK;
    int e1 = e0 + ACHUNK; if (e1 > E_EDGES) e1 = E_EDGES;
    __shared__ int lcnt[NBUCK];
    __shared__ int lbase[NBUCK];
    for (int b = threadIdx.x; b < NBUCK; b += 256) lcnt[b] = 0;
    __syncthreads();
    for (int i = e0 + threadIdx.x; i < e1; i += 256)
        atomicAdd(&lcnt[((unsigned)src[i]) >> 8], 1);
    __syncthreads();
    for (int b = threadIdx.x; b < NBUCK; b += 256) {
        lbase[b] = lcnt[b] ? atomicAdd(&gcur[arr * NBUCK + b], lcnt[b]) : 0;
        lcnt[b] = 0;
    }
    __syncthreads();
    unsigned char* sb = sbytes + (size_t)rel * E_EDGES;
    for (int i = e0 + threadIdx.x; i < e1; i += 256) {
        int s = src[i];
        int b = ((unsigned)s) >> 8;
        int p = lbase[b] + atomicAdd(&lcnt[b], 1);
        sb[p] = (unsigned char)(s & 255);
    }
}

// ------------------- per-bucket src-degree count -> scales (arrs 0,2,4)
__global__ __launch_bounds__(256) void countS(const unsigned char* __restrict__ sbytes,
                                              const int* __restrict__ gbase,
                                              float* __restrict__ scales) {
    int rel = blockIdx.y, b = blockIdx.x;
    int arr = 2 * rel;
    int p0 = gbase[arr * (NBUCK + 1) + b];
    int p1 = gbase[arr * (NBUCK + 1) + b + 1];
    const unsigned char* sb = sbytes + (size_t)rel * E_EDGES;
    __shared__ int cnt[256];
    cnt[threadIdx.x] = 0;
    __syncthreads();
    for (int i = p0 + threadIdx.x; i < p1; i += 256)
        atomicAdd(&cnt[sb[i]], 1);
    __syncthreads();
    int node = b * 256 + threadIdx.x;
    if (node < N_NODES) {
        int c = cnt[threadIdx.x];
        if (c < 1) c = 1;
        scales[(size_t)arr * N_NODES + node] = 1.0f / sqrtf((float)c);
    }
}

// ---- per-bucket: dst counts -> row_ptr + dst scales + CSR col scatter (LDS cursors)
__global__ __launch_bounds__(256) void fillB2(const unsigned* __restrict__ pairs,
                                              const int* __restrict__ gbase,
                                              int* __restrict__ row_ptr,
                                              float* __restrict__ scales,
                                              int* __restrict__ col) {
    int rel = blockIdx.y, b = blockIdx.x;
    int arr = 2 * rel + 1;
    int gb = gbase[arr * (NBUCK + 1) + b];
    int ge = gbase[arr * (NBUCK + 1) + b + 1];
    const unsigned* pp = pairs + (size_t)rel * E_EDGES;
    __shared__ int cnt[256];
    __shared__ int rowbase[256];
    __shared__ int wsum[4];
    int t = threadIdx.x;
    cnt[t] = 0;
    __syncthreads();
    for (int i = gb + t; i < ge; i += 256)
        atomicAdd(&cnt[pp[i] >> 16], 1);
    __syncthreads();
    int lane = t & 63, wid = t >> 6;
    int c0 = cnt[t];
    int v = c0;
#pragma unroll
    for (int o = 1; o < 64; o <<= 1) {
        int u = __shfl_up(v, o);
        if (lane >= o) v += u;
    }
    if (lane == 63) wsum[wid] = v;
    __syncthreads();
    int base = gb;
    for (int w = 0; w < wid; w++) base += wsum[w];
    int excl = base + v - c0;
    rowbase[t] = excl;
    int node = b * 256 + t;
    if (node <= N_NODES)
        row_ptr[(size_t)rel * (N_NODES + 1) + node] = excl;
    if (node < N_NODES) {
        int c = c0; if (c < 1) c = 1;
        scales[(size_t)arr * N_NODES + node] = 1.0f / sqrtf((float)c);
    }
    cnt[t] = 0;   // reuse as per-row cursor
    __syncthreads();
    int* cl = col + (size_t)rel * E_EDGES;
    for (int i = gb + t; i < ge; i += 256) {
        unsigned p = pp[i];
        int dl = p >> 16;
        int slot = rowbase[dl] + atomicAdd(&cnt[dl], 1);
        cl[slot] = (int)(p & 0xFFFFu);
    }
}

// ------------------- transpose+convert all 6 weight matrices to fp16 Wt[n][k]
__global__ void w_cvt6(const float* __restrict__ w0, const float* __restrict__ w1,
                       const float* __restrict__ w2, const float* __restrict__ w3,
                       const float* __restrict__ w4, const float* __restrict__ w5,
                       __half* __restrict__ t0, __half* __restrict__ t1,
                       __half* __restrict__ t2, __half* __restrict__ t3,
                       __half* __restrict__ t4, __half* __restrict__ t5) {
    int m = blockIdx.y;
    const float* W = m == 0 ? w0 : m == 1 ? w1 : m == 2 ? w2 : m == 3 ? w3 : m == 4 ? w4 : w5;
    __half* Wt = m == 0 ? t0 : m == 1 ? t1 : m == 2 ? t2 : m == 3 ? t3 : m == 4 ? t4 : t5;
    int ncol = m < 3 ? 128 : 64;
    int tot = 128 * ncol;
    for (int i = blockIdx.x * blockDim.x + threadIdx.x; i < tot; i += gridDim.x * blockDim.x) {
        int n = i >> 7, k = i & 127;          // Wt[n][k] = W[k][n]
        Wt[i] = __float2half(W[k * ncol + n]);
    }
}

// --------------------------------------------- MFMA GEMM: T = diag(s)*(X@W)
// X [50000,128] (f32 or fp16), Wt [NCOL][128] fp16, T [50000,NCOL] fp16.
// Wave = 16-row M-tile x 64-col strip. B frags register-resident, no LDS.
// A/B use the same (lane -> k-slot) bijection so the k-order is self-consistent;
// C/D layout: col = lane&15, row = (lane>>4)*4 + reg (HW-verified).
template <int NCOL, typename XT>
__global__ __launch_bounds__(256) void gemm_mfma(const XT* __restrict__ X,
                                                 const float* __restrict__ sc,
                                                 const __half* __restrict__ Wt,
                                                 __half* __restrict__ T) {
    constexpr int NHALF = NCOL / 64;        // 2 for 128, 1 for 64
    int gw = (blockIdx.x * blockDim.x + threadIdx.x) >> 6;
    int lane = threadIdx.x & 63;
    int half_id = gw % NHALF;
    int mstream = gw / NHALF;
    int nstreams = ((gridDim.x * blockDim.x) >> 6) / NHALF;
    int l15 = lane & 15, g = lane >> 4;

    // B fragments: Wt[half*64 + nt*16 + l15][kb*32 + g*8 + j]
    f16x8 b[4][4];
    {
        const __half* wb = Wt + ((size_t)half_id * 64 + l15) * 128 + g * 8;
#pragma unroll
        for (int nt = 0; nt < 4; nt++)
#pragma unroll
            for (int kb = 0; kb < 4; kb++)
                b[nt][kb] = *(const f16x8*)(wb + nt * 16 * 128 + kb * 32);
    }

    for (int mt = mstream; mt < MTILES; mt += nstreams) {
        int m0 = mt * 16;
        f16x8 a[4];
        if constexpr (std::is_same<XT, float>::value) {
            const float* xr = X + (size_t)(m0 + l15) * 128 + g * 8;
#pragma unroll
            for (int kb = 0; kb < 4; kb++) {
                float4 u = *(const float4*)(xr + kb * 32);
                float4 v = *(const float4*)(xr + kb * 32 + 4);
                f16x8 t;
                t[0] = (_Float16)u.x; t[1] = (_Float16)u.y;
                t[2] = (_Float16)u.z; t[3] = (_Float16)u.w;
                t[4] = (_Float16)v.x; t[5] = (_Float16)v.y;
                t[6] = (_Float16)v.z; t[7] = (_Float16)v.w;
                a[kb] = t;
            }
        } else {
            const _Float16* xr = (const _Float16*)X + (size_t)(m0 + l15) * 128 + g * 8;
#pragma unroll
            for (int kb = 0; kb < 4; kb++)
                a[kb] = *(const f16x8*)(xr + kb * 32);
        }
        f32x4 acc[4];
#pragma unroll
        for (int nt = 0; nt < 4; nt++) acc[nt] = (f32x4){0.f, 0.f, 0.f, 0.f};
#pragma unroll
        for (int kb = 0; kb < 4; kb++)
#pragma unroll
            for (int nt = 0; nt < 4; nt++)
                acc[nt] = __builtin_amdgcn_mfma_f32_16x16x32_f16(a[kb], b[nt][kb], acc[nt], 0, 0, 0);
        int mrow = m0 + g * 4;
#pragma unroll
        for (int j = 0; j < 4; j++) {
            float sj = sc[mrow + j];
            __half* tj = T + (size_t)(mrow + j) * NCOL + half_id * 64 + l15;
            tj[0]  = __float2half(acc[0][j] * sj);
            tj[16] = __float2half(acc[1][j] * sj);
            tj[32] = __float2half(acc[2][j] * sj);
            tj[48] = __float2half(acc[3][j] * sj);
        }
    }
}

// -------------------------------------- SpMM DIM=128 (fp16 gather, fp16 out)
template <bool ACCUM, bool RELU>
__global__ __launch_bounds__(256) void spmm128(const int* __restrict__ rp,
                                               const int* __restrict__ col,
                                               const __half* __restrict__ T,
                                               const float* __restrict__ s_in,
                                               const float* __restrict__ bias,
                                               __half* __restrict__ outp, int nrows) {
    int wave = (blockIdx.x * blockDim.x + threadIdx.x) >> 6;
    int lane = threadIdx.x & 63;
    int rowA = wave * 2, rowB = rowA + 1;
    if (rowA >= nrows) return;
    const char* Tb = (const char*)T;
    unsigned loff = (unsigned)lane << 2;   // half2 per lane
#define LD128(c) __half22float2(*(const __half2*)(Tb + (((unsigned)(c) << 8) + loff)))
    int begA = rp[rowA], endA = rp[rowA + 1];
    int eB = endA, endB = (rowB < nrows) ? rp[rowB + 1] : endA;  // contiguous CSR
    float axA = 0.f, ayA = 0.f, axB = 0.f, ayB = 0.f;
    int eA = begA;
    while (eA + 4 <= endA && eB + 4 <= endB) {
        int a0 = col[eA], a1 = col[eA+1], a2 = col[eA+2], a3 = col[eA+3];
        int b0 = col[eB], b1 = col[eB+1], b2 = col[eB+2], b3 = col[eB+3];
        float2 va0 = LD128(a0), va1 = LD128(a1), va2 = LD128(a2), va3 = LD128(a3);
        float2 vb0 = LD128(b0), vb1 = LD128(b1), vb2 = LD128(b2), vb3 = LD128(b3);
        axA += (va0.x + va1.x) + (va2.x + va3.x);
        ayA += (va0.y + va1.y) + (va2.y + va3.y);
        axB += (vb0.x + vb1.x) + (vb2.x + vb3.x);
        ayB += (vb0.y + vb1.y) + (vb2.y + vb3.y);
        eA += 4; eB += 4;
    }
    while (eA + 4 <= endA) {
        int a0 = col[eA], a1 = col[eA+1], a2 = col[eA+2], a3 = col[eA+3];
        float2 va0 = LD128(a0), va1 = LD128(a1), va2 = LD128(a2), va3 = LD128(a3);
        axA += (va0.x + va1.x) + (va2.x + va3.x);
        ayA += (va0.y + va1.y) + (va2.y + va3.y);
        eA += 4;
    }
    while (eB + 4 <= endB) {
        int b0 = col[eB], b1 = col[eB+1], b2 = col[eB+2], b3 = col[eB+3];
        float2 vb0 = LD128(b0), vb1 = LD128(b1), vb2 = LD128(b2), vb3 = LD128(b3);
        axB += (vb0.x + vb1.x) + (vb2.x + vb3.x);
        ayB += (vb0.y + vb1.y) + (vb2.y + vb3.y);
        eB += 4;
    }
    while (eA < endA && eB < endB) {
        float2 va = LD128(col[eA]), vb = LD128(col[eB]);
        axA += va.x; ayA += va.y; axB += vb.x; ayB += vb.y;
        eA++; eB++;
    }
    for (; eA < endA; eA++) { float2 v = LD128(col[eA]); axA += v.x; ayA += v.y; }
    for (; eB < endB; eB++) { float2 v = LD128(col[eB]); axB += v.x; ayB += v.y; }
#undef LD128
    float bx = bias[2 * lane], by = bias[2 * lane + 1];
    {
        float s = s_in[rowA];
        __half2* po = (__half2*)(outp + (size_t)rowA * 128 + 2 * lane);
        float ox = fmaf(axA, s, bx), oy = fmaf(ayA, s, by);
        if constexpr (ACCUM) { float2 p = __half22float2(*po); ox += p.x; oy += p.y; }
        if constexpr (RELU) { ox = fmaxf(ox, 0.f); oy = fmaxf(oy, 0.f); }
        *po = __floats2half2_rn(ox, oy);
    }
    if (rowB < nrows) {
        float s = s_in[rowB];
        __half2* po = (__half2*)(outp + (size_t)rowB * 128 + 2 * lane);
        float ox = fmaf(axB, s, bx), oy = fmaf(ayB, s, by);
        if constexpr (ACCUM) { float2 p = __half22float2(*po); ox += p.x; oy += p.y; }
        if constexpr (RELU) { ox = fmaxf(ox, 0.f); oy = fmaxf(oy, 0.f); }
        *po = __floats2half2_rn(ox, oy);
    }
}

// ------------------- SpMM DIM=64 (fp16 gather, fp16 out, 32-lane half-rows)
template <bool ACCUM>
__global__ __launch_bounds__(256) void spmm64(const int* __restrict__ rp,
                                              const int* __restrict__ col,
                                              const __half* __restrict__ T,
                                              const float* __restrict__ s_in,
                                              const float* __restrict__ bias,
                                              __half* __restrict__ outp, int nrows) {
    int g = (blockIdx.x * blockDim.x + threadIdx.x) >> 5;
    int l2 = threadIdx.x & 31;
    int rowA = g * 2, rowB = rowA + 1;
    if (rowA >= nrows) return;
    const char* Tb = (const char*)T;
    unsigned loff = (unsigned)l2 << 2;
#define LD64(c) __half22float2(*(const __half2*)(Tb + (((unsigned)(c) << 7) + loff)))
    int begA = rp[rowA], endA = rp[rowA + 1];
    int eB = endA, endB = (rowB < nrows) ? rp[rowB + 1] : endA;
    float axA = 0.f, ayA = 0.f, axB = 0.f, ayB = 0.f;
    int eA = begA;
    while (eA + 4 <= endA && eB + 4 <= endB) {
        int a0 = col[eA], a1 = col[eA+1], a2 = col[eA+2], a3 = col[eA+3];
        int b0 = col[eB], b1 = col[eB+1], b2 = col[eB+2], b3 = col[eB+3];
        float2 va0 = LD64(a0), va1 = LD64(a1), va2 = LD64(a2), va3 = LD64(a3);
        float2 vb0 = LD64(b0), vb1 = LD64(b1), vb2 = LD64(b2), vb3 = LD64(b3);
        axA += (va0.x + va1.x) + (va2.x + va3.x);
        ayA += (va0.y + va1.y) + (va2.y + va3.y);
        axB += (vb0.x + vb1.x) + (vb2.x + vb3.x);
        ayB += (vb0.y + vb1.y) + (vb2.y + vb3.y);
        eA += 4; eB += 4;
    }
    while (eA + 4 <= endA) {
        int a0 = col[eA], a1 = col[eA+1], a2 = col[eA+2], a3 = col[eA+3];
        float2 va0 = LD64(a0), va1 = LD64(a1), va2 = LD64(a2), va3 = LD64(a3);
        axA += (va0.x + va1.x) + (va2.x + va3.x);
        ayA += (va0.y + va1.y) + (va2.y + va3.y);
        eA += 4;
    }
    while (eB + 4 <= endB) {
        int b0 = col[eB], b1 = col[eB+1], b2 = col[eB+2], b3 = col[eB+3];
        float2 vb0 = LD64(b0), vb1 = LD64(b1), vb2 = LD64(b2), vb3 = LD64(b3);
        axB += (vb0.x + vb1.x) + (vb2.x + vb3.x);
        ayB += (vb0.y + vb1.y) + (vb2.y + vb3.y);
        eB += 4;
    }
    while (eA < endA && eB < endB) {
        float2 va = LD64(col[eA]), vb = LD64(col[eB]);
        axA += va.x; ayA += va.y; axB += vb.x; ayB += vb.y;
        eA++; eB++;
    }
    for (; eA < endA; eA++) { float2 v = LD64(col[eA]); axA += v.x; ayA += v.y; }
    for (; eB < endB; eB++) { float2 v = LD64(col[eB]); axB += v.x; ayB += v.y; }
#undef LD64
    float bx = bias[2 * l2], by = bias[2 * l2 + 1];
    {
        float s = s_in[rowA];
        __half2* po = (__half2*)(outp + (size_t)rowA * 64 + 2 * l2);
        float ox = fmaf(axA, s, bx), oy = fmaf(ayA, s, by);
        if constexpr (ACCUM) { float2 p = __half22float2(*po); ox += p.x; oy += p.y; }
        *po = __floats2half2_rn(ox, oy);
    }
    if (rowB < nrows) {
        float s = s_in[rowB];
        __half2* po = (__half2*)(outp + (size_t)rowB * 64 + 2 * l2);
        float ox = fmaf(axB, s, bx), oy = fmaf(ayB, s, by);
        if constexpr (ACCUM) { float2 p = __half22float2(*po); ox += p.x; oy += p.y; }
        *po = __floats2half2_rn(ox, oy);
    }
}

// ---------------------------------------------------------------- scoring
__global__ __launch_bounds__(256) void score_kernel(const __half* __restrict__ oA,
                                                    const __half* __restrict__ oB,
                                                    const int* __restrict__ src,
                                                    const int* __restrict__ dst,
                                                    float* __restrict__ out, int n) {
    int g = (blockIdx.x * blockDim.x + threadIdx.x) >> 4;
    int l = threadIdx.x & 15;
    int ng = (gridDim.x * blockDim.x) >> 4;
    const char* A = (const char*)oA;
    const char* B = (const char*)oB;
    unsigned loff = (unsigned)l << 3;   // 4 halves per lane
    for (int e0 = g * 2; e0 < n; e0 += ng * 2) {
        int e1 = e0 + 1;
        int s0 = src[e0], d0 = dst[e0], s1 = src[e1], d1 = dst[e1];
        union { uint2 u; __half2 h[2]; } a0, b0, a1, b1;
        a0.u = *(const uint2*)(A + (((unsigned)s0 << 7) + loff));
        b0.u = *(const uint2*)(B + (((unsigned)d0 << 7) + loff));
        a1.u = *(const uint2*)(A + (((unsigned)s1 << 7) + loff));
        b1.u = *(const uint2*)(B + (((unsigned)d1 << 7) + loff));
        float2 fa, fb;
        fa = __half22float2(a0.h[0]); fb = __half22float2(b0.h[0]);
        float p0 = fa.x * fb.x + fa.y * fb.y;
        fa = __half22float2(a0.h[1]); fb = __half22float2(b0.h[1]);
        p0 += fa.x * fb.x + fa.y * fb.y;
        fa = __half22float2(a1.h[0]); fb = __half22float2(b1.h[0]);
        float p1 = fa.x * fb.x + fa.y * fb.y;
        fa = __half22float2(a1.h[1]); fb = __half22float2(b1.h[1]);
        p1 += fa.x * fb.x + fa.y * fb.y;
        p0 += __shfl_xor(p0, 8); p1 += __shfl_xor(p1, 8);
        p0 += __shfl_xor(p0, 4); p1 += __shfl_xor(p1, 4);
        p0 += __shfl_xor(p0, 2); p1 += __shfl_xor(p1, 2);
        p0 += __shfl_xor(p0, 1); p1 += __shfl_xor(p1, 1);
        if (l == 0) { out[e0] = p0; out[e1] = p1; }
    }
}

// ---------------------------------------------------------------------------
extern "C" void kernel_launch(void* const* d_in, const int* in_sizes, int n_in,
                              void* d_out, int out_size, void* d_ws, size_t ws_size,
                              hipStream_t stream) {
    const float* feat_A     = (const float*)d_in[0];
    const float* feat_B     = (const float*)d_in[1];
    const int* rates_src    = (const int*)d_in[2];
    const int* rates_dst    = (const int*)d_in[3];
    const int* ratedby_src  = (const int*)d_in[4];
    const int* ratedby_dst  = (const int*)d_in[5];
    const int* follows_src  = (const int*)d_in[6];
    const int* follows_dst  = (const int*)d_in[7];
    const int* neg_src      = (const int*)d_in[8];
    const int* neg_dst      = (const int*)d_in[9];
    const float* W1_rates   = (const float*)d_in[10];
    const float* b1_rates   = (const float*)d_in[11];
    const float* W1_ratedby = (const float*)d_in[12];
    const float* b1_ratedby = (const float*)d_in[13];
    const float* W1_follows = (const float*)d_in[14];
    const float* b1_follows = (const float*)d_in[15];
    const float* W2_rates   = (const float*)d_in[16];
    const float* b2_rates   = (const float*)d_in[17];
    const float* W2_ratedby = (const float*)d_in[18];
    const float* b2_ratedby = (const float*)d_in[19];
    const float* W2_follows = (const float*)d_in[20];
    const float* b2_follows = (const float*)d_in[21];

    const int N = N_NODES, E = E_EDGES;

    char* ws = (char*)d_ws;
    size_t off = 0;
    auto alloc = [&](size_t bytes) -> void* {
        void* p = ws + off;
        off += (bytes + 255) & ~(size_t)255;
        return p;
    };
    float* scales = (float*)alloc((size_t)6 * N * 4);
    int* row_ptr  = (int*)alloc((size_t)3 * (N + 1) * 4);
    int* bhist    = (int*)alloc((size_t)6 * NBUCK * 4);
    int* gbase    = (int*)alloc((size_t)6 * (NBUCK + 1) * 4);
    int* gcur     = (int*)alloc((size_t)6 * NBUCK * 4);
    int* col      = (int*)alloc((size_t)3 * E * 4);
    __half* T     = (__half*)alloc((size_t)N * 128 * 4);   // f32-sized region: pairs+sbytes alias it
    __half* hA    = (__half*)alloc((size_t)N * 128 * 2);
    __half* hB    = (__half*)alloc((size_t)N * 128 * 2);
    __half* oA    = (__half*)alloc((size_t)N * 64 * 2);
    __half* oB    = (__half*)alloc((size_t)N * 64 * 2);
    __half* Wt    = (__half*)alloc((size_t)(3 * 128 * 128 + 3 * 128 * 64) * 2);
    (void)ws_size;
    __half* Wt1_rates   = Wt;
    __half* Wt1_ratedby = Wt + 16384;
    __half* Wt1_follows = Wt + 32768;
    __half* Wt2_rates   = Wt + 49152;
    __half* Wt2_ratedby = Wt + 57344;
    __half* Wt2_follows = Wt + 65536;
    // pairs (12MB) + sbytes (3MB) alias the T region (25.6MB): all build kernels
    // complete before the first gemm writes T (stream-ordered).
    unsigned* pairs = (unsigned*)T;
    unsigned char* sbytes = (unsigned char*)(pairs + (size_t)3 * E);

    w_cvt6<<<dim3(16, 6), 256, 0, stream>>>(W1_rates, W1_ratedby, W1_follows,
                                            W2_rates, W2_ratedby, W2_follows,
                                            Wt1_rates, Wt1_ratedby, Wt1_follows,
                                            Wt2_rates, Wt2_ratedby, Wt2_follows);
    hipMemsetAsync(bhist, 0, (size_t)6 * NBUCK * 4, stream);
    bucket_hist<<<dim3(256, 6), 256, 0, stream>>>(rates_src, rates_dst, ratedby_src,
                                                  ratedby_dst, follows_src, follows_dst,
                                                  bhist);
    bucket_scan2<<<6, 64, 0, stream>>>(bhist, gbase, gcur);
    binP<<<dim3(256, 3), 256, 0, stream>>>(rates_src, rates_dst, ratedby_src,
                                           ratedby_dst, follows_src, follows_dst,
                                           gcur, pairs);
    binS<<<dim3(256, 3), 256, 0, stream>>>(rates_src, ratedby_src, follows_src,
                                           gcur, sbytes);
    countS<<<dim3(NBUCK, 3), 256, 0, stream>>>(sbytes, gbase, scales);
    fillB2<<<dim3(NBUCK, 3), 256, 0, stream>>>(pairs, gbase, row_ptr, scales, col);

    const int* rp0 = row_ptr;                 const int* cl0 = col;
    const int* rp1 = row_ptr + (N + 1);       const int* cl1 = col + E;
    const int* rp2 = row_ptr + 2 * (N + 1);   const int* cl2 = col + 2 * (size_t)E;
    const float* s_rates_out   = scales;
    const float* s_rates_in    = scales + N;
    const float* s_ratedby_out = scales + 2 * N;
    const float* s_ratedby_in  = scales + 3 * N;
    const float* s_follows_out = scales + 4 * N;
    const float* s_follows_in  = scales + 5 * N;

    const int GB128 = 384;                  // gemm_mfma<128> blocks (1536 waves, 768 m-streams)
    const int GB64  = 256;                  // gemm_mfma<64> blocks (1024 m-streams)
    const int SB128 = (N / 2 + 3) / 4;      // spmm128 blocks
    const int SB64  = (N / 2 + 7) / 8;      // spmm64 blocks

    // ---------------- layer 1 (HID=128) ----------------
    gemm_mfma<128, float><<<GB128, 256, 0, stream>>>(feat_A, s_rates_out, Wt1_rates, T);
    spmm128<false, true><<<SB128, 256, 0, stream>>>(rp0, cl0, T, s_rates_in,
                                                    b1_rates, hB, N);
    gemm_mfma<128, float><<<GB128, 256, 0, stream>>>(feat_B, s_ratedby_out, Wt1_ratedby, T);
    spmm128<false, false><<<SB128, 256, 0, stream>>>(rp1, cl1, T, s_ratedby_in,
                                                     b1_ratedby, hA, N);
    gemm_mfma<128, float><<<GB128, 256, 0, stream>>>(feat_A, s_follows_out, Wt1_follows, T);
    spmm128<true, true><<<SB128, 256, 0, stream>>>(rp2, cl2, T, s_follows_in,
                                                   b1_follows, hA, N);

    // ---------------- layer 2 (OUT=64) ----------------
    gemm_mfma<64, __half><<<GB64, 256, 0, stream>>>(hA, s_rates_out, Wt2_rates, T);
    spmm64<false><<<SB64, 256, 0, stream>>>(rp0, cl0, T, s_rates_in, b2_rates, oB, N);
    gemm_mfma<64, __half><<<GB64, 256, 0, stream>>>(hB, s_ratedby_out, Wt2_ratedby, T);
    spmm64<false><<<SB64, 256, 0, stream>>>(rp1, cl1, T, s_ratedby_in, b2_ratedby, oA, N);
    gemm_mfma<64, __half><<<GB64, 256, 0, stream>>>(hA, s_follows_out, Wt2_follows, T);
    spmm64<true><<<SB64, 256, 0, stream>>>(rp2, cl2, T, s_follows_in, b2_follows, oA, N);

    // ---------------- scoring ----------------
    float* outp = (float*)d_out;
    score_kernel<<<8192, 256, 0, stream>>>(oA, oB, rates_src, rates_dst, outp, E);
    score_kernel<<<8192, 256, 0, stream>>>(oA, oB, neg_src, neg_dst, outp + E, E);
}

// Round 8
// 358.863 us; speedup vs baseline: 4.3525x; 1.2395x over previous
//
#include <hip/hip_runtime.h>
#include <hip/hip_fp16.h>
#include <cstddef>
#include <type_traits>

#define N_NODES 50000
#define E_EDGES 1000000
#define NBUCK 196          // ceil(50000/256) node-buckets (node>>8)
#define ACHUNK 3907        // ceil(E/256) edges per binning block
#define MTILES 3125        // 50000 / 16
#define HB 96              // hist blocks per index array
#define HCHUNK 10417       // ceil(E/96)
#define GB1 384            // layer-1 gemm blocks per relation
#define GB2 256            // layer-2 gemm blocks per relation
// IN = 128, HID = 128, OUT = 64

typedef _Float16 f16x8 __attribute__((ext_vector_type(8)));
typedef float f32x4 __attribute__((ext_vector_type(4)));

// ---------------- dispatch 1: weight cvt/transpose  ||  hist partials --------
// Hist blocks write private per-block partial histograms (no atomics, no
// pre-zeroing needed). Weight blocks build fp16 Wt[n][k] for all 6 matrices.
__global__ __launch_bounds__(256) void fused0(
        const float* __restrict__ w0, const float* __restrict__ w1,
        const float* __restrict__ w2, const float* __restrict__ w3,
        const float* __restrict__ w4, const float* __restrict__ w5,
        __half* __restrict__ Wt,
        const int* __restrict__ rs, const int* __restrict__ rd,
        const int* __restrict__ bs, const int* __restrict__ bd,
        const int* __restrict__ fs, const int* __restrict__ fd,
        int* __restrict__ bphist) {
    int bx = blockIdx.x;
    if (bx < 6 * HB) {
        __shared__ int l[NBUCK];
        int arr = bx / HB, blk = bx % HB;
        const int* idx = arr == 0 ? rs : arr == 1 ? rd : arr == 2 ? bs
                       : arr == 3 ? bd : arr == 4 ? fs : fd;
        for (int b = threadIdx.x; b < NBUCK; b += 256) l[b] = 0;
        __syncthreads();
        int e0 = blk * HCHUNK;
        int e1 = e0 + HCHUNK; if (e1 > E_EDGES) e1 = E_EDGES;
        for (int i = e0 + threadIdx.x; i < e1; i += 256)
            atomicAdd(&l[((unsigned)idx[i]) >> 8], 1);
        __syncthreads();
        int* dst = bphist + (size_t)(arr * HB + blk) * NBUCK;
        for (int b = threadIdx.x; b < NBUCK; b += 256) dst[b] = l[b];
        return;
    }
    bx -= 6 * HB;
    int m = bx / 16, part = bx % 16;
    const float* W = m == 0 ? w0 : m == 1 ? w1 : m == 2 ? w2 : m == 3 ? w3 : m == 4 ? w4 : w5;
    __half* Tt = Wt + (m < 3 ? m * 16384 : 49152 + (m - 3) * 8192);
    int ncol = m < 3 ? 128 : 64;
    int tot = 128 * ncol;
    for (int i = part * 256 + threadIdx.x; i < tot; i += 16 * 256) {
        int n = i >> 7, k = i & 127;          // Wt[n][k] = W[k][n]
        Tt[i] = __float2half(W[k * ncol + n]);
    }
}

// ---------------- dispatch 2: parallel bucket scan -> gbase, gcur ------------
__global__ void bucket_scan_par(const int* __restrict__ bphist, int* __restrict__ gbase,
                                int* __restrict__ gcur) {
    int arr = blockIdx.x;   // 0..5
    int t = threadIdx.x;    // 256
    int c = 0;
    if (t < NBUCK) {
        const int* p = bphist + (size_t)arr * HB * NBUCK + t;
#pragma unroll 8
        for (int blk = 0; blk < HB; blk++) c += p[(size_t)blk * NBUCK];
    }
    int lane = t & 63, wid = t >> 6;
    __shared__ int wsum[4];
    int v = c;
#pragma unroll
    for (int o = 1; o < 64; o <<= 1) { int u = __shfl_up(v, o); if (lane >= o) v += u; }
    if (lane == 63) wsum[wid] = v;
    __syncthreads();
    int base = 0;
    for (int ww = 0; ww < wid; ww++) base += wsum[ww];
    int excl = base + v - c;
    if (t < NBUCK) {
        gbase[arr * (NBUCK + 1) + t] = excl;
        gcur[arr * NBUCK + t] = excl;
    }
    if (t == 255) gbase[arr * (NBUCK + 1) + NBUCK] = base + v;   // == E
}

// ---------------- dispatch 3: binP (y<3) || binS (y>=3) ----------------------
__global__ __launch_bounds__(256) void fused_bin(
        const int* __restrict__ rs, const int* __restrict__ rd,
        const int* __restrict__ bs, const int* __restrict__ bd,
        const int* __restrict__ fs, const int* __restrict__ fd,
        int* __restrict__ gcur, unsigned* __restrict__ pairs,
        unsigned char* __restrict__ sbytes) {
    int y = blockIdx.y;
    __shared__ int lcnt[NBUCK];
    __shared__ int lbase[NBUCK];
    int e0 = blockIdx.x * ACHUNK;
    int e1 = e0 + ACHUNK; if (e1 > E_EDGES) e1 = E_EDGES;
    for (int b = threadIdx.x; b < NBUCK; b += 256) lcnt[b] = 0;
    __syncthreads();
    if (y < 3) {
        int rel = y, arr = 2 * rel + 1;
        const int* src = rel == 0 ? rs : rel == 1 ? bs : fs;
        const int* dst = rel == 0 ? rd : rel == 1 ? bd : fd;
        for (int i = e0 + threadIdx.x; i < e1; i += 256)
            atomicAdd(&lcnt[((unsigned)dst[i]) >> 8], 1);
        __syncthreads();
        for (int b = threadIdx.x; b < NBUCK; b += 256) {
            lbase[b] = lcnt[b] ? atomicAdd(&gcur[arr * NBUCK + b], lcnt[b]) : 0;
            lcnt[b] = 0;
        }
        __syncthreads();
        unsigned* pp = pairs + (size_t)rel * E_EDGES;
        for (int i = e0 + threadIdx.x; i < e1; i += 256) {
            int d = dst[i];
            int b = ((unsigned)d) >> 8;
            int p = lbase[b] + atomicAdd(&lcnt[b], 1);
            pp[p] = ((unsigned)(d & 255) << 16) | (unsigned)src[i];
        }
    } else {
        int rel = y - 3, arr = 2 * rel;
        const int* src = rel == 0 ? rs : rel == 1 ? bs : fs;
        for (int i = e0 + threadIdx.x; i < e1; i += 256)
            atomicAdd(&lcnt[((unsigned)src[i]) >> 8], 1);
        __syncthreads();
        for (int b = threadIdx.x; b < NBUCK; b += 256) {
            lbase[b] = lcnt[b] ? atomicAdd(&gcur[arr * NBUCK + b], lcnt[b]) : 0;
            lcnt[b] = 0;
        }
        __syncthreads();
        unsigned char* sb = sbytes + (size_t)rel * E_EDGES;
        for (int i = e0 + threadIdx.x; i < e1; i += 256) {
            int s = src[i];
            int b = ((unsigned)s) >> 8;
            int p = lbase[b] + atomicAdd(&lcnt[b], 1);
            sb[p] = (unsigned char)(s & 255);
        }
    }
}

// ---------------- dispatch 4: countS (y<3) || fillB2 (y>=3) ------------------
__global__ __launch_bounds__(256) void fused_finish(
        const unsigned* __restrict__ pairs, const unsigned char* __restrict__ sbytes,
        const int* __restrict__ gbase, int* __restrict__ row_ptr,
        float* __restrict__ scales, int* __restrict__ col) {
    int y = blockIdx.y, b = blockIdx.x, t = threadIdx.x;
    __shared__ int cnt[256];
    __shared__ int rowbase[256];
    __shared__ int wsum[4];
    if (y < 3) {
        int rel = y, arr = 2 * rel;
        int p0 = gbase[arr * (NBUCK + 1) + b];
        int p1 = gbase[arr * (NBUCK + 1) + b + 1];
        const unsigned char* sb = sbytes + (size_t)rel * E_EDGES;
        cnt[t] = 0;
        __syncthreads();
        for (int i = p0 + t; i < p1; i += 256)
            atomicAdd(&cnt[sb[i]], 1);
        __syncthreads();
        int node = b * 256 + t;
        if (node < N_NODES) {
            int c = cnt[t]; if (c < 1) c = 1;
            scales[(size_t)arr * N_NODES + node] = 1.0f / sqrtf((float)c);
        }
    } else {
        int rel = y - 3, arr = 2 * rel + 1;
        int gb = gbase[arr * (NBUCK + 1) + b];
        int ge = gbase[arr * (NBUCK + 1) + b + 1];
        const unsigned* pp = pairs + (size_t)rel * E_EDGES;
        cnt[t] = 0;
        __syncthreads();
        for (int i = gb + t; i < ge; i += 256)
            atomicAdd(&cnt[pp[i] >> 16], 1);
        __syncthreads();
        int lane = t & 63, wid = t >> 6;
        int c0 = cnt[t];
        int v = c0;
#pragma unroll
        for (int o = 1; o < 64; o <<= 1) { int u = __shfl_up(v, o); if (lane >= o) v += u; }
        if (lane == 63) wsum[wid] = v;
        __syncthreads();
        int base = gb;
        for (int w = 0; w < wid; w++) base += wsum[w];
        int excl = base + v - c0;
        rowbase[t] = excl;
        int node = b * 256 + t;
        if (node <= N_NODES)
            row_ptr[(size_t)rel * (N_NODES + 1) + node] = excl;
        if (node < N_NODES) {
            int c = c0; if (c < 1) c = 1;
            scales[(size_t)arr * N_NODES + node] = 1.0f / sqrtf((float)c);
        }
        cnt[t] = 0;   // reuse as per-row cursor
        __syncthreads();
        int* cl = col + (size_t)rel * E_EDGES;
        for (int i = gb + t; i < ge; i += 256) {
            unsigned p = pp[i];
            int dl = p >> 16;
            int slot = rowbase[dl] + atomicAdd(&cnt[dl], 1);
            cl[slot] = (int)(p & 0xFFFFu);
        }
    }
}

// --------------------------------------------- MFMA GEMM body: T = diag(s)*(X@W)
// Wave = 16-row M-tile x 64-col strip; B frags register-resident, no LDS.
// C/D layout: col = lane&15, row = (lane>>4)*4 + reg (HW-verified).
template <int NCOL, typename XT>
__device__ __forceinline__ void gemm_body(const XT* __restrict__ X,
                                          const float* __restrict__ sc,
                                          const __half* __restrict__ Wt,
                                          __half* __restrict__ T,
                                          int bxr, int nblocks) {
    constexpr int NHALF = NCOL / 64;        // 2 for 128, 1 for 64
    int gw = bxr * 4 + ((int)threadIdx.x >> 6);
    int lane = threadIdx.x & 63;
    int half_id = gw % NHALF;
    int mstream = gw / NHALF;
    int nstreams = nblocks * 4 / NHALF;
    int l15 = lane & 15, g = lane >> 4;

    f16x8 b[4][4];
    {
        const __half* wb = Wt + ((size_t)half_id * 64 + l15) * 128 + g * 8;
#pragma unroll
        for (int nt = 0; nt < 4; nt++)
#pragma unroll
            for (int kb = 0; kb < 4; kb++)
                b[nt][kb] = *(const f16x8*)(wb + nt * 16 * 128 + kb * 32);
    }

    for (int mt = mstream; mt < MTILES; mt += nstreams) {
        int m0 = mt * 16;
        f16x8 a[4];
        if constexpr (std::is_same<XT, float>::value) {
            const float* xr = X + (size_t)(m0 + l15) * 128 + g * 8;
#pragma unroll
            for (int kb = 0; kb < 4; kb++) {
                float4 u = *(const float4*)(xr + kb * 32);
                float4 v = *(const float4*)(xr + kb * 32 + 4);
                f16x8 t;
                t[0] = (_Float16)u.x; t[1] = (_Float16)u.y;
                t[2] = (_Float16)u.z; t[3] = (_Float16)u.w;
                t[4] = (_Float16)v.x; t[5] = (_Float16)v.y;
                t[6] = (_Float16)v.z; t[7] = (_Float16)v.w;
                a[kb] = t;
            }
        } else {
            const _Float16* xr = (const _Float16*)X + (size_t)(m0 + l15) * 128 + g * 8;
#pragma unroll
            for (int kb = 0; kb < 4; kb++)
                a[kb] = *(const f16x8*)(xr + kb * 32);
        }
        f32x4 acc[4];
#pragma unroll
        for (int nt = 0; nt < 4; nt++) acc[nt] = (f32x4){0.f, 0.f, 0.f, 0.f};
#pragma unroll
        for (int kb = 0; kb < 4; kb++)
#pragma unroll
            for (int nt = 0; nt < 4; nt++)
                acc[nt] = __builtin_amdgcn_mfma_f32_16x16x32_f16(a[kb], b[nt][kb], acc[nt], 0, 0, 0);
        int mrow = m0 + g * 4;
#pragma unroll
        for (int j = 0; j < 4; j++) {
            float sj = sc[mrow + j];
            __half* tj = T + (size_t)(mrow + j) * NCOL + half_id * 64 + l15;
            tj[0]  = __float2half(acc[0][j] * sj);
            tj[16] = __float2half(acc[1][j] * sj);
            tj[32] = __float2half(acc[2][j] * sj);
            tj[48] = __float2half(acc[3][j] * sj);
        }
    }
}

// ---------------- dispatch 5: layer-1 GEMMs (3 relations) --------------------
__global__ __launch_bounds__(256) void gemm_l1(const float* __restrict__ fA,
                                               const float* __restrict__ fB,
                                               const float* __restrict__ scales,
                                               const __half* __restrict__ Wt,
                                               __half* __restrict__ T012) {
    int rel = blockIdx.x / GB1, bxr = blockIdx.x % GB1;
    const float* X = (rel == 1) ? fB : fA;
    const float* sc = scales + (rel == 0 ? 0 : rel == 1 ? 2 * N_NODES : 4 * N_NODES);
    const __half* W = Wt + rel * 16384;
    __half* T = T012 + (size_t)rel * N_NODES * 128;
    gemm_body<128, float>(X, sc, W, T, bxr, GB1);
}

// ---------------- dispatch 7: layer-2 GEMMs (3 relations) --------------------
__global__ __launch_bounds__(256) void gemm_l2(const __half* __restrict__ hA,
                                               const __half* __restrict__ hB,
                                               const float* __restrict__ scales,
                                               const __half* __restrict__ Wt,
                                               __half* __restrict__ Tp) {
    int rel = blockIdx.x / GB2, bxr = blockIdx.x % GB2;
    const __half* X = (rel == 1) ? hB : hA;
    const float* sc = scales + (rel == 0 ? 0 : rel == 1 ? 2 * N_NODES : 4 * N_NODES);
    const __half* W = Wt + 49152 + rel * 8192;
    __half* T = Tp + (size_t)rel * N_NODES * 64;
    gemm_body<64, __half>(X, sc, W, T, bxr, GB2);
}

// ---------------- dispatch 6: layer-1 fused SpMM -----------------------------
// waves [0, 25000): two B-rows each via CSR0/T0 -> hB (relu)
// waves [25000, 75000): one A-row, dual-stream CSR1/T1 + CSR2/T2 -> hA (relu)
__global__ __launch_bounds__(256) void spmm_l1(
        const int* __restrict__ row_ptr, const int* __restrict__ col,
        const __half* __restrict__ T012, const float* __restrict__ scales,
        const float* __restrict__ b1r, const float* __restrict__ b1rb,
        const float* __restrict__ b1f,
        __half* __restrict__ hB, __half* __restrict__ hA) {
    int w = (blockIdx.x * blockDim.x + threadIdx.x) >> 6;
    int lane = threadIdx.x & 63;
    unsigned loff = (unsigned)lane << 2;
    const char* T0 = (const char*)T012;
    const char* T1 = T0 + (size_t)N_NODES * 256;
    const char* T2 = T1 + (size_t)N_NODES * 256;
#define LDT(B, c) __half22float2(*(const __half2*)((B) + (((unsigned)(c) << 8) + loff)))
    if (w < N_NODES / 2) {
        const int* cl = col;
        int rowA = w * 2, rowB = rowA + 1;
        int eA = row_ptr[rowA], EA = row_ptr[rowA + 1];
        int eB = EA, EB = row_ptr[rowB + 1];
        float axA = 0.f, ayA = 0.f, axB = 0.f, ayB = 0.f;
        while (eA + 4 <= EA && eB + 4 <= EB) {
            int a0 = cl[eA], a1 = cl[eA+1], a2 = cl[eA+2], a3 = cl[eA+3];
            int b0 = cl[eB], b1 = cl[eB+1], b2 = cl[eB+2], b3 = cl[eB+3];
            float2 v0 = LDT(T0, a0), v1 = LDT(T0, a1), v2 = LDT(T0, a2), v3 = LDT(T0, a3);
            float2 u0 = LDT(T0, b0), u1 = LDT(T0, b1), u2 = LDT(T0, b2), u3 = LDT(T0, b3);
            axA += (v0.x + v1.x) + (v2.x + v3.x); ayA += (v0.y + v1.y) + (v2.y + v3.y);
            axB += (u0.x + u1.x) + (u2.x + u3.x); ayB += (u0.y + u1.y) + (u2.y + u3.y);
            eA += 4; eB += 4;
        }
        while (eA + 4 <= EA) {
            int a0 = cl[eA], a1 = cl[eA+1], a2 = cl[eA+2], a3 = cl[eA+3];
            float2 v0 = LDT(T0, a0), v1 = LDT(T0, a1), v2 = LDT(T0, a2), v3 = LDT(T0, a3);
            axA += (v0.x + v1.x) + (v2.x + v3.x); ayA += (v0.y + v1.y) + (v2.y + v3.y);
            eA += 4;
        }
        while (eB + 4 <= EB) {
            int b0 = cl[eB], b1 = cl[eB+1], b2 = cl[eB+2], b3 = cl[eB+3];
            float2 u0 = LDT(T0, b0), u1 = LDT(T0, b1), u2 = LDT(T0, b2), u3 = LDT(T0, b3);
            axB += (u0.x + u1.x) + (u2.x + u3.x); ayB += (u0.y + u1.y) + (u2.y + u3.y);
            eB += 4;
        }
        while (eA < EA && eB < EB) {
            float2 v = LDT(T0, cl[eA]), u = LDT(T0, cl[eB]);
            axA += v.x; ayA += v.y; axB += u.x; ayB += u.y;
            eA++; eB++;
        }
        for (; eA < EA; eA++) { float2 v = LDT(T0, cl[eA]); axA += v.x; ayA += v.y; }
        for (; eB < EB; eB++) { float2 v = LDT(T0, cl[eB]); axB += v.x; ayB += v.y; }
        float bx = b1r[2 * lane], by = b1r[2 * lane + 1];
        float sA = scales[N_NODES + rowA], sB = scales[N_NODES + rowB];
        float ox = fmaxf(fmaf(axA, sA, bx), 0.f), oy = fmaxf(fmaf(ayA, sA, by), 0.f);
        *(__half2*)(hB + (size_t)rowA * 128 + 2 * lane) = __floats2half2_rn(ox, oy);
        ox = fmaxf(fmaf(axB, sB, bx), 0.f); oy = fmaxf(fmaf(ayB, sB, by), 0.f);
        *(__half2*)(hB + (size_t)rowB * 128 + 2 * lane) = __floats2half2_rn(ox, oy);
    } else {
        int r = w - N_NODES / 2;
        const int* rp1 = row_ptr + (N_NODES + 1);
        const int* rp2 = row_ptr + 2 * (N_NODES + 1);
        const int* cl1 = col + E_EDGES;
        const int* cl2 = col + 2 * (size_t)E_EDGES;
        int e1 = rp1[r], E1 = rp1[r + 1];
        int e2 = rp2[r], E2 = rp2[r + 1];
        float a1x = 0.f, a1y = 0.f, a2x = 0.f, a2y = 0.f;
        while (e1 + 4 <= E1 && e2 + 4 <= E2) {
            int a0 = cl1[e1], a1 = cl1[e1+1], a2 = cl1[e1+2], a3 = cl1[e1+3];
            int b0 = cl2[e2], b1 = cl2[e2+1], b2 = cl2[e2+2], b3 = cl2[e2+3];
            float2 v0 = LDT(T1, a0), v1 = LDT(T1, a1), v2 = LDT(T1, a2), v3 = LDT(T1, a3);
            float2 u0 = LDT(T2, b0), u1 = LDT(T2, b1), u2 = LDT(T2, b2), u3 = LDT(T2, b3);
            a1x += (v0.x + v1.x) + (v2.x + v3.x); a1y += (v0.y + v1.y) + (v2.y + v3.y);
            a2x += (u0.x + u1.x) + (u2.x + u3.x); a2y += (u0.y + u1.y) + (u2.y + u3.y);
            e1 += 4; e2 += 4;
        }
        while (e1 + 4 <= E1) {
            int a0 = cl1[e1], a1 = cl1[e1+1], a2 = cl1[e1+2], a3 = cl1[e1+3];
            float2 v0 = LDT(T1, a0), v1 = LDT(T1, a1), v2 = LDT(T1, a2), v3 = LDT(T1, a3);
            a1x += (v0.x + v1.x) + (v2.x + v3.x); a1y += (v0.y + v1.y) + (v2.y + v3.y);
            e1 += 4;
        }
        while (e2 + 4 <= E2) {
            int b0 = cl2[e2], b1 = cl2[e2+1], b2 = cl2[e2+2], b3 = cl2[e2+3];
            float2 u0 = LDT(T2, b0), u1 = LDT(T2, b1), u2 = LDT(T2, b2), u3 = LDT(T2, b3);
            a2x += (u0.x + u1.x) + (u2.x + u3.x); a2y += (u0.y + u1.y) + (u2.y + u3.y);
            e2 += 4;
        }
        while (e1 < E1 && e2 < E2) {
            float2 v = LDT(T1, cl1[e1]), u = LDT(T2, cl2[e2]);
            a1x += v.x; a1y += v.y; a2x += u.x; a2y += u.y;
            e1++; e2++;
        }
        for (; e1 < E1; e1++) { float2 v = LDT(T1, cl1[e1]); a1x += v.x; a1y += v.y; }
        for (; e2 < E2; e2++) { float2 v = LDT(T2, cl2[e2]); a2x += v.x; a2y += v.y; }
        float s1 = scales[3 * N_NODES + r], s2 = scales[5 * N_NODES + r];
        float ox = a1x * s1 + a2x * s2 + b1rb[2 * lane] + b1f[2 * lane];
        float oy = a1y * s1 + a2y * s2 + b1rb[2 * lane + 1] + b1f[2 * lane + 1];
        ox = fmaxf(ox, 0.f); oy = fmaxf(oy, 0.f);
        *(__half2*)(hA + (size_t)r * 128 + 2 * lane) = __floats2half2_rn(ox, oy);
    }
#undef LDT
}

// ---------------- dispatch 8: layer-2 fused SpMM (32-lane groups) ------------
__global__ __launch_bounds__(256) void spmm_l2(
        const int* __restrict__ row_ptr, const int* __restrict__ col,
        const __half* __restrict__ Tp, const float* __restrict__ scales,
        const float* __restrict__ b2r, const float* __restrict__ b2rb,
        const float* __restrict__ b2f,
        __half* __restrict__ oB, __half* __restrict__ oA) {
    int g = (blockIdx.x * blockDim.x + threadIdx.x) >> 5;
    int l2 = threadIdx.x & 31;
    unsigned loff = (unsigned)l2 << 2;
    const char* T0 = (const char*)Tp;
    const char* T1 = T0 + (size_t)N_NODES * 128;
    const char* T2 = T1 + (size_t)N_NODES * 128;
#define LDT(B, c) __half22float2(*(const __half2*)((B) + (((unsigned)(c) << 7) + loff)))
    if (g < N_NODES / 2) {
        const int* cl = col;
        int rowA = g * 2, rowB = rowA + 1;
        int eA = row_ptr[rowA], EA = row_ptr[rowA + 1];
        int eB = EA, EB = row_ptr[rowB + 1];
        float axA = 0.f, ayA = 0.f, axB = 0.f, ayB = 0.f;
        while (eA + 4 <= EA && eB + 4 <= EB) {
            int a0 = cl[eA], a1 = cl[eA+1], a2 = cl[eA+2], a3 = cl[eA+3];
            int b0 = cl[eB], b1 = cl[eB+1], b2 = cl[eB+2], b3 = cl[eB+3];
            float2 v0 = LDT(T0, a0), v1 = LDT(T0, a1), v2 = LDT(T0, a2), v3 = LDT(T0, a3);
            float2 u0 = LDT(T0, b0), u1 = LDT(T0, b1), u2 = LDT(T0, b2), u3 = LDT(T0, b3);
            axA += (v0.x + v1.x) + (v2.x + v3.x); ayA += (v0.y + v1.y) + (v2.y + v3.y);
            axB += (u0.x + u1.x) + (u2.x + u3.x); ayB += (u0.y + u1.y) + (u2.y + u3.y);
            eA += 4; eB += 4;
        }
        while (eA + 4 <= EA) {
            int a0 = cl[eA], a1 = cl[eA+1], a2 = cl[eA+2], a3 = cl[eA+3];
            float2 v0 = LDT(T0, a0), v1 = LDT(T0, a1), v2 = LDT(T0, a2), v3 = LDT(T0, a3);
            axA += (v0.x + v1.x) + (v2.x + v3.x); ayA += (v0.y + v1.y) + (v2.y + v3.y);
            eA += 4;
        }
        while (eB + 4 <= EB) {
            int b0 = cl[eB], b1 = cl[eB+1], b2 = cl[eB+2], b3 = cl[eB+3];
            float2 u0 = LDT(T0, b0), u1 = LDT(T0, b1), u2 = LDT(T0, b2), u3 = LDT(T0, b3);
            axB += (u0.x + u1.x) + (u2.x + u3.x); ayB += (u0.y + u1.y) + (u2.y + u3.y);
            eB += 4;
        }
        while (eA < EA && eB < EB) {
            float2 v = LDT(T0, cl[eA]), u = LDT(T0, cl[eB]);
            axA += v.x; ayA += v.y; axB += u.x; ayB += u.y;
            eA++; eB++;
        }
        for (; eA < EA; eA++) { float2 v = LDT(T0, cl[eA]); axA += v.x; ayA += v.y; }
        for (; eB < EB; eB++) { float2 v = LDT(T0, cl[eB]); axB += v.x; ayB += v.y; }
        float bx = b2r[2 * l2], by = b2r[2 * l2 + 1];
        float sA = scales[N_NODES + rowA], sB = scales[N_NODES + rowB];
        *(__half2*)(oB + (size_t)rowA * 64 + 2 * l2) =
            __floats2half2_rn(fmaf(axA, sA, bx), fmaf(ayA, sA, by));
        *(__half2*)(oB + (size_t)rowB * 64 + 2 * l2) =
            __floats2half2_rn(fmaf(axB, sB, bx), fmaf(ayB, sB, by));
    } else {
        int r = g - N_NODES / 2;
        const int* rp1 = row_ptr + (N_NODES + 1);
        const int* rp2 = row_ptr + 2 * (N_NODES + 1);
        const int* cl1 = col + E_EDGES;
        const int* cl2 = col + 2 * (size_t)E_EDGES;
        int e1 = rp1[r], E1 = rp1[r + 1];
        int e2 = rp2[r], E2 = rp2[r + 1];
        float a1x = 0.f, a1y = 0.f, a2x = 0.f, a2y = 0.f;
        while (e1 + 4 <= E1 && e2 + 4 <= E2) {
            int a0 = cl1[e1], a1 = cl1[e1+1], a2 = cl1[e1+2], a3 = cl1[e1+3];
            int b0 = cl2[e2], b1 = cl2[e2+1], b2 = cl2[e2+2], b3 = cl2[e2+3];
            float2 v0 = LDT(T1, a0), v1 = LDT(T1, a1), v2 = LDT(T1, a2), v3 = LDT(T1, a3);
            float2 u0 = LDT(T2, b0), u1 = LDT(T2, b1), u2 = LDT(T2, b2), u3 = LDT(T2, b3);
            a1x += (v0.x + v1.x) + (v2.x + v3.x); a1y += (v0.y + v1.y) + (v2.y + v3.y);
            a2x += (u0.x + u1.x) + (u2.x + u3.x); a2y += (u0.y + u1.y) + (u2.y + u3.y);
            e1 += 4; e2 += 4;
        }
        while (e1 + 4 <= E1) {
            int a0 = cl1[e1], a1 = cl1[e1+1], a2 = cl1[e1+2], a3 = cl1[e1+3];
            float2 v0 = LDT(T1, a0), v1 = LDT(T1, a1), v2 = LDT(T1, a2), v3 = LDT(T1, a3);
            a1x += (v0.x + v1.x) + (v2.x + v3.x); a1y += (v0.y + v1.y) + (v2.y + v3.y);
            e1 += 4;
        }
        while (e2 + 4 <= E2) {
            int b0 = cl2[e2], b1 = cl2[e2+1], b2 = cl2[e2+2], b3 = cl2[e2+3];
            float2 u0 = LDT(T2, b0), u1 = LDT(T2, b1), u2 = LDT(T2, b2), u3 = LDT(T2, b3);
            a2x += (u0.x + u1.x) + (u2.x + u3.x); a2y += (u0.y + u1.y) + (u2.y + u3.y);
            e2 += 4;
        }
        while (e1 < E1 && e2 < E2) {
            float2 v = LDT(T1, cl1[e1]), u = LDT(T2, cl2[e2]);
            a1x += v.x; a1y += v.y; a2x += u.x; a2y += u.y;
            e1++; e2++;
        }
        for (; e1 < E1; e1++) { float2 v = LDT(T1, cl1[e1]); a1x += v.x; a1y += v.y; }
        for (; e2 < E2; e2++) { float2 v = LDT(T2, cl2[e2]); a2x += v.x; a2y += v.y; }
        float s1 = scales[3 * N_NODES + r], s2 = scales[5 * N_NODES + r];
        float ox = a1x * s1 + a2x * s2 + b2rb[2 * l2] + b2f[2 * l2];
        float oy = a1y * s1 + a2y * s2 + b2rb[2 * l2 + 1] + b2f[2 * l2 + 1];
        *(__half2*)(oA + (size_t)r * 64 + 2 * l2) = __floats2half2_rn(ox, oy);
    }
#undef LDT
}

// ---------------- dispatch 9: scoring (pos + neg fused) ----------------------
__global__ __launch_bounds__(256) void score2(const __half* __restrict__ oA,
                                              const __half* __restrict__ oB,
                                              const int* __restrict__ ps,
                                              const int* __restrict__ pd,
                                              const int* __restrict__ ns,
                                              const int* __restrict__ nd,
                                              float* __restrict__ out) {
    int g = (blockIdx.x * blockDim.x + threadIdx.x) >> 4;
    int l = threadIdx.x & 15;
    int ng = (gridDim.x * blockDim.x) >> 4;
    const char* A = (const char*)oA;
    const char* B = (const char*)oB;
    unsigned loff = (unsigned)l << 3;   // 4 halves per lane
#define SCORE_LOOP(SRC, DST, OUT)                                               \
    for (int e0 = g * 2; e0 < E_EDGES; e0 += ng * 2) {                          \
        int e1 = e0 + 1;                                                        \
        int s0 = SRC[e0], d0 = DST[e0], s1 = SRC[e1], d1 = DST[e1];             \
        union { uint2 u; __half2 h[2]; } a0, b0, a1, b1;                        \
        a0.u = *(const uint2*)(A + (((unsigned)s0 << 7) + loff));               \
        b0.u = *(const uint2*)(B + (((unsigned)d0 << 7) + loff));               \
        a1.u = *(const uint2*)(A + (((unsigned)s1 << 7) + loff));               \
        b1.u = *(const uint2*)(B + (((unsigned)d1 << 7) + loff));               \
        float2 fa, fb;                                                          \
        fa = __half22float2(a0.h[0]); fb = __half22float2(b0.h[0]);             \
        float p0 = fa.x * fb.x + fa.y * fb.y;                                   \
        fa = __half22float2(a0.h[1]); fb = __half22float2(b0.h[1]);             \
        p0 += fa.x * fb.x + fa.y * fb.y;                                        \
        fa = __half22float2(a1.h[0]); fb = __half22float2(b1.h[0]);             \
        float p1 = fa.x * fb.x + fa.y * fb.y;                                   \
        fa = __half22float2(a1.h[1]); fb = __half22float2(b1.h[1]);             \
        p1 += fa.x * fb.x + fa.y * fb.y;                                        \
        p0 += __shfl_xor(p0, 8); p1 += __shfl_xor(p1, 8);                       \
        p0 += __shfl_xor(p0, 4); p1 += __shfl_xor(p1, 4);                       \
        p0 += __shfl_xor(p0, 2); p1 += __shfl_xor(p1, 2);                       \
        p0 += __shfl_xor(p0, 1); p1 += __shfl_xor(p1, 1);                       \
        if (l == 0) { OUT[e0] = p0; OUT[e1] = p1; }                             \
    }
    SCORE_LOOP(ps, pd, out)
    float* outn = out + E_EDGES;
    SCORE_LOOP(ns, nd, outn)
#undef SCORE_LOOP
}

// ---------------------------------------------------------------------------
extern "C" void kernel_launch(void* const* d_in, const int* in_sizes, int n_in,
                              void* d_out, int out_size, void* d_ws, size_t ws_size,
                              hipStream_t stream) {
    const float* feat_A     = (const float*)d_in[0];
    const float* feat_B     = (const float*)d_in[1];
    const int* rates_src    = (const int*)d_in[2];
    const int* rates_dst    = (const int*)d_in[3];
    const int* ratedby_src  = (const int*)d_in[4];
    const int* ratedby_dst  = (const int*)d_in[5];
    const int* follows_src  = (const int*)d_in[6];
    const int* follows_dst  = (const int*)d_in[7];
    const int* neg_src      = (const int*)d_in[8];
    const int* neg_dst      = (const int*)d_in[9];
    const float* W1_rates   = (const float*)d_in[10];
    const float* b1_rates   = (const float*)d_in[11];
    const float* W1_ratedby = (const float*)d_in[12];
    const float* b1_ratedby = (const float*)d_in[13];
    const float* W1_follows = (const float*)d_in[14];
    const float* b1_follows = (const float*)d_in[15];
    const float* W2_rates   = (const float*)d_in[16];
    const float* b2_rates   = (const float*)d_in[17];
    const float* W2_ratedby = (const float*)d_in[18];
    const float* b2_ratedby = (const float*)d_in[19];
    const float* W2_follows = (const float*)d_in[20];
    const float* b2_follows = (const float*)d_in[21];

    const int N = N_NODES, E = E_EDGES;

    char* ws = (char*)d_ws;
    size_t off = 0;
    auto alloc = [&](size_t bytes) -> void* {
        void* p = ws + off;
        off += (bytes + 255) & ~(size_t)255;
        return p;
    };
    float* scales = (float*)alloc((size_t)6 * N * 4);
    int* row_ptr  = (int*)alloc((size_t)3 * (N + 1) * 4);
    int* bphist   = (int*)alloc((size_t)6 * HB * NBUCK * 4);
    int* gbase    = (int*)alloc((size_t)6 * (NBUCK + 1) * 4);
    int* gcur     = (int*)alloc((size_t)6 * NBUCK * 4);
    int* col      = (int*)alloc((size_t)3 * E * 4);
    unsigned* pairs = (unsigned*)alloc((size_t)3 * E * 4);
    unsigned char* sbytes = (unsigned char*)alloc((size_t)3 * E);
    __half* T012  = (__half*)alloc((size_t)3 * N * 128 * 2);
    __half* Tp    = (__half*)alloc((size_t)3 * N * 64 * 2);
    __half* hA    = (__half*)alloc((size_t)N * 128 * 2);
    __half* hB    = (__half*)alloc((size_t)N * 128 * 2);
    __half* oA    = (__half*)alloc((size_t)N * 64 * 2);
    __half* oB    = (__half*)alloc((size_t)N * 64 * 2);
    __half* Wt    = (__half*)alloc((size_t)(3 * 128 * 128 + 3 * 128 * 64) * 2);
    (void)ws_size;

    fused0<<<6 * HB + 96, 256, 0, stream>>>(W1_rates, W1_ratedby, W1_follows,
                                            W2_rates, W2_ratedby, W2_follows, Wt,
                                            rates_src, rates_dst, ratedby_src,
                                            ratedby_dst, follows_src, follows_dst,
                                            bphist);
    bucket_scan_par<<<6, 256, 0, stream>>>(bphist, gbase, gcur);
    fused_bin<<<dim3(256, 6), 256, 0, stream>>>(rates_src, rates_dst, ratedby_src,
                                                ratedby_dst, follows_src, follows_dst,
                                                gcur, pairs, sbytes);
    fused_finish<<<dim3(NBUCK, 6), 256, 0, stream>>>(pairs, sbytes, gbase,
                                                     row_ptr, scales, col);

    gemm_l1<<<3 * GB1, 256, 0, stream>>>(feat_A, feat_B, scales, Wt, T012);
    spmm_l1<<<(3 * N / 2) / 4, 256, 0, stream>>>(row_ptr, col, T012, scales,
                                                 b1_rates, b1_ratedby, b1_follows,
                                                 hB, hA);
    gemm_l2<<<3 * GB2, 256, 0, stream>>>(hA, hB, scales, Wt, Tp);
    spmm_l2<<<(3 * N / 2) / 8, 256, 0, stream>>>(row_ptr, col, Tp, scales,
                                                 b2_rates, b2_ratedby, b2_follows,
                                                 oB, oA);
    score2<<<8192, 256, 0, stream>>>(oA, oB, rates_src, rates_dst,
                                     neg_src, neg_dst, (float*)d_out);
}